// Round 1
// baseline (23309.489 us; speedup 1.0000x reference)
//
#include <hip/hip_runtime.h>
#include <math.h>

// ---------------------------------------------------------------------------
// CLSADecoder: 2-layer RowSharedConvLSTM + inter-attn + causal self-attn + head
// B=128, T=64, D=2048 (ROWS=8, CH=32, COLS=8), S=128.
// Strategy: bf16x3 MFMA for the four (128x4096)@(4096x2048) fuse GEMMs per
// step, single-pass flash inter-attention over bf16 encoder, f32 (hi+lo bf16)
// refined history for self-attn scores, layer-0 ConvLSTM precomputed for all
// T, head batched at the end.
// ---------------------------------------------------------------------------

typedef __bf16 bf16x8 __attribute__((ext_vector_type(8)));
typedef float  f32x16 __attribute__((ext_vector_type(16)));
typedef float  f32x4v __attribute__((ext_vector_type(4)));
typedef unsigned short u16x8 __attribute__((ext_vector_type(8)));
typedef unsigned short u16x4 __attribute__((ext_vector_type(4)));

#define BD 262144   // 128*2048  (one [B][D] plane)

__device__ __forceinline__ unsigned short f2bf(float x){
  unsigned int u = __builtin_bit_cast(unsigned int, x);
  u += 0x7fffu + ((u >> 16) & 1u);          // round-to-nearest-even
  return (unsigned short)(u >> 16);
}
__device__ __forceinline__ float bf2f(unsigned short h){
  unsigned int u = ((unsigned int)h) << 16;
  return __builtin_bit_cast(float, u);
}
__device__ __forceinline__ float sigmoidf_(float x){
  return 1.0f / (1.0f + __expf(-x));
}

// ---------------------------------------------------------------------------
// Prologue: transpose+split f32 weight [K][N] -> bf16 hi/lo planes [Npad][K]
// ---------------------------------------------------------------------------
__global__ __launch_bounds__(256) void k_transpose_split(
    const float* __restrict__ src, unsigned short* __restrict__ dhi,
    unsigned short* __restrict__ dlo, const int K, const int N, const int Npad)
{
  __shared__ float tile[32][33];
  const int n0 = blockIdx.x * 32, k0 = blockIdx.y * 32;
  const int tx = threadIdx.x & 31, ty = threadIdx.x >> 5;   // ty in [0,8)
  #pragma unroll
  for (int ii = 0; ii < 4; ++ii){
    const int k = k0 + ty + ii*8, n = n0 + tx;
    float v = (n < N) ? src[(size_t)k * N + n] : 0.0f;
    tile[ty + ii*8][tx] = v;
  }
  __syncthreads();
  #pragma unroll
  for (int ii = 0; ii < 4; ++ii){
    const int n = n0 + ty + ii*8, k = k0 + tx;
    const float v = tile[tx][ty + ii*8];
    const unsigned short h = f2bf(v);
    dhi[(size_t)n * K + k] = h;
    dlo[(size_t)n * K + k] = f2bf(v - bf2f(h));
  }
}

__global__ void k_f32_to_bf16(const float* __restrict__ src,
                              unsigned short* __restrict__ dst, const int n4)
{
  const int i = blockIdx.x * 256 + threadIdx.x;
  if (i < n4){
    f32x4v v = *reinterpret_cast<const f32x4v*>(src + (size_t)i * 4);
    u16x4 o;
    #pragma unroll
    for (int j = 0; j < 4; ++j) o[j] = f2bf(v[j]);
    *reinterpret_cast<u16x4*>(dst + (size_t)i * 4) = o;
  }
}

// pack cell1 conv weights: [128][32][3] ch + [128][32][3] cx -> bf16 [128][32][6]
__global__ void k_pack_cellw(const float* __restrict__ chw,
                             const float* __restrict__ cxw,
                             unsigned short* __restrict__ wp)
{
  const int i = blockIdx.x * 256 + threadIdx.x;
  if (i < 128 * 32){
    #pragma unroll
    for (int k = 0; k < 3; ++k){
      wp[i*6 + k]     = f2bf(chw[i*3 + k]);
      wp[i*6 + 3 + k] = f2bf(cxw[i*3 + k]);
    }
  }
}

// ---------------------------------------------------------------------------
// Layer-0 ConvLSTM for ALL 64 steps (independent of attention).
// Block = (b,row); 256 threads; h,c carried in LDS/regs; writes hraw0 hi/lo.
// ---------------------------------------------------------------------------
__global__ __launch_bounds__(256) void k_cell0(
    const float* __restrict__ x_flat,                       // [B][T][64]
    const float* __restrict__ h0, const float* __restrict__ c0, // layer0 slices [B][2048]
    const float* __restrict__ cxw, const float* __restrict__ cxb,
    const float* __restrict__ chw, const float* __restrict__ chb,
    unsigned short* __restrict__ hrawHi, unsigned short* __restrict__ hrawLo) // [T][B][2048]
{
  const int b = blockIdx.x >> 3, row = blockIdx.x & 7;
  const int tid = threadIdx.x;
  __shared__ float h_lds[256];
  __shared__ float x_lds[8];
  __shared__ float P[128][2][8];
  const int gc = tid >> 1, ih = tid & 1;
  float wh[16][3];
  #pragma unroll
  for (int icl = 0; icl < 16; ++icl)
    #pragma unroll
    for (int k = 0; k < 3; ++k)
      wh[icl][k] = chw[(gc*32 + ih*16 + icl)*3 + k];
  const float wx0 = cxw[gc*3+0], wx1 = cxw[gc*3+1], wx2 = cxw[gc*3+2];
  const float bsum = cxb[gc] + chb[gc];
  const int ic = tid >> 3, col = tid & 7;
  const size_t dg = (size_t)b*2048 + row*256 + tid;
  float c_reg = c0[dg];
  h_lds[tid] = h0[dg];
  __syncthreads();
  for (int t = 0; t < 64; ++t){
    if (tid < 8) x_lds[tid] = x_flat[((size_t)b*64 + t)*64 + row*8 + tid];
    __syncthreads();
    float g8[8];
    #pragma unroll
    for (int c2 = 0; c2 < 8; ++c2) g8[c2] = 0.f;
    #pragma unroll
    for (int icl = 0; icl < 16; ++icl){
      const int icg = ih*16 + icl;
      f32x4v hv0 = *reinterpret_cast<const f32x4v*>(&h_lds[icg*8]);
      f32x4v hv1 = *reinterpret_cast<const f32x4v*>(&h_lds[icg*8 + 4]);
      const float hv[8] = {hv0[0],hv0[1],hv0[2],hv0[3],hv1[0],hv1[1],hv1[2],hv1[3]};
      #pragma unroll
      for (int c2 = 0; c2 < 8; ++c2){
        float s = hv[c2] * wh[icl][1];
        if (c2 > 0) s += hv[c2-1] * wh[icl][0];
        if (c2 < 7) s += hv[c2+1] * wh[icl][2];
        g8[c2] += s;
      }
    }
    if (ih == 0){
      #pragma unroll
      for (int c2 = 0; c2 < 8; ++c2){
        float s = x_lds[c2] * wx1 + bsum;
        if (c2 > 0) s += x_lds[c2-1] * wx0;
        if (c2 < 7) s += x_lds[c2+1] * wx2;
        g8[c2] += s;
      }
    }
    #pragma unroll
    for (int c2 = 0; c2 < 8; ++c2) P[gc][ih][c2] = g8[c2];
    __syncthreads();
    const float ipre = P[ic   ][0][col] + P[ic   ][1][col];
    const float fpre = P[ic+32][0][col] + P[ic+32][1][col];
    const float opre = P[ic+64][0][col] + P[ic+64][1][col];
    const float gpre = P[ic+96][0][col] + P[ic+96][1][col];
    const float cn = sigmoidf_(fpre)*c_reg + sigmoidf_(ipre)*tanhf(gpre);
    c_reg = cn;
    const float hn = sigmoidf_(opre)*tanhf(cn);
    h_lds[tid] = hn;
    const unsigned short hh = f2bf(hn);
    hrawHi[((size_t)t*128 + b)*2048 + row*256 + tid] = hh;
    hrawLo[((size_t)t*128 + b)*2048 + row*256 + tid] = f2bf(hn - bf2f(hh));
    __syncthreads();
  }
}

// ---------------------------------------------------------------------------
// Layer-1 ConvLSTM for one step. Block=(b,row). Also acts as the epilogue of
// the layer-0 fuse-GEMM: hr0 = tanh(sum(partials)+sa_b0) is this cell's x.
// ---------------------------------------------------------------------------
__global__ __launch_bounds__(256) void k_cell1(
    const float* __restrict__ partials,   // [16][128][2048]
    const float* __restrict__ sab0,       // [2048]
    const float* __restrict__ h_src, const float* __restrict__ c_src,
    float* __restrict__ hB, float* __restrict__ cB,
    const unsigned short* __restrict__ wp,   // [128][32][6] bf16
    const float* __restrict__ cxb, const float* __restrict__ chb,
    unsigned short* __restrict__ r0Hi, unsigned short* __restrict__ r0Lo, // hist [T][B][2048]
    unsigned short* __restrict__ hrw1Hi, unsigned short* __restrict__ hrw1Lo, // [B][2048]
    const int t)
{
  const int b = blockIdx.x >> 3, row = blockIdx.x & 7;
  const int tid = threadIdx.x;
  __shared__ float x_lds[256];
  __shared__ float h_lds[256];
  __shared__ float P[128][2][8];
  __shared__ unsigned short wlds[128*32*6];
  const size_t dg = (size_t)b*2048 + row*256 + tid;
  {
    float y = 0.f;
    #pragma unroll
    for (int p = 0; p < 16; ++p) y += partials[(size_t)p*BD + dg];
    const float hr0 = tanhf(y + sab0[row*256 + tid]);
    x_lds[tid] = hr0;
    const unsigned short hh = f2bf(hr0);
    r0Hi[(size_t)t*BD + dg] = hh;
    r0Lo[(size_t)t*BD + dg] = f2bf(hr0 - bf2f(hh));
    h_lds[tid] = h_src[dg];
  }
  for (int i = tid; i < 128*32*6; i += 256) wlds[i] = wp[i];
  __syncthreads();
  {
    const int gc = tid >> 1, ih = tid & 1;
    float g8[8];
    #pragma unroll
    for (int c2 = 0; c2 < 8; ++c2) g8[c2] = 0.f;
    #pragma unroll
    for (int icl = 0; icl < 16; ++icl){
      const int icg = ih*16 + icl;
      f32x4v hv0 = *reinterpret_cast<const f32x4v*>(&h_lds[icg*8]);
      f32x4v hv1 = *reinterpret_cast<const f32x4v*>(&h_lds[icg*8 + 4]);
      f32x4v xv0 = *reinterpret_cast<const f32x4v*>(&x_lds[icg*8]);
      f32x4v xv1 = *reinterpret_cast<const f32x4v*>(&x_lds[icg*8 + 4]);
      const float hv[8] = {hv0[0],hv0[1],hv0[2],hv0[3],hv1[0],hv1[1],hv1[2],hv1[3]};
      const float xv[8] = {xv0[0],xv0[1],xv0[2],xv0[3],xv1[0],xv1[1],xv1[2],xv1[3]};
      const unsigned short* wq = &wlds[(gc*32 + icg)*6];
      const float wh0 = bf2f(wq[0]), wh1 = bf2f(wq[1]), wh2 = bf2f(wq[2]);
      const float wx0 = bf2f(wq[3]), wx1 = bf2f(wq[4]), wx2 = bf2f(wq[5]);
      #pragma unroll
      for (int c2 = 0; c2 < 8; ++c2){
        float s = hv[c2]*wh1 + xv[c2]*wx1;
        if (c2 > 0) s += hv[c2-1]*wh0 + xv[c2-1]*wx0;
        if (c2 < 7) s += hv[c2+1]*wh2 + xv[c2+1]*wx2;
        g8[c2] += s;
      }
    }
    #pragma unroll
    for (int c2 = 0; c2 < 8; ++c2) P[gc][ih][c2] = g8[c2];
  }
  __syncthreads();
  {
    const int ic = tid >> 3, col = tid & 7;
    const float ipre = P[ic   ][0][col] + P[ic   ][1][col] + cxb[ic]    + chb[ic];
    const float fpre = P[ic+32][0][col] + P[ic+32][1][col] + cxb[ic+32] + chb[ic+32];
    const float opre = P[ic+64][0][col] + P[ic+64][1][col] + cxb[ic+64] + chb[ic+64];
    const float gpre = P[ic+96][0][col] + P[ic+96][1][col] + cxb[ic+96] + chb[ic+96];
    const float c_old = c_src[dg];
    const float cn = sigmoidf_(fpre)*c_old + sigmoidf_(ipre)*tanhf(gpre);
    cB[dg] = cn;
    const float hraw = sigmoidf_(opre)*tanhf(cn);
    hB[dg] = hraw;
    const unsigned short hh = f2bf(hraw);
    hrw1Hi[dg] = hh;
    hrw1Lo[dg] = f2bf(hraw - bf2f(hh));
  }
}

// ---------------------------------------------------------------------------
// Inter-attention: single-pass online softmax over S=128 encoder rows.
// Block per batch b, 512 threads = 8 waves, each wave 16 rows.
// ---------------------------------------------------------------------------
__global__ __launch_bounds__(512) void k_inter(
    const unsigned short* __restrict__ encBf,   // [B][128][2048] bf16
    const float* __restrict__ stF,              // state f32 [B][2048] or null
    const unsigned short* __restrict__ stHi, const unsigned short* __restrict__ stLo,
    unsigned short* __restrict__ ctxHi, unsigned short* __restrict__ ctxLo)
{
  const int b = blockIdx.x;
  const int tid = threadIdx.x;
  const int lane = tid & 63, wv = tid >> 6;
  __shared__ float ctx_lds[2048];
  __shared__ float mw[8];
  __shared__ float lw[8];
  float sv[32], av[32];
  #pragma unroll
  for (int p = 0; p < 4; ++p){
    const int d = (p*64 + lane)*8;
    if (stF){
      f32x4v v0 = *reinterpret_cast<const f32x4v*>(stF + (size_t)b*2048 + d);
      f32x4v v1 = *reinterpret_cast<const f32x4v*>(stF + (size_t)b*2048 + d + 4);
      #pragma unroll
      for (int j = 0; j < 4; ++j){ sv[p*8+j] = v0[j]; sv[p*8+4+j] = v1[j]; }
    } else {
      u16x8 hh = *reinterpret_cast<const u16x8*>(stHi + (size_t)b*2048 + d);
      u16x8 ll = *reinterpret_cast<const u16x8*>(stLo + (size_t)b*2048 + d);
      #pragma unroll
      for (int j = 0; j < 8; ++j) sv[p*8+j] = bf2f(hh[j]) + bf2f(ll[j]);
    }
    #pragma unroll
    for (int j = 0; j < 8; ++j) av[p*8+j] = 0.f;
  }
  float m = -INFINITY, l = 0.f;
  for (int s = wv; s < 128; s += 8){
    const unsigned short* er = encBf + ((size_t)b*128 + s)*2048;
    float ef[32];
    float dot = 0.f;
    #pragma unroll
    for (int p = 0; p < 4; ++p){
      u16x8 ev = *reinterpret_cast<const u16x8*>(er + (p*64 + lane)*8);
      #pragma unroll
      for (int j = 0; j < 8; ++j){ const float e = bf2f(ev[j]); ef[p*8+j] = e; dot += e * sv[p*8+j]; }
    }
    #pragma unroll
    for (int off = 1; off < 64; off <<= 1) dot += __shfl_xor(dot, off);
    if (dot > m){
      const float sc = __expf(m - dot);
      l *= sc;
      #pragma unroll
      for (int r = 0; r < 32; ++r) av[r] *= sc;
      m = dot;
    }
    const float pp = __expf(dot - m);
    l += pp;
    #pragma unroll
    for (int r = 0; r < 32; ++r) av[r] += pp * ef[r];
  }
  for (int i = tid; i < 2048; i += 512) ctx_lds[i] = 0.f;
  if (lane == 0){ mw[wv] = m; lw[wv] = l; }
  __syncthreads();
  float M = mw[0];
  #pragma unroll
  for (int i = 1; i < 8; ++i) M = fmaxf(M, mw[i]);
  float L = 0.f;
  #pragma unroll
  for (int i = 0; i < 8; ++i) L += lw[i] * __expf(mw[i] - M);
  const float u = __expf(m - M);
  #pragma unroll
  for (int p = 0; p < 4; ++p){
    const int d = (p*64 + lane)*8;
    #pragma unroll
    for (int j = 0; j < 8; ++j) atomicAdd(&ctx_lds[d + j], u * av[p*8+j]);
  }
  __syncthreads();
  const float Linv = 1.f / L;
  for (int i = tid; i < 2048; i += 512){
    const float v = ctx_lds[i] * Linv;
    const unsigned short hh = f2bf(v);
    ctxHi[(size_t)b*2048 + i] = hh;
    ctxLo[(size_t)b*2048 + i] = f2bf(v - bf2f(hh));
  }
}

// ---------------------------------------------------------------------------
// Fuse GEMM: y = [A0|A1](128x4096) @ W(4096x2048) via bf16x3 MFMA, split-K=16.
// Writes f32 partials [16][128][2048]. W given as hi/lo planes [2048 n][4096 k].
// ---------------------------------------------------------------------------
__global__ __launch_bounds__(256) void k_gemm(
    const unsigned short* __restrict__ a0Hi, const unsigned short* __restrict__ a0Lo,
    const unsigned short* __restrict__ a1Hi, const unsigned short* __restrict__ a1Lo,
    const unsigned short* __restrict__ wHi,  const unsigned short* __restrict__ wLo,
    float* __restrict__ partials)
{
  const int tileN = blockIdx.x;    // 0..31, 64 cols each
  const int kc    = blockIdx.y;    // 0..15, 256 K each
  const int lane  = threadIdx.x & 63;
  const int wv    = threadIdx.x >> 6;
  const int half  = kc >> 3;
  const unsigned short* aHi = half ? a1Hi : a0Hi;
  const unsigned short* aLo = half ? a1Lo : a0Lo;
  const int rowA   = wv*32 + (lane & 31);
  const int kb     = lane >> 5;
  const int klocal = (kc & 7)*256 + kb*8;
  const int kglob  = kc*256 + kb*8;
  const unsigned short* pAH = aHi + (size_t)rowA*2048 + klocal;
  const unsigned short* pAL = aLo + (size_t)rowA*2048 + klocal;
  const int n0 = tileN*64 + (lane & 31);
  const unsigned short* pB0H = wHi + (size_t)n0*4096 + kglob;
  const unsigned short* pB0L = wLo + (size_t)n0*4096 + kglob;
  const unsigned short* pB1H = pB0H + (size_t)32*4096;
  const unsigned short* pB1L = pB0L + (size_t)32*4096;
  f32x16 acc0, acc1;
  #pragma unroll
  for (int r = 0; r < 16; ++r){ acc0[r] = 0.f; acc1[r] = 0.f; }
  #pragma unroll 4
  for (int s = 0; s < 16; ++s){
    bf16x8 ah  = *reinterpret_cast<const bf16x8*>(pAH  + s*16);
    bf16x8 al  = *reinterpret_cast<const bf16x8*>(pAL  + s*16);
    bf16x8 b0h = *reinterpret_cast<const bf16x8*>(pB0H + s*16);
    bf16x8 b0l = *reinterpret_cast<const bf16x8*>(pB0L + s*16);
    bf16x8 b1h = *reinterpret_cast<const bf16x8*>(pB1H + s*16);
    bf16x8 b1l = *reinterpret_cast<const bf16x8*>(pB1L + s*16);
    acc0 = __builtin_amdgcn_mfma_f32_32x32x16_bf16(ah, b0h, acc0, 0, 0, 0);
    acc1 = __builtin_amdgcn_mfma_f32_32x32x16_bf16(ah, b1h, acc1, 0, 0, 0);
    acc0 = __builtin_amdgcn_mfma_f32_32x32x16_bf16(al, b0h, acc0, 0, 0, 0);
    acc1 = __builtin_amdgcn_mfma_f32_32x32x16_bf16(al, b1h, acc1, 0, 0, 0);
    acc0 = __builtin_amdgcn_mfma_f32_32x32x16_bf16(ah, b0l, acc0, 0, 0, 0);
    acc1 = __builtin_amdgcn_mfma_f32_32x32x16_bf16(ah, b1l, acc1, 0, 0, 0);
  }
  float* outp = partials + (size_t)kc*BD + (size_t)(tileN*64 + (lane & 31));
  const int rowBase = wv*32 + 4*kb;
  #pragma unroll
  for (int r = 0; r < 16; ++r){
    const int rr = rowBase + (r & 3) + 8*(r >> 2);
    outp[(size_t)rr*2048]      = acc0[r];
    outp[(size_t)rr*2048 + 32] = acc1[r];
  }
}

// ---------------------------------------------------------------------------
// Self-attention + epilogue of the inter fuse-GEMM. Block per b.
// hi = tanh(sum(partials)+bias); scores vs refined hist (hi+lo = ~f32);
// softmax over i<t; sctx from pre-hist (bf16). Writes p[t], state-lo, sctx.
// ---------------------------------------------------------------------------
__global__ __launch_bounds__(256) void k_self(
    const float* __restrict__ partials,
    const float* __restrict__ bias,
    unsigned short* __restrict__ pHist,     // [T][B][2048]; slot t written here
    const unsigned short* __restrict__ rHi, const unsigned short* __restrict__ rLo,
    unsigned short* __restrict__ stLo,      // lo plane of hi-state [B][2048]
    unsigned short* __restrict__ sctxHi, unsigned short* __restrict__ sctxLo,
    const int t)
{
  const int b = blockIdx.x;
  const int tid = threadIdx.x;
  __shared__ float hi_lds[2048];
  __shared__ float sc[64];
  __shared__ float a_lds[64];
  #pragma unroll
  for (int j = 0; j < 8; ++j){
    const int d = tid + 256*j;
    float y = 0.f;
    #pragma unroll
    for (int p = 0; p < 16; ++p) y += partials[(size_t)p*BD + (size_t)b*2048 + d];
    const float h = tanhf(y + bias[d]);
    hi_lds[d] = h;
    const unsigned short hh = f2bf(h);
    pHist[((size_t)t*128 + b)*2048 + d] = hh;
    stLo[(size_t)b*2048 + d] = f2bf(h - bf2f(hh));
  }
  __syncthreads();
  const int lane = tid & 63, wv = tid >> 6;
  for (int i = wv; i < t; i += 4){
    const unsigned short* rh = rHi + ((size_t)i*128 + b)*2048;
    const unsigned short* rl = rLo + ((size_t)i*128 + b)*2048;
    float dot = 0.f;
    for (int j = 0; j < 32; ++j){
      const int d = lane + 64*j;
      dot += (bf2f(rh[d]) + bf2f(rl[d])) * hi_lds[d];
    }
    #pragma unroll
    for (int off = 1; off < 64; off <<= 1) dot += __shfl_xor(dot, off);
    if (lane == 0) sc[i] = dot;
  }
  __syncthreads();
  if (t > 0){
    if (tid < 64){
      const float s = (tid < t) ? sc[tid] : -INFINITY;
      float mm = s;
      #pragma unroll
      for (int off = 1; off < 64; off <<= 1) mm = fmaxf(mm, __shfl_xor(mm, off));
      const float e = (tid < t) ? __expf(s - mm) : 0.f;
      float sum = e;
      #pragma unroll
      for (int off = 1; off < 64; off <<= 1) sum += __shfl_xor(sum, off);
      a_lds[tid] = e / sum;
    }
    __syncthreads();
    #pragma unroll
    for (int j = 0; j < 8; ++j){
      const int d = tid + 256*j;
      float acc = 0.f;
      for (int i = 0; i < t; ++i)
        acc += a_lds[i] * bf2f(pHist[((size_t)i*128 + b)*2048 + d]);
      const unsigned short hh = f2bf(acc);
      sctxHi[(size_t)b*2048 + d] = hh;
      sctxLo[(size_t)b*2048 + d] = f2bf(acc - bf2f(hh));
    }
  } else {
    #pragma unroll
    for (int j = 0; j < 8; ++j){
      const int d = tid + 256*j;
      sctxHi[(size_t)b*2048 + d] = 0;
      sctxLo[(size_t)b*2048 + d] = 0;
    }
  }
}

// epilogue of layer-1 self fuse-GEMM: hr1 -> refined history (hi/lo)
__global__ __launch_bounds__(256) void k_epi(
    const float* __restrict__ partials, const float* __restrict__ bias,
    unsigned short* __restrict__ rHi, unsigned short* __restrict__ rLo, const int t)
{
  const int b = blockIdx.x, tid = threadIdx.x;
  #pragma unroll
  for (int j = 0; j < 8; ++j){
    const int d = tid + 256*j;
    float y = 0.f;
    #pragma unroll
    for (int p = 0; p < 16; ++p) y += partials[(size_t)p*BD + (size_t)b*2048 + d];
    const float h = tanhf(y + bias[d]);
    const unsigned short hh = f2bf(h);
    rHi[((size_t)t*128 + b)*2048 + d] = hh;
    rLo[((size_t)t*128 + b)*2048 + d] = f2bf(h - bf2f(hh));
  }
}

// ---------------------------------------------------------------------------
// Head stage 1: z1 = relu(r1(8192x2048) @ hw1 + hb1), bf16x3 MFMA, N padded 224
// ---------------------------------------------------------------------------
__global__ __launch_bounds__(256) void k_headgemm(
    const unsigned short* __restrict__ aHi, const unsigned short* __restrict__ aLo,
    const unsigned short* __restrict__ wHi, const unsigned short* __restrict__ wLo, // [224][2048]
    const float* __restrict__ hb1,
    float* __restrict__ z1)   // [8192][224]
{
  const int mb = blockIdx.x;   // 0..63 (128 rows each)
  const int nt = blockIdx.y;   // 0..6
  const int lane = threadIdx.x & 63, wv = threadIdx.x >> 6;
  const int rowA = mb*128 + wv*32 + (lane & 31);
  const int kb = lane >> 5;
  const int n = nt*32 + (lane & 31);
  const unsigned short* pAH = aHi + (size_t)rowA*2048 + kb*8;
  const unsigned short* pAL = aLo + (size_t)rowA*2048 + kb*8;
  const unsigned short* pBH = wHi + (size_t)n*2048 + kb*8;
  const unsigned short* pBL = wLo + (size_t)n*2048 + kb*8;
  f32x16 acc;
  #pragma unroll
  for (int r = 0; r < 16; ++r) acc[r] = 0.f;
  #pragma unroll 4
  for (int s = 0; s < 128; ++s){
    bf16x8 ah = *reinterpret_cast<const bf16x8*>(pAH + s*16);
    bf16x8 al = *reinterpret_cast<const bf16x8*>(pAL + s*16);
    bf16x8 bh = *reinterpret_cast<const bf16x8*>(pBH + s*16);
    bf16x8 bl = *reinterpret_cast<const bf16x8*>(pBL + s*16);
    acc = __builtin_amdgcn_mfma_f32_32x32x16_bf16(ah, bh, acc, 0, 0, 0);
    acc = __builtin_amdgcn_mfma_f32_32x32x16_bf16(al, bh, acc, 0, 0, 0);
    acc = __builtin_amdgcn_mfma_f32_32x32x16_bf16(ah, bl, acc, 0, 0, 0);
  }
  const float bias = (n < 200) ? hb1[n] : 0.f;
  const int rowBase = mb*128 + wv*32 + 4*kb;
  #pragma unroll
  for (int r = 0; r < 16; ++r){
    const int rr = rowBase + (r & 3) + 8*(r >> 2);
    z1[(size_t)rr*224 + n] = fmaxf(acc[r] + bias, 0.f);
  }
}

// Head stage 2: z2 = relu(z1 @ hw2 + hb2); logits = z2 @ hw3 + hb3
__global__ __launch_bounds__(256) void k_head2(
    const float* __restrict__ z1,   // [8192][224]
    const float* __restrict__ hw2, const float* __restrict__ hb2,   // [200][50],[50]
    const float* __restrict__ hw3, const float* __restrict__ hb3,   // [50][2],[2]
    float* __restrict__ out)        // [128][64][2]
{
  const int r0 = blockIdx.x * 64;
  const int tid = threadIdx.x;
  __shared__ float zl[64][200];
  __shared__ float z2[64][50];
  for (int i = tid; i < 64*200; i += 256){
    const int r = i / 200, n = i % 200;
    zl[r][n] = z1[(size_t)(r0 + r)*224 + n];
  }
  __syncthreads();
  for (int i = tid; i < 64*50; i += 256){
    const int r = i / 50, n = i % 50;
    float s = hb2[n];
    for (int k = 0; k < 200; ++k) s += zl[r][k] * hw2[k*50 + n];
    z2[r][n] = fmaxf(s, 0.f);
  }
  __syncthreads();
  for (int i = tid; i < 128; i += 256){
    const int r = i >> 1, c = i & 1;
    float s = hb3[c];
    for (int k = 0; k < 50; ++k) s += z2[r][k] * hw3[k*2 + c];
    const int rg = r0 + r;
    const int tt = rg >> 7, b = rg & 127;    // rows are [t][b]
    out[(size_t)b*128 + tt*2 + c] = s;
  }
}

// ---------------------------------------------------------------------------
extern "C" void kernel_launch(void* const* d_in, const int* in_sizes, int n_in,
                              void* d_out, int out_size, void* d_ws, size_t ws_size,
                              hipStream_t stream)
{
  (void)in_sizes; (void)n_in; (void)out_size; (void)ws_size;
  const float* x_flat = (const float*)d_in[0];
  const float* enc    = (const float*)d_in[1];
  const float* h0     = (const float*)d_in[2];
  const float* c0     = (const float*)d_in[3];
  const float* cx_w0  = (const float*)d_in[4];
  const float* cx_b0  = (const float*)d_in[5];
  const float* ch_w0  = (const float*)d_in[6];
  const float* ch_b0  = (const float*)d_in[7];
  const float* cx_w1  = (const float*)d_in[8];
  const float* cx_b1  = (const float*)d_in[9];
  const float* ch_w1  = (const float*)d_in[10];
  const float* ch_b1  = (const float*)d_in[11];
  const float* ia_w0  = (const float*)d_in[12];
  const float* ia_b0  = (const float*)d_in[13];
  const float* sa_w0  = (const float*)d_in[14];
  const float* sa_b0  = (const float*)d_in[15];
  const float* ia_w1  = (const float*)d_in[16];
  const float* ia_b1  = (const float*)d_in[17];
  const float* sa_w1  = (const float*)d_in[18];
  const float* sa_b1  = (const float*)d_in[19];
  const float* hw1    = (const float*)d_in[20];
  const float* hb1    = (const float*)d_in[21];
  const float* hw2    = (const float*)d_in[22];
  const float* hb2    = (const float*)d_in[23];
  const float* hw3    = (const float*)d_in[24];
  const float* hb3    = (const float*)d_in[25];
  float* out = (float*)d_out;

  char* ws = (char*)d_ws;
  size_t off = 0;
  auto alloc = [&](size_t bytes) -> char* {
    char* p = ws + off;
    off += (bytes + 255) & ~(size_t)255;
    return p;
  };
  const size_t WPLANE = (size_t)2048*4096*2;   // one bf16 weight plane
  unsigned short* wIa0Hi = (unsigned short*)alloc(WPLANE);
  unsigned short* wIa0Lo = (unsigned short*)alloc(WPLANE);
  unsigned short* wSa0Hi = (unsigned short*)alloc(WPLANE);
  unsigned short* wSa0Lo = (unsigned short*)alloc(WPLANE);
  unsigned short* wIa1Hi = (unsigned short*)alloc(WPLANE);
  unsigned short* wIa1Lo = (unsigned short*)alloc(WPLANE);
  unsigned short* wSa1Hi = (unsigned short*)alloc(WPLANE);
  unsigned short* wSa1Lo = (unsigned short*)alloc(WPLANE);
  unsigned short* w1Hi   = (unsigned short*)alloc((size_t)224*2048*2);
  unsigned short* w1Lo   = (unsigned short*)alloc((size_t)224*2048*2);
  unsigned short* encBf  = (unsigned short*)alloc((size_t)128*128*2048*2);
  unsigned short* hr0AHi = (unsigned short*)alloc((size_t)64*BD*2);
  unsigned short* hr0ALo = (unsigned short*)alloc((size_t)64*BD*2);
  unsigned short* p0     = (unsigned short*)alloc((size_t)64*BD*2);
  unsigned short* p1     = (unsigned short*)alloc((size_t)64*BD*2);
  unsigned short* r0Hi   = (unsigned short*)alloc((size_t)64*BD*2);
  unsigned short* r0Lo   = (unsigned short*)alloc((size_t)64*BD*2);
  unsigned short* r1Hi   = (unsigned short*)alloc((size_t)64*BD*2);
  unsigned short* r1Lo   = (unsigned short*)alloc((size_t)64*BD*2);
  float*          partials = (float*)alloc((size_t)16*BD*4);
  unsigned short* ctxHi  = (unsigned short*)alloc((size_t)BD*2);
  unsigned short* ctxLo  = (unsigned short*)alloc((size_t)BD*2);
  unsigned short* hiLo   = (unsigned short*)alloc((size_t)BD*2);
  unsigned short* sctxHi = (unsigned short*)alloc((size_t)BD*2);
  unsigned short* sctxLo = (unsigned short*)alloc((size_t)BD*2);
  unsigned short* hrw1Hi = (unsigned short*)alloc((size_t)BD*2);
  unsigned short* hrw1Lo = (unsigned short*)alloc((size_t)BD*2);
  float*          hB     = (float*)alloc((size_t)BD*4);
  float*          cB     = (float*)alloc((size_t)BD*4);
  unsigned short* wpack1 = (unsigned short*)alloc((size_t)128*32*6*2);
  float*          z1     = (float*)alloc((size_t)8192*224*4);
  // total ws use: ~479 MiB

  // ---- prologue -----------------------------------------------------------
  k_transpose_split<<<dim3(64,128),256,0,stream>>>(ia_w0, wIa0Hi, wIa0Lo, 4096, 2048, 2048);
  k_transpose_split<<<dim3(64,128),256,0,stream>>>(sa_w0, wSa0Hi, wSa0Lo, 4096, 2048, 2048);
  k_transpose_split<<<dim3(64,128),256,0,stream>>>(ia_w1, wIa1Hi, wIa1Lo, 4096, 2048, 2048);
  k_transpose_split<<<dim3(64,128),256,0,stream>>>(sa_w1, wSa1Hi, wSa1Lo, 4096, 2048, 2048);
  k_transpose_split<<<dim3(7,64),256,0,stream>>>(hw1, w1Hi, w1Lo, 2048, 200, 224);
  k_f32_to_bf16<<<(128*128*2048/4 + 255)/256, 256, 0, stream>>>(enc, encBf, 128*128*2048/4);
  k_pack_cellw<<<16,256,0,stream>>>(ch_w1, cx_w1, wpack1);
  k_cell0<<<1024,256,0,stream>>>(x_flat, h0, c0, cx_w0, cx_b0, ch_w0, ch_b0, hr0AHi, hr0ALo);

  // ---- 64 sequential steps ------------------------------------------------
  for (int t = 0; t < 64; ++t){
    const size_t tb = (size_t)t * BD;
    // layer 0
    k_inter<<<128,512,0,stream>>>(encBf, nullptr, hr0AHi + tb, hr0ALo + tb, ctxHi, ctxLo);
    k_gemm<<<dim3(32,16),256,0,stream>>>(hr0AHi + tb, hr0ALo + tb, ctxHi, ctxLo,
                                         wIa0Hi, wIa0Lo, partials);
    k_self<<<128,256,0,stream>>>(partials, ia_b0, p0, r0Hi, r0Lo, hiLo, sctxHi, sctxLo, t);
    k_gemm<<<dim3(32,16),256,0,stream>>>(p0 + tb, hiLo, sctxHi, sctxLo,
                                         wSa0Hi, wSa0Lo, partials);
    // layer 1 cell (also fuse0b epilogue -> hr0)
    k_cell1<<<1024,256,0,stream>>>(partials, sa_b0,
        (t == 0) ? (h0 + (size_t)128*2048) : hB,
        (t == 0) ? (c0 + (size_t)128*2048) : cB,
        hB, cB, wpack1, cx_b1, ch_b1, r0Hi, r0Lo, hrw1Hi, hrw1Lo, t);
    // layer 1
    k_inter<<<128,512,0,stream>>>(encBf, hB, nullptr, nullptr, ctxHi, ctxLo);
    k_gemm<<<dim3(32,16),256,0,stream>>>(hrw1Hi, hrw1Lo, ctxHi, ctxLo,
                                         wIa1Hi, wIa1Lo, partials);
    k_self<<<128,256,0,stream>>>(partials, ia_b1, p1, r1Hi, r1Lo, hiLo, sctxHi, sctxLo, t);
    k_gemm<<<dim3(32,16),256,0,stream>>>(p1 + tb, hiLo, sctxHi, sctxLo,
                                         wSa1Hi, wSa1Lo, partials);
    k_epi<<<128,256,0,stream>>>(partials, sa_b1, r1Hi, r1Lo, t);
  }

  // ---- head (batched over all t,b) ----------------------------------------
  k_headgemm<<<dim3(64,7),256,0,stream>>>(r1Hi, r1Lo, w1Hi, w1Lo, hb1, z1);
  k_head2<<<128,256,0,stream>>>(z1, hw2, hb2, hw3, hb3, out);
}

// Round 2
// 12406.180 us; speedup vs baseline: 1.8789x; 1.8789x over previous
//
#include <hip/hip_runtime.h>
#include <math.h>

// ---------------------------------------------------------------------------
// CLSADecoder: 2-layer RowSharedConvLSTM + inter-attn + causal self-attn + head
// B=128, T=64, D=2048 (ROWS=8, CH=32, COLS=8), S=128.
// R1 changes: LDS-staged swizzled k_gemm (coalesced W reads, split-K 8),
// vectorized k_self (u16x8), parallel deterministic k_inter (512 blocks +
// combine kernel).
// ---------------------------------------------------------------------------

typedef __bf16 bf16x8 __attribute__((ext_vector_type(8)));
typedef float  f32x16 __attribute__((ext_vector_type(16)));
typedef float  f32x4v __attribute__((ext_vector_type(4)));
typedef unsigned short u16x8 __attribute__((ext_vector_type(8)));
typedef unsigned short u16x4 __attribute__((ext_vector_type(4)));

#define BD 262144   // 128*2048  (one [B][D] plane)
#define NPART 8     // split-K planes

__device__ __forceinline__ unsigned short f2bf(float x){
  unsigned int u = __builtin_bit_cast(unsigned int, x);
  u += 0x7fffu + ((u >> 16) & 1u);          // round-to-nearest-even
  return (unsigned short)(u >> 16);
}
__device__ __forceinline__ float bf2f(unsigned short h){
  unsigned int u = ((unsigned int)h) << 16;
  return __builtin_bit_cast(float, u);
}
__device__ __forceinline__ float sigmoidf_(float x){
  return 1.0f / (1.0f + __expf(-x));
}

// ---------------------------------------------------------------------------
// Prologue: transpose+split f32 weight [K][N] -> bf16 hi/lo planes [Npad][K]
// ---------------------------------------------------------------------------
__global__ __launch_bounds__(256) void k_transpose_split(
    const float* __restrict__ src, unsigned short* __restrict__ dhi,
    unsigned short* __restrict__ dlo, const int K, const int N, const int Npad)
{
  __shared__ float tile[32][33];
  const int n0 = blockIdx.x * 32, k0 = blockIdx.y * 32;
  const int tx = threadIdx.x & 31, ty = threadIdx.x >> 5;   // ty in [0,8)
  #pragma unroll
  for (int ii = 0; ii < 4; ++ii){
    const int k = k0 + ty + ii*8, n = n0 + tx;
    float v = (n < N) ? src[(size_t)k * N + n] : 0.0f;
    tile[ty + ii*8][tx] = v;
  }
  __syncthreads();
  #pragma unroll
  for (int ii = 0; ii < 4; ++ii){
    const int n = n0 + ty + ii*8, k = k0 + tx;
    const float v = tile[tx][ty + ii*8];
    const unsigned short h = f2bf(v);
    dhi[(size_t)n * K + k] = h;
    dlo[(size_t)n * K + k] = f2bf(v - bf2f(h));
  }
}

__global__ void k_f32_to_bf16(const float* __restrict__ src,
                              unsigned short* __restrict__ dst, const int n4)
{
  const int i = blockIdx.x * 256 + threadIdx.x;
  if (i < n4){
    f32x4v v = *reinterpret_cast<const f32x4v*>(src + (size_t)i * 4);
    u16x4 o;
    #pragma unroll
    for (int j = 0; j < 4; ++j) o[j] = f2bf(v[j]);
    *reinterpret_cast<u16x4*>(dst + (size_t)i * 4) = o;
  }
}

// pack cell1 conv weights: [128][32][3] ch + [128][32][3] cx -> bf16 [128][32][6]
__global__ void k_pack_cellw(const float* __restrict__ chw,
                             const float* __restrict__ cxw,
                             unsigned short* __restrict__ wp)
{
  const int i = blockIdx.x * 256 + threadIdx.x;
  if (i < 128 * 32){
    #pragma unroll
    for (int k = 0; k < 3; ++k){
      wp[i*6 + k]     = f2bf(chw[i*3 + k]);
      wp[i*6 + 3 + k] = f2bf(cxw[i*3 + k]);
    }
  }
}

// ---------------------------------------------------------------------------
// Layer-0 ConvLSTM for ALL 64 steps (independent of attention).
// ---------------------------------------------------------------------------
__global__ __launch_bounds__(256) void k_cell0(
    const float* __restrict__ x_flat,                       // [B][T][64]
    const float* __restrict__ h0, const float* __restrict__ c0,
    const float* __restrict__ cxw, const float* __restrict__ cxb,
    const float* __restrict__ chw, const float* __restrict__ chb,
    unsigned short* __restrict__ hrawHi, unsigned short* __restrict__ hrawLo) // [T][B][2048]
{
  const int b = blockIdx.x >> 3, row = blockIdx.x & 7;
  const int tid = threadIdx.x;
  __shared__ float h_lds[256];
  __shared__ float x_lds[8];
  __shared__ float P[128][2][8];
  const int gc = tid >> 1, ih = tid & 1;
  float wh[16][3];
  #pragma unroll
  for (int icl = 0; icl < 16; ++icl)
    #pragma unroll
    for (int k = 0; k < 3; ++k)
      wh[icl][k] = chw[(gc*32 + ih*16 + icl)*3 + k];
  const float wx0 = cxw[gc*3+0], wx1 = cxw[gc*3+1], wx2 = cxw[gc*3+2];
  const float bsum = cxb[gc] + chb[gc];
  const int ic = tid >> 3, col = tid & 7;
  const size_t dg = (size_t)b*2048 + row*256 + tid;
  float c_reg = c0[dg];
  h_lds[tid] = h0[dg];
  __syncthreads();
  for (int t = 0; t < 64; ++t){
    if (tid < 8) x_lds[tid] = x_flat[((size_t)b*64 + t)*64 + row*8 + tid];
    __syncthreads();
    float g8[8];
    #pragma unroll
    for (int c2 = 0; c2 < 8; ++c2) g8[c2] = 0.f;
    #pragma unroll
    for (int icl = 0; icl < 16; ++icl){
      const int icg = ih*16 + icl;
      f32x4v hv0 = *reinterpret_cast<const f32x4v*>(&h_lds[icg*8]);
      f32x4v hv1 = *reinterpret_cast<const f32x4v*>(&h_lds[icg*8 + 4]);
      const float hv[8] = {hv0[0],hv0[1],hv0[2],hv0[3],hv1[0],hv1[1],hv1[2],hv1[3]};
      #pragma unroll
      for (int c2 = 0; c2 < 8; ++c2){
        float s = hv[c2] * wh[icl][1];
        if (c2 > 0) s += hv[c2-1] * wh[icl][0];
        if (c2 < 7) s += hv[c2+1] * wh[icl][2];
        g8[c2] += s;
      }
    }
    if (ih == 0){
      #pragma unroll
      for (int c2 = 0; c2 < 8; ++c2){
        float s = x_lds[c2] * wx1 + bsum;
        if (c2 > 0) s += x_lds[c2-1] * wx0;
        if (c2 < 7) s += x_lds[c2+1] * wx2;
        g8[c2] += s;
      }
    }
    #pragma unroll
    for (int c2 = 0; c2 < 8; ++c2) P[gc][ih][c2] = g8[c2];
    __syncthreads();
    const float ipre = P[ic   ][0][col] + P[ic   ][1][col];
    const float fpre = P[ic+32][0][col] + P[ic+32][1][col];
    const float opre = P[ic+64][0][col] + P[ic+64][1][col];
    const float gpre = P[ic+96][0][col] + P[ic+96][1][col];
    const float cn = sigmoidf_(fpre)*c_reg + sigmoidf_(ipre)*tanhf(gpre);
    c_reg = cn;
    const float hn = sigmoidf_(opre)*tanhf(cn);
    h_lds[tid] = hn;
    const unsigned short hh = f2bf(hn);
    hrawHi[((size_t)t*128 + b)*2048 + row*256 + tid] = hh;
    hrawLo[((size_t)t*128 + b)*2048 + row*256 + tid] = f2bf(hn - bf2f(hh));
    __syncthreads();
  }
}

// ---------------------------------------------------------------------------
// Layer-1 ConvLSTM for one step (also epilogue of the layer-0 sa fuse-GEMM).
// ---------------------------------------------------------------------------
__global__ __launch_bounds__(256) void k_cell1(
    const float* __restrict__ partials,   // [NPART][128][2048]
    const float* __restrict__ sab0,
    const float* __restrict__ h_src, const float* __restrict__ c_src,
    float* __restrict__ hB, float* __restrict__ cB,
    const unsigned short* __restrict__ wp,
    const float* __restrict__ cxb, const float* __restrict__ chb,
    unsigned short* __restrict__ r0Hi, unsigned short* __restrict__ r0Lo,
    unsigned short* __restrict__ hrw1Hi, unsigned short* __restrict__ hrw1Lo,
    const int t)
{
  const int b = blockIdx.x >> 3, row = blockIdx.x & 7;
  const int tid = threadIdx.x;
  __shared__ float x_lds[256];
  __shared__ float h_lds[256];
  __shared__ float P[128][2][8];
  __shared__ unsigned short wlds[128*32*6];
  const size_t dg = (size_t)b*2048 + row*256 + tid;
  {
    float y = 0.f;
    #pragma unroll
    for (int p = 0; p < NPART; ++p) y += partials[(size_t)p*BD + dg];
    const float hr0 = tanhf(y + sab0[row*256 + tid]);
    x_lds[tid] = hr0;
    const unsigned short hh = f2bf(hr0);
    r0Hi[(size_t)t*BD + dg] = hh;
    r0Lo[(size_t)t*BD + dg] = f2bf(hr0 - bf2f(hh));
    h_lds[tid] = h_src[dg];
  }
  for (int i = tid; i < 128*32*6; i += 256) wlds[i] = wp[i];
  __syncthreads();
  {
    const int gc = tid >> 1, ih = tid & 1;
    float g8[8];
    #pragma unroll
    for (int c2 = 0; c2 < 8; ++c2) g8[c2] = 0.f;
    #pragma unroll
    for (int icl = 0; icl < 16; ++icl){
      const int icg = ih*16 + icl;
      f32x4v hv0 = *reinterpret_cast<const f32x4v*>(&h_lds[icg*8]);
      f32x4v hv1 = *reinterpret_cast<const f32x4v*>(&h_lds[icg*8 + 4]);
      f32x4v xv0 = *reinterpret_cast<const f32x4v*>(&x_lds[icg*8]);
      f32x4v xv1 = *reinterpret_cast<const f32x4v*>(&x_lds[icg*8 + 4]);
      const float hv[8] = {hv0[0],hv0[1],hv0[2],hv0[3],hv1[0],hv1[1],hv1[2],hv1[3]};
      const float xv[8] = {xv0[0],xv0[1],xv0[2],xv0[3],xv1[0],xv1[1],xv1[2],xv1[3]};
      const unsigned short* wq = &wlds[(gc*32 + icg)*6];
      const float wh0 = bf2f(wq[0]), wh1 = bf2f(wq[1]), wh2 = bf2f(wq[2]);
      const float wx0 = bf2f(wq[3]), wx1 = bf2f(wq[4]), wx2 = bf2f(wq[5]);
      #pragma unroll
      for (int c2 = 0; c2 < 8; ++c2){
        float s = hv[c2]*wh1 + xv[c2]*wx1;
        if (c2 > 0) s += hv[c2-1]*wh0 + xv[c2-1]*wx0;
        if (c2 < 7) s += hv[c2+1]*wh2 + xv[c2+1]*wx2;
        g8[c2] += s;
      }
    }
    #pragma unroll
    for (int c2 = 0; c2 < 8; ++c2) P[gc][ih][c2] = g8[c2];
  }
  __syncthreads();
  {
    const int ic = tid >> 3, col = tid & 7;
    const float ipre = P[ic   ][0][col] + P[ic   ][1][col] + cxb[ic]    + chb[ic];
    const float fpre = P[ic+32][0][col] + P[ic+32][1][col] + cxb[ic+32] + chb[ic+32];
    const float opre = P[ic+64][0][col] + P[ic+64][1][col] + cxb[ic+64] + chb[ic+64];
    const float gpre = P[ic+96][0][col] + P[ic+96][1][col] + cxb[ic+96] + chb[ic+96];
    const float c_old = c_src[dg];
    const float cn = sigmoidf_(fpre)*c_old + sigmoidf_(ipre)*tanhf(gpre);
    cB[dg] = cn;
    const float hraw = sigmoidf_(opre)*tanhf(cn);
    hB[dg] = hraw;
    const unsigned short hh = f2bf(hraw);
    hrw1Hi[dg] = hh;
    hrw1Lo[dg] = f2bf(hraw - bf2f(hh));
  }
}

// ---------------------------------------------------------------------------
// Inter-attention part 1: block=(b, sc) handles 32 encoder rows, online
// softmax per wave, deterministic LDS reduction. Writes unnormalized partial
// ctx (f32) + per-block (m, l).
// ---------------------------------------------------------------------------
__global__ __launch_bounds__(256) void k_inter_part(
    const unsigned short* __restrict__ encBf,   // [B][128][2048] bf16
    const float* __restrict__ stF,              // state f32 [B][2048] or null
    const unsigned short* __restrict__ stHi, const unsigned short* __restrict__ stLo,
    float* __restrict__ pctx, float* __restrict__ pm, float* __restrict__ pl)
{
  const int b = blockIdx.x, sc = blockIdx.y;
  const int tid = threadIdx.x;
  const int lane = tid & 63, wv = tid >> 6;
  __shared__ float wav[4][2048];
  __shared__ float wm[4], wl[4];
  float sv[32], av[32];
  #pragma unroll
  for (int p = 0; p < 4; ++p){
    const int d = (p*64 + lane)*8;
    if (stF){
      f32x4v v0 = *reinterpret_cast<const f32x4v*>(stF + (size_t)b*2048 + d);
      f32x4v v1 = *reinterpret_cast<const f32x4v*>(stF + (size_t)b*2048 + d + 4);
      #pragma unroll
      for (int j = 0; j < 4; ++j){ sv[p*8+j] = v0[j]; sv[p*8+4+j] = v1[j]; }
    } else {
      u16x8 hh = *reinterpret_cast<const u16x8*>(stHi + (size_t)b*2048 + d);
      u16x8 ll = *reinterpret_cast<const u16x8*>(stLo + (size_t)b*2048 + d);
      #pragma unroll
      for (int j = 0; j < 8; ++j) sv[p*8+j] = bf2f(hh[j]) + bf2f(ll[j]);
    }
    #pragma unroll
    for (int j = 0; j < 8; ++j) av[p*8+j] = 0.f;
  }
  float m = -INFINITY, l = 0.f;
  const int s0 = sc*32 + wv*8;
  for (int r = 0; r < 8; ++r){
    const unsigned short* er = encBf + ((size_t)b*128 + s0 + r)*2048;
    float ef[32];
    float dot = 0.f;
    #pragma unroll
    for (int p = 0; p < 4; ++p){
      u16x8 ev = *reinterpret_cast<const u16x8*>(er + (p*64 + lane)*8);
      #pragma unroll
      for (int j = 0; j < 8; ++j){ const float e = bf2f(ev[j]); ef[p*8+j] = e; dot += e * sv[p*8+j]; }
    }
    #pragma unroll
    for (int off = 1; off < 64; off <<= 1) dot += __shfl_xor(dot, off);
    if (dot > m){
      const float scf = __expf(m - dot);
      l *= scf;
      #pragma unroll
      for (int q = 0; q < 32; ++q) av[q] *= scf;
      m = dot;
    }
    const float pp = __expf(dot - m);
    l += pp;
    #pragma unroll
    for (int q = 0; q < 32; ++q) av[q] += pp * ef[q];
  }
  // deterministic block combine
  #pragma unroll
  for (int p = 0; p < 4; ++p){
    const int d = (p*64 + lane)*8;
    f32x4v v0, v1;
    #pragma unroll
    for (int j = 0; j < 4; ++j){ v0[j] = av[p*8+j]; v1[j] = av[p*8+4+j]; }
    *reinterpret_cast<f32x4v*>(&wav[wv][d]) = v0;
    *reinterpret_cast<f32x4v*>(&wav[wv][d+4]) = v1;
  }
  if (lane == 0){ wm[wv] = m; wl[wv] = l; }
  __syncthreads();
  float M = fmaxf(fmaxf(wm[0], wm[1]), fmaxf(wm[2], wm[3]));
  float u0 = __expf(wm[0]-M), u1 = __expf(wm[1]-M), u2 = __expf(wm[2]-M), u3 = __expf(wm[3]-M);
  const float Lb = wl[0]*u0 + wl[1]*u1 + wl[2]*u2 + wl[3]*u3;
  const int d0 = tid*8;
  f32x4v c0, c1;
  #pragma unroll
  for (int j = 0; j < 4; ++j){ c0[j] = 0.f; c1[j] = 0.f; }
  {
    f32x4v a0 = *reinterpret_cast<const f32x4v*>(&wav[0][d0]);
    f32x4v a1 = *reinterpret_cast<const f32x4v*>(&wav[0][d0+4]);
    f32x4v b0 = *reinterpret_cast<const f32x4v*>(&wav[1][d0]);
    f32x4v b1 = *reinterpret_cast<const f32x4v*>(&wav[1][d0+4]);
    f32x4v e0 = *reinterpret_cast<const f32x4v*>(&wav[2][d0]);
    f32x4v e1 = *reinterpret_cast<const f32x4v*>(&wav[2][d0+4]);
    f32x4v g0 = *reinterpret_cast<const f32x4v*>(&wav[3][d0]);
    f32x4v g1 = *reinterpret_cast<const f32x4v*>(&wav[3][d0+4]);
    #pragma unroll
    for (int j = 0; j < 4; ++j){
      c0[j] = u0*a0[j] + u1*b0[j] + u2*e0[j] + u3*g0[j];
      c1[j] = u0*a1[j] + u1*b1[j] + u2*e1[j] + u3*g1[j];
    }
  }
  float* po = pctx + ((size_t)b*4 + sc)*2048 + d0;
  *reinterpret_cast<f32x4v*>(po) = c0;
  *reinterpret_cast<f32x4v*>(po + 4) = c1;
  if (tid == 0){ pm[b*4 + sc] = M; pl[b*4 + sc] = Lb; }
}

// Inter-attention part 2: combine 4 partials -> ctx hi/lo bf16
__global__ __launch_bounds__(256) void k_inter_comb(
    const float* __restrict__ pctx, const float* __restrict__ pm,
    const float* __restrict__ pl,
    unsigned short* __restrict__ ctxHi, unsigned short* __restrict__ ctxLo)
{
  const int b = blockIdx.x, tid = threadIdx.x;
  const float m0 = pm[b*4+0], m1 = pm[b*4+1], m2 = pm[b*4+2], m3 = pm[b*4+3];
  const float M = fmaxf(fmaxf(m0, m1), fmaxf(m2, m3));
  const float u0 = __expf(m0-M), u1 = __expf(m1-M), u2 = __expf(m2-M), u3 = __expf(m3-M);
  const float L = pl[b*4+0]*u0 + pl[b*4+1]*u1 + pl[b*4+2]*u2 + pl[b*4+3]*u3;
  const float Linv = 1.f / L;
  const int d0 = tid*8;
  const float* p0 = pctx + ((size_t)b*4 + 0)*2048 + d0;
  const float* p1 = pctx + ((size_t)b*4 + 1)*2048 + d0;
  const float* p2 = pctx + ((size_t)b*4 + 2)*2048 + d0;
  const float* p3 = pctx + ((size_t)b*4 + 3)*2048 + d0;
  float v[8];
  #pragma unroll
  for (int h = 0; h < 2; ++h){
    f32x4v a = *reinterpret_cast<const f32x4v*>(p0 + h*4);
    f32x4v bb = *reinterpret_cast<const f32x4v*>(p1 + h*4);
    f32x4v c = *reinterpret_cast<const f32x4v*>(p2 + h*4);
    f32x4v d = *reinterpret_cast<const f32x4v*>(p3 + h*4);
    #pragma unroll
    for (int j = 0; j < 4; ++j)
      v[h*4+j] = (u0*a[j] + u1*bb[j] + u2*c[j] + u3*d[j]) * Linv;
  }
  u16x8 hh, ll;
  #pragma unroll
  for (int j = 0; j < 8; ++j){
    hh[j] = f2bf(v[j]);
    ll[j] = f2bf(v[j] - bf2f(hh[j]));
  }
  *reinterpret_cast<u16x8*>(ctxHi + (size_t)b*2048 + d0) = hh;
  *reinterpret_cast<u16x8*>(ctxLo + (size_t)b*2048 + d0) = ll;
}

// ---------------------------------------------------------------------------
// Fuse GEMM: y = [A0|A1](128x4096) @ W(4096x2048), bf16x3 MFMA, LDS-staged.
// Grid (32 n-tiles of 64, 8 k-chunks of 512). XOR-swizzled LDS layout,
// reg-staged with loads issued ahead of compute. W read exactly once/call.
// ---------------------------------------------------------------------------
__global__ __launch_bounds__(256) void k_gemm(
    const unsigned short* __restrict__ a0Hi, const unsigned short* __restrict__ a0Lo,
    const unsigned short* __restrict__ a1Hi, const unsigned short* __restrict__ a1Lo,
    const unsigned short* __restrict__ wHi,  const unsigned short* __restrict__ wLo,
    float* __restrict__ partials)
{
  const int nt = blockIdx.x;        // 64-col tile
  const int kc = blockIdx.y;        // 512-k chunk
  const int tid = threadIdx.x;
  const int lane = tid & 63, wv = tid >> 6;
  // 48 KB: aH [0,16K) aL [16K,32K) bH [32K,40K) bL [40K,48K) bytes
  __shared__ __align__(16) unsigned short lds[24576];
  const unsigned short* aH = (kc < 4) ? a0Hi : a1Hi;
  const unsigned short* aL = (kc < 4) ? a0Lo : a1Lo;
  const int kA = (kc & 3) * 512;
  const unsigned short* wH = wHi + (size_t)(nt*64)*4096 + kc*512;
  const unsigned short* wL = wLo + (size_t)(nt*64)*4096 + kc*512;

  u16x8 rga[4], rgb[4], rgw[2], rgx[2];
  auto loads = [&](int ki){
    #pragma unroll
    for (int i = 0; i < 4; ++i){
      const int c = i*256 + tid, row = c >> 3;
      const int srcb = ((c & 7)*16) ^ ((row & 7) << 4);
      rga[i] = *reinterpret_cast<const u16x8*>((const char*)(aH + (size_t)row*2048 + kA + ki) + srcb);
      rgb[i] = *reinterpret_cast<const u16x8*>((const char*)(aL + (size_t)row*2048 + kA + ki) + srcb);
    }
    #pragma unroll
    for (int i = 0; i < 2; ++i){
      const int c = i*256 + tid, row = c >> 3;
      const int srcb = ((c & 7)*16) ^ ((row & 7) << 4);
      rgw[i] = *reinterpret_cast<const u16x8*>((const char*)(wH + (size_t)row*4096 + ki) + srcb);
      rgx[i] = *reinterpret_cast<const u16x8*>((const char*)(wL + (size_t)row*4096 + ki) + srcb);
    }
  };
  auto writes = [&](){
    #pragma unroll
    for (int i = 0; i < 4; ++i){
      *reinterpret_cast<u16x8*>((char*)lds + (i*256+tid)*16) = rga[i];
      *reinterpret_cast<u16x8*>((char*)lds + 16384 + (i*256+tid)*16) = rgb[i];
    }
    #pragma unroll
    for (int i = 0; i < 2; ++i){
      *reinterpret_cast<u16x8*>((char*)lds + 32768 + (i*256+tid)*16) = rgw[i];
      *reinterpret_cast<u16x8*>((char*)lds + 40960 + (i*256+tid)*16) = rgx[i];
    }
  };

  f32x16 acc0, acc1;
  #pragma unroll
  for (int r = 0; r < 16; ++r){ acc0[r] = 0.f; acc1[r] = 0.f; }
  const int rA = wv*32 + (lane & 31);
  const int kb = lane >> 5;
  const int rB0 = lane & 31;
  const int aswz = (rA & 7) << 4;
  const int bswz = (rB0 & 7) << 4;

  loads(0); writes();
  __syncthreads();
  for (int ki = 0; ki < 8; ++ki){
    if (ki < 7) loads((ki+1)*64);
    #pragma unroll
    for (int s = 0; s < 4; ++s){
      const int cb = s*32 + kb*16;
      bf16x8 ah  = *reinterpret_cast<const bf16x8*>((const char*)lds + rA*128 + (cb ^ aswz));
      bf16x8 al  = *reinterpret_cast<const bf16x8*>((const char*)lds + 16384 + rA*128 + (cb ^ aswz));
      bf16x8 b0h = *reinterpret_cast<const bf16x8*>((const char*)lds + 32768 + rB0*128 + (cb ^ bswz));
      bf16x8 b0l = *reinterpret_cast<const bf16x8*>((const char*)lds + 40960 + rB0*128 + (cb ^ bswz));
      bf16x8 b1h = *reinterpret_cast<const bf16x8*>((const char*)lds + 32768 + 4096 + rB0*128 + (cb ^ bswz));
      bf16x8 b1l = *reinterpret_cast<const bf16x8*>((const char*)lds + 40960 + 4096 + rB0*128 + (cb ^ bswz));
      acc0 = __builtin_amdgcn_mfma_f32_32x32x16_bf16(ah, b0h, acc0, 0, 0, 0);
      acc1 = __builtin_amdgcn_mfma_f32_32x32x16_bf16(ah, b1h, acc1, 0, 0, 0);
      acc0 = __builtin_amdgcn_mfma_f32_32x32x16_bf16(al, b0h, acc0, 0, 0, 0);
      acc1 = __builtin_amdgcn_mfma_f32_32x32x16_bf16(al, b1h, acc1, 0, 0, 0);
      acc0 = __builtin_amdgcn_mfma_f32_32x32x16_bf16(ah, b0l, acc0, 0, 0, 0);
      acc1 = __builtin_amdgcn_mfma_f32_32x32x16_bf16(ah, b1l, acc1, 0, 0, 0);
    }
    __syncthreads();
    if (ki < 7){ writes(); __syncthreads(); }
  }

  float* outp = partials + (size_t)kc*BD + (size_t)(nt*64 + (lane & 31));
  const int rowBase = wv*32 + 4*kb;
  #pragma unroll
  for (int r = 0; r < 16; ++r){
    const int rr = rowBase + (r & 3) + 8*(r >> 2);
    outp[(size_t)rr*2048]      = acc0[r];
    outp[(size_t)rr*2048 + 32] = acc1[r];
  }
}

// ---------------------------------------------------------------------------
// Self-attention + epilogue of the inter fuse-GEMM (vectorized).
// ---------------------------------------------------------------------------
__global__ __launch_bounds__(256) void k_self(
    const float* __restrict__ partials,
    const float* __restrict__ bias,
    unsigned short* __restrict__ pHist,
    const unsigned short* __restrict__ rHi, const unsigned short* __restrict__ rLo,
    unsigned short* __restrict__ stLo,
    unsigned short* __restrict__ sctxHi, unsigned short* __restrict__ sctxLo,
    const int t)
{
  const int b = blockIdx.x;
  const int tid = threadIdx.x;
  __shared__ float hi_lds[2048];
  __shared__ float sc[64];
  __shared__ float a_lds[64];
  const int d0 = tid*8;
  // phase A: sum partials, tanh, publish state
  {
    f32x4v y0, y1;
    #pragma unroll
    for (int j = 0; j < 4; ++j){ y0[j] = 0.f; y1[j] = 0.f; }
    #pragma unroll
    for (int p = 0; p < NPART; ++p){
      const float* pp = partials + (size_t)p*BD + (size_t)b*2048 + d0;
      f32x4v v0 = *reinterpret_cast<const f32x4v*>(pp);
      f32x4v v1 = *reinterpret_cast<const f32x4v*>(pp + 4);
      #pragma unroll
      for (int j = 0; j < 4; ++j){ y0[j] += v0[j]; y1[j] += v1[j]; }
    }
    f32x4v bb0 = *reinterpret_cast<const f32x4v*>(bias + d0);
    f32x4v bb1 = *reinterpret_cast<const f32x4v*>(bias + d0 + 4);
    float h[8];
    #pragma unroll
    for (int j = 0; j < 4; ++j){ h[j] = tanhf(y0[j] + bb0[j]); h[4+j] = tanhf(y1[j] + bb1[j]); }
    f32x4v h0, h1;
    #pragma unroll
    for (int j = 0; j < 4; ++j){ h0[j] = h[j]; h1[j] = h[4+j]; }
    *reinterpret_cast<f32x4v*>(&hi_lds[d0]) = h0;
    *reinterpret_cast<f32x4v*>(&hi_lds[d0+4]) = h1;
    u16x8 hh, ll;
    #pragma unroll
    for (int j = 0; j < 8; ++j){ hh[j] = f2bf(h[j]); ll[j] = f2bf(h[j] - bf2f(hh[j])); }
    *reinterpret_cast<u16x8*>(pHist + ((size_t)t*128 + b)*2048 + d0) = hh;
    *reinterpret_cast<u16x8*>(stLo + (size_t)b*2048 + d0) = ll;
  }
  __syncthreads();
  const int lane = tid & 63, wv = tid >> 6;
  // cache state slice in registers
  float hreg[32];
  #pragma unroll
  for (int jj = 0; jj < 4; ++jj){
    const int d = (jj*64 + lane)*8;
    f32x4v v0 = *reinterpret_cast<const f32x4v*>(&hi_lds[d]);
    f32x4v v1 = *reinterpret_cast<const f32x4v*>(&hi_lds[d+4]);
    #pragma unroll
    for (int j = 0; j < 4; ++j){ hreg[jj*8+j] = v0[j]; hreg[jj*8+4+j] = v1[j]; }
  }
  // phase B: scores vs refined history (hi+lo ~ f32)
  for (int i = wv; i < t; i += 4){
    const unsigned short* rh = rHi + ((size_t)i*128 + b)*2048;
    const unsigned short* rl = rLo + ((size_t)i*128 + b)*2048;
    float dot = 0.f;
    #pragma unroll
    for (int jj = 0; jj < 4; ++jj){
      const int d = (jj*64 + lane)*8;
      u16x8 h8 = *reinterpret_cast<const u16x8*>(rh + d);
      u16x8 l8 = *reinterpret_cast<const u16x8*>(rl + d);
      #pragma unroll
      for (int j = 0; j < 8; ++j)
        dot += (bf2f(h8[j]) + bf2f(l8[j])) * hreg[jj*8+j];
    }
    #pragma unroll
    for (int off = 1; off < 64; off <<= 1) dot += __shfl_xor(dot, off);
    if (lane == 0) sc[i] = dot;
  }
  __syncthreads();
  if (t > 0){
    if (tid < 64){
      const float s = (tid < t) ? sc[tid] : -INFINITY;
      float mm = s;
      #pragma unroll
      for (int off = 1; off < 64; off <<= 1) mm = fmaxf(mm, __shfl_xor(mm, off));
      const float e = (tid < t) ? __expf(s - mm) : 0.f;
      float sum = e;
      #pragma unroll
      for (int off = 1; off < 64; off <<= 1) sum += __shfl_xor(sum, off);
      a_lds[tid] = e / sum;
    }
    __syncthreads();
    float acc8[8];
    #pragma unroll
    for (int j = 0; j < 8; ++j) acc8[j] = 0.f;
    for (int i = 0; i < t; ++i){
      const float a = a_lds[i];
      u16x8 ph = *reinterpret_cast<const u16x8*>(pHist + ((size_t)i*128 + b)*2048 + d0);
      #pragma unroll
      for (int j = 0; j < 8; ++j) acc8[j] += a * bf2f(ph[j]);
    }
    u16x8 hh, ll;
    #pragma unroll
    for (int j = 0; j < 8; ++j){ hh[j] = f2bf(acc8[j]); ll[j] = f2bf(acc8[j] - bf2f(hh[j])); }
    *reinterpret_cast<u16x8*>(sctxHi + (size_t)b*2048 + d0) = hh;
    *reinterpret_cast<u16x8*>(sctxLo + (size_t)b*2048 + d0) = ll;
  } else {
    u16x8 z;
    #pragma unroll
    for (int j = 0; j < 8; ++j) z[j] = 0;
    *reinterpret_cast<u16x8*>(sctxHi + (size_t)b*2048 + d0) = z;
    *reinterpret_cast<u16x8*>(sctxLo + (size_t)b*2048 + d0) = z;
  }
}

// epilogue of layer-1 self fuse-GEMM: hr1 -> refined history (hi/lo)
__global__ __launch_bounds__(256) void k_epi(
    const float* __restrict__ partials, const float* __restrict__ bias,
    unsigned short* __restrict__ rHi, unsigned short* __restrict__ rLo, const int t)
{
  const int b = blockIdx.x, tid = threadIdx.x;
  const int d0 = tid*8;
  f32x4v y0, y1;
  #pragma unroll
  for (int j = 0; j < 4; ++j){ y0[j] = 0.f; y1[j] = 0.f; }
  #pragma unroll
  for (int p = 0; p < NPART; ++p){
    const float* pp = partials + (size_t)p*BD + (size_t)b*2048 + d0;
    f32x4v v0 = *reinterpret_cast<const f32x4v*>(pp);
    f32x4v v1 = *reinterpret_cast<const f32x4v*>(pp + 4);
    #pragma unroll
    for (int j = 0; j < 4; ++j){ y0[j] += v0[j]; y1[j] += v1[j]; }
  }
  f32x4v bb0 = *reinterpret_cast<const f32x4v*>(bias + d0);
  f32x4v bb1 = *reinterpret_cast<const f32x4v*>(bias + d0 + 4);
  u16x8 hh, ll;
  #pragma unroll
  for (int j = 0; j < 4; ++j){
    const float a = tanhf(y0[j] + bb0[j]);
    const float c = tanhf(y1[j] + bb1[j]);
    hh[j] = f2bf(a); ll[j] = f2bf(a - bf2f(hh[j]));
    hh[4+j] = f2bf(c); ll[4+j] = f2bf(c - bf2f(hh[4+j]));
  }
  *reinterpret_cast<u16x8*>(rHi + ((size_t)t*128 + b)*2048 + d0) = hh;
  *reinterpret_cast<u16x8*>(rLo + ((size_t)t*128 + b)*2048 + d0) = ll;
}

// ---------------------------------------------------------------------------
// Head stage 1: z1 = relu(r1(8192x2048) @ hw1 + hb1), bf16x3 MFMA
// ---------------------------------------------------------------------------
__global__ __launch_bounds__(256) void k_headgemm(
    const unsigned short* __restrict__ aHi, const unsigned short* __restrict__ aLo,
    const unsigned short* __restrict__ wHi, const unsigned short* __restrict__ wLo, // [224][2048]
    const float* __restrict__ hb1,
    float* __restrict__ z1)   // [8192][224]
{
  const int mb = blockIdx.x;   // 0..63 (128 rows each)
  const int nt = blockIdx.y;   // 0..6
  const int lane = threadIdx.x & 63, wv = threadIdx.x >> 6;
  const int rowA = mb*128 + wv*32 + (lane & 31);
  const int kb = lane >> 5;
  const int n = nt*32 + (lane & 31);
  const unsigned short* pAH = aHi + (size_t)rowA*2048 + kb*8;
  const unsigned short* pAL = aLo + (size_t)rowA*2048 + kb*8;
  const unsigned short* pBH = wHi + (size_t)n*2048 + kb*8;
  const unsigned short* pBL = wLo + (size_t)n*2048 + kb*8;
  f32x16 acc;
  #pragma unroll
  for (int r = 0; r < 16; ++r) acc[r] = 0.f;
  #pragma unroll 4
  for (int s = 0; s < 128; ++s){
    bf16x8 ah = *reinterpret_cast<const bf16x8*>(pAH + s*16);
    bf16x8 al = *reinterpret_cast<const bf16x8*>(pAL + s*16);
    bf16x8 bh = *reinterpret_cast<const bf16x8*>(pBH + s*16);
    bf16x8 bl = *reinterpret_cast<const bf16x8*>(pBL + s*16);
    acc = __builtin_amdgcn_mfma_f32_32x32x16_bf16(ah, bh, acc, 0, 0, 0);
    acc = __builtin_amdgcn_mfma_f32_32x32x16_bf16(al, bh, acc, 0, 0, 0);
    acc = __builtin_amdgcn_mfma_f32_32x32x16_bf16(ah, bl, acc, 0, 0, 0);
  }
  const float bias = (n < 200) ? hb1[n] : 0.f;
  const int rowBase = mb*128 + wv*32 + 4*kb;
  #pragma unroll
  for (int r = 0; r < 16; ++r){
    const int rr = rowBase + (r & 3) + 8*(r >> 2);
    z1[(size_t)rr*224 + n] = fmaxf(acc[r] + bias, 0.f);
  }
}

// Head stage 2: z2 = relu(z1 @ hw2 + hb2); logits = z2 @ hw3 + hb3
__global__ __launch_bounds__(256) void k_head2(
    const float* __restrict__ z1,   // [8192][224]
    const float* __restrict__ hw2, const float* __restrict__ hb2,
    const float* __restrict__ hw3, const float* __restrict__ hb3,
    float* __restrict__ out)        // [128][64][2]
{
  const int r0 = blockIdx.x * 64;
  const int tid = threadIdx.x;
  __shared__ float zl[64][200];
  __shared__ float z2[64][50];
  for (int i = tid; i < 64*200; i += 256){
    const int r = i / 200, n = i % 200;
    zl[r][n] = z1[(size_t)(r0 + r)*224 + n];
  }
  __syncthreads();
  for (int i = tid; i < 64*50; i += 256){
    const int r = i / 50, n = i % 50;
    float s = hb2[n];
    for (int k = 0; k < 200; ++k) s += zl[r][k] * hw2[k*50 + n];
    z2[r][n] = fmaxf(s, 0.f);
  }
  __syncthreads();
  for (int i = tid; i < 128; i += 256){
    const int r = i >> 1, c = i & 1;
    float s = hb3[c];
    for (int k = 0; k < 50; ++k) s += z2[r][k] * hw3[k*2 + c];
    const int rg = r0 + r;
    const int tt = rg >> 7, b = rg & 127;    // rows are [t][b]
    out[(size_t)b*128 + tt*2 + c] = s;
  }
}

// ---------------------------------------------------------------------------
extern "C" void kernel_launch(void* const* d_in, const int* in_sizes, int n_in,
                              void* d_out, int out_size, void* d_ws, size_t ws_size,
                              hipStream_t stream)
{
  (void)in_sizes; (void)n_in; (void)out_size; (void)ws_size;
  const float* x_flat = (const float*)d_in[0];
  const float* enc    = (const float*)d_in[1];
  const float* h0     = (const float*)d_in[2];
  const float* c0     = (const float*)d_in[3];
  const float* cx_w0  = (const float*)d_in[4];
  const float* cx_b0  = (const float*)d_in[5];
  const float* ch_w0  = (const float*)d_in[6];
  const float* ch_b0  = (const float*)d_in[7];
  const float* cx_w1  = (const float*)d_in[8];
  const float* cx_b1  = (const float*)d_in[9];
  const float* ch_w1  = (const float*)d_in[10];
  const float* ch_b1  = (const float*)d_in[11];
  const float* ia_w0  = (const float*)d_in[12];
  const float* ia_b0  = (const float*)d_in[13];
  const float* sa_w0  = (const float*)d_in[14];
  const float* sa_b0  = (const float*)d_in[15];
  const float* ia_w1  = (const float*)d_in[16];
  const float* ia_b1  = (const float*)d_in[17];
  const float* sa_w1  = (const float*)d_in[18];
  const float* sa_b1  = (const float*)d_in[19];
  const float* hw1    = (const float*)d_in[20];
  const float* hb1    = (const float*)d_in[21];
  const float* hw2    = (const float*)d_in[22];
  const float* hb2    = (const float*)d_in[23];
  const float* hw3    = (const float*)d_in[24];
  const float* hb3    = (const float*)d_in[25];
  float* out = (float*)d_out;

  char* ws = (char*)d_ws;
  size_t off = 0;
  auto alloc = [&](size_t bytes) -> char* {
    char* p = ws + off;
    off += (bytes + 255) & ~(size_t)255;
    return p;
  };
  const size_t WPLANE = (size_t)2048*4096*2;   // one bf16 weight plane
  unsigned short* wIa0Hi = (unsigned short*)alloc(WPLANE);
  unsigned short* wIa0Lo = (unsigned short*)alloc(WPLANE);
  unsigned short* wSa0Hi = (unsigned short*)alloc(WPLANE);
  unsigned short* wSa0Lo = (unsigned short*)alloc(WPLANE);
  unsigned short* wIa1Hi = (unsigned short*)alloc(WPLANE);
  unsigned short* wIa1Lo = (unsigned short*)alloc(WPLANE);
  unsigned short* wSa1Hi = (unsigned short*)alloc(WPLANE);
  unsigned short* wSa1Lo = (unsigned short*)alloc(WPLANE);
  unsigned short* w1Hi   = (unsigned short*)alloc((size_t)224*2048*2);
  unsigned short* w1Lo   = (unsigned short*)alloc((size_t)224*2048*2);
  unsigned short* encBf  = (unsigned short*)alloc((size_t)128*128*2048*2);
  unsigned short* hr0AHi = (unsigned short*)alloc((size_t)64*BD*2);
  unsigned short* hr0ALo = (unsigned short*)alloc((size_t)64*BD*2);
  unsigned short* p0     = (unsigned short*)alloc((size_t)64*BD*2);
  unsigned short* p1     = (unsigned short*)alloc((size_t)64*BD*2);
  unsigned short* r0Hi   = (unsigned short*)alloc((size_t)64*BD*2);
  unsigned short* r0Lo   = (unsigned short*)alloc((size_t)64*BD*2);
  unsigned short* r1Hi   = (unsigned short*)alloc((size_t)64*BD*2);
  unsigned short* r1Lo   = (unsigned short*)alloc((size_t)64*BD*2);
  float*          partials = (float*)alloc((size_t)NPART*BD*4);
  unsigned short* ctxHi  = (unsigned short*)alloc((size_t)BD*2);
  unsigned short* ctxLo  = (unsigned short*)alloc((size_t)BD*2);
  unsigned short* hiLo   = (unsigned short*)alloc((size_t)BD*2);
  unsigned short* sctxHi = (unsigned short*)alloc((size_t)BD*2);
  unsigned short* sctxLo = (unsigned short*)alloc((size_t)BD*2);
  unsigned short* hrw1Hi = (unsigned short*)alloc((size_t)BD*2);
  unsigned short* hrw1Lo = (unsigned short*)alloc((size_t)BD*2);
  float*          hB     = (float*)alloc((size_t)BD*4);
  float*          cB     = (float*)alloc((size_t)BD*4);
  unsigned short* wpack1 = (unsigned short*)alloc((size_t)128*32*6*2);
  float*          z1     = (float*)alloc((size_t)8192*224*4);
  float*          pctx   = (float*)alloc((size_t)512*2048*4);
  float*          pm     = (float*)alloc((size_t)512*4);
  float*          pl     = (float*)alloc((size_t)512*4);

  // ---- prologue -----------------------------------------------------------
  k_transpose_split<<<dim3(64,128),256,0,stream>>>(ia_w0, wIa0Hi, wIa0Lo, 4096, 2048, 2048);
  k_transpose_split<<<dim3(64,128),256,0,stream>>>(sa_w0, wSa0Hi, wSa0Lo, 4096, 2048, 2048);
  k_transpose_split<<<dim3(64,128),256,0,stream>>>(ia_w1, wIa1Hi, wIa1Lo, 4096, 2048, 2048);
  k_transpose_split<<<dim3(64,128),256,0,stream>>>(sa_w1, wSa1Hi, wSa1Lo, 4096, 2048, 2048);
  k_transpose_split<<<dim3(7,64),256,0,stream>>>(hw1, w1Hi, w1Lo, 2048, 200, 224);
  k_f32_to_bf16<<<(128*128*2048/4 + 255)/256, 256, 0, stream>>>(enc, encBf, 128*128*2048/4);
  k_pack_cellw<<<16,256,0,stream>>>(ch_w1, cx_w1, wpack1);
  k_cell0<<<1024,256,0,stream>>>(x_flat, h0, c0, cx_w0, cx_b0, ch_w0, ch_b0, hr0AHi, hr0ALo);

  // ---- 64 sequential steps ------------------------------------------------
  for (int t = 0; t < 64; ++t){
    const size_t tb = (size_t)t * BD;
    // layer 0
    k_inter_part<<<dim3(128,4),256,0,stream>>>(encBf, nullptr, hr0AHi + tb, hr0ALo + tb, pctx, pm, pl);
    k_inter_comb<<<128,256,0,stream>>>(pctx, pm, pl, ctxHi, ctxLo);
    k_gemm<<<dim3(32,NPART),256,0,stream>>>(hr0AHi + tb, hr0ALo + tb, ctxHi, ctxLo,
                                            wIa0Hi, wIa0Lo, partials);
    k_self<<<128,256,0,stream>>>(partials, ia_b0, p0, r0Hi, r0Lo, hiLo, sctxHi, sctxLo, t);
    k_gemm<<<dim3(32,NPART),256,0,stream>>>(p0 + tb, hiLo, sctxHi, sctxLo,
                                            wSa0Hi, wSa0Lo, partials);
    // layer 1 cell (also fuse0b epilogue -> hr0)
    k_cell1<<<1024,256,0,stream>>>(partials, sa_b0,
        (t == 0) ? (h0 + (size_t)128*2048) : hB,
        (t == 0) ? (c0 + (size_t)128*2048) : cB,
        hB, cB, wpack1, cx_b1, ch_b1, r0Hi, r0Lo, hrw1Hi, hrw1Lo, t);
    // layer 1
    k_inter_part<<<dim3(128,4),256,0,stream>>>(encBf, hB, nullptr, nullptr, pctx, pm, pl);
    k_inter_comb<<<128,256,0,stream>>>(pctx, pm, pl, ctxHi, ctxLo);
    k_gemm<<<dim3(32,NPART),256,0,stream>>>(hrw1Hi, hrw1Lo, ctxHi, ctxLo,
                                            wIa1Hi, wIa1Lo, partials);
    k_self<<<128,256,0,stream>>>(partials, ia_b1, p1, r1Hi, r1Lo, hiLo, sctxHi, sctxLo, t);
    k_gemm<<<dim3(32,NPART),256,0,stream>>>(p1 + tb, hiLo, sctxHi, sctxLo,
                                            wSa1Hi, wSa1Lo, partials);
    k_epi<<<128,256,0,stream>>>(partials, sa_b1, r1Hi, r1Lo, t);
  }

  // ---- head (batched over all t,b) ----------------------------------------
  k_headgemm<<<dim3(64,7),256,0,stream>>>(r1Hi, r1Lo, w1Hi, w1Lo, hb1, z1);
  k_head2<<<128,256,0,stream>>>(z1, hw2, hb2, hw3, hb3, out);
}

// Round 3
// 10977.982 us; speedup vs baseline: 2.1233x; 1.1301x over previous
//
#include <hip/hip_runtime.h>
#include <math.h>

// ---------------------------------------------------------------------------
// CLSADecoder: 2-layer RowSharedConvLSTM + inter-attn + causal self-attn + head
// B=128, T=64, D=2048 (ROWS=8, CH=32, COLS=8), S=128.
// R2: fuse GEMMs use f16 hi/lo A x single-f16 W (2 MFMA passes instead of 3
// bf16 passes): only error is W's f16 rounding (~1e-4/GEMM). Halves W traffic
// and cuts LDS-issue pressure. All state/history hi/lo pairs now f16.
// Inter-attention merged to a single kernel (8-wave deterministic combine).
// ---------------------------------------------------------------------------

typedef _Float16 f16;
typedef _Float16 f16x8 __attribute__((ext_vector_type(8)));
typedef _Float16 f16x4 __attribute__((ext_vector_type(4)));
typedef float  f32x16 __attribute__((ext_vector_type(16)));
typedef float  f32x4v __attribute__((ext_vector_type(4)));
typedef unsigned short u16x8 __attribute__((ext_vector_type(8)));
typedef unsigned short u16x4 __attribute__((ext_vector_type(4)));

#define BD 262144   // 128*2048  (one [B][D] plane)
#define NPART 8     // split-K planes

__device__ __forceinline__ unsigned short f2bf(float x){
  unsigned int u = __builtin_bit_cast(unsigned int, x);
  u += 0x7fffu + ((u >> 16) & 1u);          // round-to-nearest-even
  return (unsigned short)(u >> 16);
}
__device__ __forceinline__ float bf2f(unsigned short h){
  unsigned int u = ((unsigned int)h) << 16;
  return __builtin_bit_cast(float, u);
}
__device__ __forceinline__ float sigmoidf_(float x){
  return 1.0f / (1.0f + __expf(-x));
}

// ---------------------------------------------------------------------------
// Prologue: transpose f32 weight [K][N] -> f16 plane [Npad][K]
// ---------------------------------------------------------------------------
__global__ __launch_bounds__(256) void k_transpose_f16(
    const float* __restrict__ src, f16* __restrict__ dhi,
    const int K, const int N)
{
  __shared__ float tile[32][33];
  const int n0 = blockIdx.x * 32, k0 = blockIdx.y * 32;
  const int tx = threadIdx.x & 31, ty = threadIdx.x >> 5;   // ty in [0,8)
  #pragma unroll
  for (int ii = 0; ii < 4; ++ii){
    const int k = k0 + ty + ii*8, n = n0 + tx;
    float v = (n < N) ? src[(size_t)k * N + n] : 0.0f;
    tile[ty + ii*8][tx] = v;
  }
  __syncthreads();
  #pragma unroll
  for (int ii = 0; ii < 4; ++ii){
    const int n = n0 + ty + ii*8, k = k0 + tx;
    dhi[(size_t)n * K + k] = (f16)tile[tx][ty + ii*8];
  }
}

__global__ void k_f32_to_bf16(const float* __restrict__ src,
                              unsigned short* __restrict__ dst, const int n4)
{
  const int i = blockIdx.x * 256 + threadIdx.x;
  if (i < n4){
    f32x4v v = *reinterpret_cast<const f32x4v*>(src + (size_t)i * 4);
    u16x4 o;
    #pragma unroll
    for (int j = 0; j < 4; ++j) o[j] = f2bf(v[j]);
    *reinterpret_cast<u16x4*>(dst + (size_t)i * 4) = o;
  }
}

// pack cell1 conv weights: [128][32][3] ch + [128][32][3] cx -> bf16 [128][32][6]
__global__ void k_pack_cellw(const float* __restrict__ chw,
                             const float* __restrict__ cxw,
                             unsigned short* __restrict__ wp)
{
  const int i = blockIdx.x * 256 + threadIdx.x;
  if (i < 128 * 32){
    #pragma unroll
    for (int k = 0; k < 3; ++k){
      wp[i*6 + k]     = f2bf(chw[i*3 + k]);
      wp[i*6 + 3 + k] = f2bf(cxw[i*3 + k]);
    }
  }
}

// ---------------------------------------------------------------------------
// Layer-0 ConvLSTM for ALL 64 steps (independent of attention).
// ---------------------------------------------------------------------------
__global__ __launch_bounds__(256) void k_cell0(
    const float* __restrict__ x_flat,                       // [B][T][64]
    const float* __restrict__ h0, const float* __restrict__ c0,
    const float* __restrict__ cxw, const float* __restrict__ cxb,
    const float* __restrict__ chw, const float* __restrict__ chb,
    f16* __restrict__ hrawHi, f16* __restrict__ hrawLo)     // [T][B][2048]
{
  const int b = blockIdx.x >> 3, row = blockIdx.x & 7;
  const int tid = threadIdx.x;
  __shared__ float h_lds[256];
  __shared__ float x_lds[8];
  __shared__ float P[128][2][8];
  const int gc = tid >> 1, ih = tid & 1;
  float wh[16][3];
  #pragma unroll
  for (int icl = 0; icl < 16; ++icl)
    #pragma unroll
    for (int k = 0; k < 3; ++k)
      wh[icl][k] = chw[(gc*32 + ih*16 + icl)*3 + k];
  const float wx0 = cxw[gc*3+0], wx1 = cxw[gc*3+1], wx2 = cxw[gc*3+2];
  const float bsum = cxb[gc] + chb[gc];
  const int ic = tid >> 3, col = tid & 7;
  const size_t dg = (size_t)b*2048 + row*256 + tid;
  float c_reg = c0[dg];
  h_lds[tid] = h0[dg];
  __syncthreads();
  for (int t = 0; t < 64; ++t){
    if (tid < 8) x_lds[tid] = x_flat[((size_t)b*64 + t)*64 + row*8 + tid];
    __syncthreads();
    float g8[8];
    #pragma unroll
    for (int c2 = 0; c2 < 8; ++c2) g8[c2] = 0.f;
    #pragma unroll
    for (int icl = 0; icl < 16; ++icl){
      const int icg = ih*16 + icl;
      f32x4v hv0 = *reinterpret_cast<const f32x4v*>(&h_lds[icg*8]);
      f32x4v hv1 = *reinterpret_cast<const f32x4v*>(&h_lds[icg*8 + 4]);
      const float hv[8] = {hv0[0],hv0[1],hv0[2],hv0[3],hv1[0],hv1[1],hv1[2],hv1[3]};
      #pragma unroll
      for (int c2 = 0; c2 < 8; ++c2){
        float s = hv[c2] * wh[icl][1];
        if (c2 > 0) s += hv[c2-1] * wh[icl][0];
        if (c2 < 7) s += hv[c2+1] * wh[icl][2];
        g8[c2] += s;
      }
    }
    if (ih == 0){
      #pragma unroll
      for (int c2 = 0; c2 < 8; ++c2){
        float s = x_lds[c2] * wx1 + bsum;
        if (c2 > 0) s += x_lds[c2-1] * wx0;
        if (c2 < 7) s += x_lds[c2+1] * wx2;
        g8[c2] += s;
      }
    }
    #pragma unroll
    for (int c2 = 0; c2 < 8; ++c2) P[gc][ih][c2] = g8[c2];
    __syncthreads();
    const float ipre = P[ic   ][0][col] + P[ic   ][1][col];
    const float fpre = P[ic+32][0][col] + P[ic+32][1][col];
    const float opre = P[ic+64][0][col] + P[ic+64][1][col];
    const float gpre = P[ic+96][0][col] + P[ic+96][1][col];
    const float cn = sigmoidf_(fpre)*c_reg + sigmoidf_(ipre)*tanhf(gpre);
    c_reg = cn;
    const float hn = sigmoidf_(opre)*tanhf(cn);
    h_lds[tid] = hn;
    const f16 hh = (f16)hn;
    hrawHi[((size_t)t*128 + b)*2048 + row*256 + tid] = hh;
    hrawLo[((size_t)t*128 + b)*2048 + row*256 + tid] = (f16)(hn - (float)hh);
    __syncthreads();
  }
}

// ---------------------------------------------------------------------------
// Layer-1 ConvLSTM for one step (also epilogue of the layer-0 sa fuse-GEMM).
// ---------------------------------------------------------------------------
__global__ __launch_bounds__(256) void k_cell1(
    const float* __restrict__ partials,   // [NPART][128][2048]
    const float* __restrict__ sab0,
    const float* __restrict__ h_src, const float* __restrict__ c_src,
    float* __restrict__ hB, float* __restrict__ cB,
    const unsigned short* __restrict__ wp,
    const float* __restrict__ cxb, const float* __restrict__ chb,
    f16* __restrict__ r0Hi, f16* __restrict__ r0Lo,
    f16* __restrict__ hrw1Hi, f16* __restrict__ hrw1Lo,
    const int t)
{
  const int b = blockIdx.x >> 3, row = blockIdx.x & 7;
  const int tid = threadIdx.x;
  __shared__ float x_lds[256];
  __shared__ float h_lds[256];
  __shared__ float P[128][2][8];
  __shared__ unsigned short wlds[128*32*6];
  const size_t dg = (size_t)b*2048 + row*256 + tid;
  {
    float y = 0.f;
    #pragma unroll
    for (int p = 0; p < NPART; ++p) y += partials[(size_t)p*BD + dg];
    const float hr0 = tanhf(y + sab0[row*256 + tid]);
    x_lds[tid] = hr0;
    const f16 hh = (f16)hr0;
    r0Hi[(size_t)t*BD + dg] = hh;
    r0Lo[(size_t)t*BD + dg] = (f16)(hr0 - (float)hh);
    h_lds[tid] = h_src[dg];
  }
  for (int i = tid; i < 128*32*6; i += 256) wlds[i] = wp[i];
  __syncthreads();
  {
    const int gc = tid >> 1, ih = tid & 1;
    float g8[8];
    #pragma unroll
    for (int c2 = 0; c2 < 8; ++c2) g8[c2] = 0.f;
    #pragma unroll
    for (int icl = 0; icl < 16; ++icl){
      const int icg = ih*16 + icl;
      f32x4v hv0 = *reinterpret_cast<const f32x4v*>(&h_lds[icg*8]);
      f32x4v hv1 = *reinterpret_cast<const f32x4v*>(&h_lds[icg*8 + 4]);
      f32x4v xv0 = *reinterpret_cast<const f32x4v*>(&x_lds[icg*8]);
      f32x4v xv1 = *reinterpret_cast<const f32x4v*>(&x_lds[icg*8 + 4]);
      const float hv[8] = {hv0[0],hv0[1],hv0[2],hv0[3],hv1[0],hv1[1],hv1[2],hv1[3]};
      const float xv[8] = {xv0[0],xv0[1],xv0[2],xv0[3],xv1[0],xv1[1],xv1[2],xv1[3]};
      const unsigned short* wq = &wlds[(gc*32 + icg)*6];
      const float wh0 = bf2f(wq[0]), wh1 = bf2f(wq[1]), wh2 = bf2f(wq[2]);
      const float wx0 = bf2f(wq[3]), wx1 = bf2f(wq[4]), wx2 = bf2f(wq[5]);
      #pragma unroll
      for (int c2 = 0; c2 < 8; ++c2){
        float s = hv[c2]*wh1 + xv[c2]*wx1;
        if (c2 > 0) s += hv[c2-1]*wh0 + xv[c2-1]*wx0;
        if (c2 < 7) s += hv[c2+1]*wh2 + xv[c2+1]*wx2;
        g8[c2] += s;
      }
    }
    #pragma unroll
    for (int c2 = 0; c2 < 8; ++c2) P[gc][ih][c2] = g8[c2];
  }
  __syncthreads();
  {
    const int ic = tid >> 3, col = tid & 7;
    const float ipre = P[ic   ][0][col] + P[ic   ][1][col] + cxb[ic]    + chb[ic];
    const float fpre = P[ic+32][0][col] + P[ic+32][1][col] + cxb[ic+32] + chb[ic+32];
    const float opre = P[ic+64][0][col] + P[ic+64][1][col] + cxb[ic+64] + chb[ic+64];
    const float gpre = P[ic+96][0][col] + P[ic+96][1][col] + cxb[ic+96] + chb[ic+96];
    const float c_old = c_src[dg];
    const float cn = sigmoidf_(fpre)*c_old + sigmoidf_(ipre)*tanhf(gpre);
    cB[dg] = cn;
    const float hraw = sigmoidf_(opre)*tanhf(cn);
    hB[dg] = hraw;
    const f16 hh = (f16)hraw;
    hrw1Hi[dg] = hh;
    hrw1Lo[dg] = (f16)(hraw - (float)hh);
  }
}

// ---------------------------------------------------------------------------
// Inter-attention (single kernel): block per b, 512 threads = 8 waves, each
// wave 16 encoder rows, online softmax, deterministic 8-way LDS combine.
// ---------------------------------------------------------------------------
__global__ __launch_bounds__(512) void k_inter(
    const unsigned short* __restrict__ encBf,   // [B][128][2048] bf16
    const float* __restrict__ stF,              // state f32 [B][2048] or null
    const f16* __restrict__ stHi, const f16* __restrict__ stLo,
    f16* __restrict__ ctxHi, f16* __restrict__ ctxLo)
{
  const int b = blockIdx.x;
  const int tid = threadIdx.x;
  const int lane = tid & 63, wv = tid >> 6;
  __shared__ float wav[8][2048];
  __shared__ float wm[8], wl[8];
  float sv[32], av[32];
  #pragma unroll
  for (int p = 0; p < 4; ++p){
    const int d = (p*64 + lane)*8;
    if (stF){
      f32x4v v0 = *reinterpret_cast<const f32x4v*>(stF + (size_t)b*2048 + d);
      f32x4v v1 = *reinterpret_cast<const f32x4v*>(stF + (size_t)b*2048 + d + 4);
      #pragma unroll
      for (int j = 0; j < 4; ++j){ sv[p*8+j] = v0[j]; sv[p*8+4+j] = v1[j]; }
    } else {
      f16x8 hh = *reinterpret_cast<const f16x8*>(stHi + (size_t)b*2048 + d);
      f16x8 ll = *reinterpret_cast<const f16x8*>(stLo + (size_t)b*2048 + d);
      #pragma unroll
      for (int j = 0; j < 8; ++j) sv[p*8+j] = (float)hh[j] + (float)ll[j];
    }
    #pragma unroll
    for (int j = 0; j < 8; ++j) av[p*8+j] = 0.f;
  }
  float m = -INFINITY, l = 0.f;
  const int s0 = wv*16;
  for (int r = 0; r < 16; ++r){
    const unsigned short* er = encBf + ((size_t)b*128 + s0 + r)*2048;
    float ef[32];
    float dot = 0.f;
    #pragma unroll
    for (int p = 0; p < 4; ++p){
      u16x8 ev = *reinterpret_cast<const u16x8*>(er + (p*64 + lane)*8);
      #pragma unroll
      for (int j = 0; j < 8; ++j){ const float e = bf2f(ev[j]); ef[p*8+j] = e; dot += e * sv[p*8+j]; }
    }
    #pragma unroll
    for (int off = 1; off < 64; off <<= 1) dot += __shfl_xor(dot, off);
    if (dot > m){
      const float scf = __expf(m - dot);
      l *= scf;
      #pragma unroll
      for (int q = 0; q < 32; ++q) av[q] *= scf;
      m = dot;
    }
    const float pp = __expf(dot - m);
    l += pp;
    #pragma unroll
    for (int q = 0; q < 32; ++q) av[q] += pp * ef[q];
  }
  #pragma unroll
  for (int p = 0; p < 4; ++p){
    const int d = (p*64 + lane)*8;
    f32x4v v0, v1;
    #pragma unroll
    for (int j = 0; j < 4; ++j){ v0[j] = av[p*8+j]; v1[j] = av[p*8+4+j]; }
    *reinterpret_cast<f32x4v*>(&wav[wv][d]) = v0;
    *reinterpret_cast<f32x4v*>(&wav[wv][d+4]) = v1;
  }
  if (lane == 0){ wm[wv] = m; wl[wv] = l; }
  __syncthreads();
  float M = wm[0];
  #pragma unroll
  for (int i = 1; i < 8; ++i) M = fmaxf(M, wm[i]);
  float U[8];
  float L = 0.f;
  #pragma unroll
  for (int i = 0; i < 8; ++i){ U[i] = __expf(wm[i] - M); L += wl[i] * U[i]; }
  const float Linv = 1.f / L;
  const int d0 = tid * 4;
  float acc[4] = {0.f, 0.f, 0.f, 0.f};
  #pragma unroll
  for (int w = 0; w < 8; ++w){
    f32x4v v = *reinterpret_cast<const f32x4v*>(&wav[w][d0]);
    #pragma unroll
    for (int j = 0; j < 4; ++j) acc[j] += U[w] * v[j];
  }
  f16x4 hh, ll;
  #pragma unroll
  for (int j = 0; j < 4; ++j){
    const float v = acc[j] * Linv;
    hh[j] = (f16)v;
    ll[j] = (f16)(v - (float)hh[j]);
  }
  *reinterpret_cast<f16x4*>(ctxHi + (size_t)b*2048 + d0) = hh;
  *reinterpret_cast<f16x4*>(ctxLo + (size_t)b*2048 + d0) = ll;
}

// ---------------------------------------------------------------------------
// Fuse GEMM: y = [A0|A1](128x4096) @ W(4096x2048), f16 2-pass MFMA (A hi/lo x
// single-f16 W). LDS-staged, XOR-swizzled. Grid (32 n-tiles, 8 k-chunks).
// ---------------------------------------------------------------------------
__global__ __launch_bounds__(256) void k_gemm(
    const f16* __restrict__ a0Hi, const f16* __restrict__ a0Lo,
    const f16* __restrict__ a1Hi, const f16* __restrict__ a1Lo,
    const f16* __restrict__ wHp,
    float* __restrict__ partials)
{
  const int nt = blockIdx.x;        // 64-col tile
  const int kc = blockIdx.y;        // 512-k chunk
  const int tid = threadIdx.x;
  const int lane = tid & 63, wv = tid >> 6;
  // 40 KB: aH [0,16K) aL [16K,32K) W [32K,40K) bytes
  __shared__ __align__(16) unsigned short lds[20480];
  const f16* aH = (kc < 4) ? a0Hi : a1Hi;
  const f16* aL = (kc < 4) ? a0Lo : a1Lo;
  const int kA = (kc & 3) * 512;
  const f16* wH = wHp + (size_t)(nt*64)*4096 + kc*512;

  u16x8 rga[4], rgb[4], rgw[2];
  auto loads = [&](int ki){
    #pragma unroll
    for (int i = 0; i < 4; ++i){
      const int c = i*256 + tid, row = c >> 3;
      const int srcb = ((c & 7)*16) ^ ((row & 7) << 4);
      rga[i] = *reinterpret_cast<const u16x8*>((const char*)(aH + (size_t)row*2048 + kA + ki) + srcb);
      rgb[i] = *reinterpret_cast<const u16x8*>((const char*)(aL + (size_t)row*2048 + kA + ki) + srcb);
    }
    #pragma unroll
    for (int i = 0; i < 2; ++i){
      const int c = i*256 + tid, row = c >> 3;
      const int srcb = ((c & 7)*16) ^ ((row & 7) << 4);
      rgw[i] = *reinterpret_cast<const u16x8*>((const char*)(wH + (size_t)row*4096 + ki) + srcb);
    }
  };
  auto writes = [&](){
    #pragma unroll
    for (int i = 0; i < 4; ++i){
      *reinterpret_cast<u16x8*>((char*)lds + (i*256+tid)*16) = rga[i];
      *reinterpret_cast<u16x8*>((char*)lds + 16384 + (i*256+tid)*16) = rgb[i];
    }
    #pragma unroll
    for (int i = 0; i < 2; ++i){
      *reinterpret_cast<u16x8*>((char*)lds + 32768 + (i*256+tid)*16) = rgw[i];
    }
  };

  f32x16 acc0, acc1;
  #pragma unroll
  for (int r = 0; r < 16; ++r){ acc0[r] = 0.f; acc1[r] = 0.f; }
  const int rA = wv*32 + (lane & 31);
  const int kb = lane >> 5;
  const int rB0 = lane & 31;
  const int aswz = (rA & 7) << 4;
  const int bswz = (rB0 & 7) << 4;

  loads(0); writes();
  __syncthreads();
  for (int ki = 0; ki < 8; ++ki){
    if (ki < 7) loads((ki+1)*64);
    #pragma unroll
    for (int s = 0; s < 4; ++s){
      const int cb = s*32 + kb*16;
      f16x8 ah  = *reinterpret_cast<const f16x8*>((const char*)lds + rA*128 + (cb ^ aswz));
      f16x8 al  = *reinterpret_cast<const f16x8*>((const char*)lds + 16384 + rA*128 + (cb ^ aswz));
      f16x8 b0h = *reinterpret_cast<const f16x8*>((const char*)lds + 32768 + rB0*128 + (cb ^ bswz));
      f16x8 b1h = *reinterpret_cast<const f16x8*>((const char*)lds + 32768 + 4096 + rB0*128 + (cb ^ bswz));
      acc0 = __builtin_amdgcn_mfma_f32_32x32x16_f16(ah, b0h, acc0, 0, 0, 0);
      acc1 = __builtin_amdgcn_mfma_f32_32x32x16_f16(ah, b1h, acc1, 0, 0, 0);
      acc0 = __builtin_amdgcn_mfma_f32_32x32x16_f16(al, b0h, acc0, 0, 0, 0);
      acc1 = __builtin_amdgcn_mfma_f32_32x32x16_f16(al, b1h, acc1, 0, 0, 0);
    }
    __syncthreads();
    if (ki < 7){ writes(); __syncthreads(); }
  }

  float* outp = partials + (size_t)kc*BD + (size_t)(nt*64 + (lane & 31));
  const int rowBase = wv*32 + 4*kb;
  #pragma unroll
  for (int r = 0; r < 16; ++r){
    const int rr = rowBase + (r & 3) + 8*(r >> 2);
    outp[(size_t)rr*2048]      = acc0[r];
    outp[(size_t)rr*2048 + 32] = acc1[r];
  }
}

// ---------------------------------------------------------------------------
// Self-attention + epilogue of the inter fuse-GEMM (vectorized, f16 hists).
// ---------------------------------------------------------------------------
__global__ __launch_bounds__(256) void k_self(
    const float* __restrict__ partials,
    const float* __restrict__ bias,
    f16* __restrict__ pHist,                      // [T][B][2048] f16 hi
    const f16* __restrict__ rHi, const f16* __restrict__ rLo,
    f16* __restrict__ stLo,                       // current-t lo plane
    f16* __restrict__ sctxHi, f16* __restrict__ sctxLo,
    const int t)
{
  const int b = blockIdx.x;
  const int tid = threadIdx.x;
  __shared__ float hi_lds[2048];
  __shared__ float sc[64];
  __shared__ float a_lds[64];
  const int d0 = tid*8;
  // phase A: sum partials, tanh, publish state
  {
    f32x4v y0, y1;
    #pragma unroll
    for (int j = 0; j < 4; ++j){ y0[j] = 0.f; y1[j] = 0.f; }
    #pragma unroll
    for (int p = 0; p < NPART; ++p){
      const float* pp = partials + (size_t)p*BD + (size_t)b*2048 + d0;
      f32x4v v0 = *reinterpret_cast<const f32x4v*>(pp);
      f32x4v v1 = *reinterpret_cast<const f32x4v*>(pp + 4);
      #pragma unroll
      for (int j = 0; j < 4; ++j){ y0[j] += v0[j]; y1[j] += v1[j]; }
    }
    f32x4v bb0 = *reinterpret_cast<const f32x4v*>(bias + d0);
    f32x4v bb1 = *reinterpret_cast<const f32x4v*>(bias + d0 + 4);
    float h[8];
    #pragma unroll
    for (int j = 0; j < 4; ++j){ h[j] = tanhf(y0[j] + bb0[j]); h[4+j] = tanhf(y1[j] + bb1[j]); }
    f32x4v h0, h1;
    #pragma unroll
    for (int j = 0; j < 4; ++j){ h0[j] = h[j]; h1[j] = h[4+j]; }
    *reinterpret_cast<f32x4v*>(&hi_lds[d0]) = h0;
    *reinterpret_cast<f32x4v*>(&hi_lds[d0+4]) = h1;
    f16x8 hh, ll;
    #pragma unroll
    for (int j = 0; j < 8; ++j){ hh[j] = (f16)h[j]; ll[j] = (f16)(h[j] - (float)hh[j]); }
    *reinterpret_cast<f16x8*>(pHist + ((size_t)t*128 + b)*2048 + d0) = hh;
    *reinterpret_cast<f16x8*>(stLo + (size_t)b*2048 + d0) = ll;
  }
  __syncthreads();
  const int lane = tid & 63, wv = tid >> 6;
  // cache state slice in registers
  float hreg[32];
  #pragma unroll
  for (int jj = 0; jj < 4; ++jj){
    const int d = (jj*64 + lane)*8;
    f32x4v v0 = *reinterpret_cast<const f32x4v*>(&hi_lds[d]);
    f32x4v v1 = *reinterpret_cast<const f32x4v*>(&hi_lds[d+4]);
    #pragma unroll
    for (int j = 0; j < 4; ++j){ hreg[jj*8+j] = v0[j]; hreg[jj*8+4+j] = v1[j]; }
  }
  // phase B: scores vs refined history (f16 hi+lo ~ f32)
  for (int i = wv; i < t; i += 4){
    const f16* rh = rHi + ((size_t)i*128 + b)*2048;
    const f16* rl = rLo + ((size_t)i*128 + b)*2048;
    float dot = 0.f;
    #pragma unroll
    for (int jj = 0; jj < 4; ++jj){
      const int d = (jj*64 + lane)*8;
      f16x8 h8 = *reinterpret_cast<const f16x8*>(rh + d);
      f16x8 l8 = *reinterpret_cast<const f16x8*>(rl + d);
      #pragma unroll
      for (int j = 0; j < 8; ++j)
        dot += ((float)h8[j] + (float)l8[j]) * hreg[jj*8+j];
    }
    #pragma unroll
    for (int off = 1; off < 64; off <<= 1) dot += __shfl_xor(dot, off);
    if (lane == 0) sc[i] = dot;
  }
  __syncthreads();
  if (t > 0){
    if (tid < 64){
      const float s = (tid < t) ? sc[tid] : -INFINITY;
      float mm = s;
      #pragma unroll
      for (int off = 1; off < 64; off <<= 1) mm = fmaxf(mm, __shfl_xor(mm, off));
      const float e = (tid < t) ? __expf(s - mm) : 0.f;
      float sum = e;
      #pragma unroll
      for (int off = 1; off < 64; off <<= 1) sum += __shfl_xor(sum, off);
      a_lds[tid] = e / sum;
    }
    __syncthreads();
    float acc8[8];
    #pragma unroll
    for (int j = 0; j < 8; ++j) acc8[j] = 0.f;
    for (int i = 0; i < t; ++i){
      const float a = a_lds[i];
      f16x8 ph = *reinterpret_cast<const f16x8*>(pHist + ((size_t)i*128 + b)*2048 + d0);
      #pragma unroll
      for (int j = 0; j < 8; ++j) acc8[j] += a * (float)ph[j];
    }
    f16x8 hh, ll;
    #pragma unroll
    for (int j = 0; j < 8; ++j){ hh[j] = (f16)acc8[j]; ll[j] = (f16)(acc8[j] - (float)hh[j]); }
    *reinterpret_cast<f16x8*>(sctxHi + (size_t)b*2048 + d0) = hh;
    *reinterpret_cast<f16x8*>(sctxLo + (size_t)b*2048 + d0) = ll;
  } else {
    f16x8 z;
    #pragma unroll
    for (int j = 0; j < 8; ++j) z[j] = (f16)0.f;
    *reinterpret_cast<f16x8*>(sctxHi + (size_t)b*2048 + d0) = z;
    *reinterpret_cast<f16x8*>(sctxLo + (size_t)b*2048 + d0) = z;
  }
}

// epilogue of layer-1 self fuse-GEMM: hr1 -> refined history (f16 hi/lo)
__global__ __launch_bounds__(256) void k_epi(
    const float* __restrict__ partials, const float* __restrict__ bias,
    f16* __restrict__ rHi, f16* __restrict__ rLo, const int t)
{
  const int b = blockIdx.x, tid = threadIdx.x;
  const int d0 = tid*8;
  f32x4v y0, y1;
  #pragma unroll
  for (int j = 0; j < 4; ++j){ y0[j] = 0.f; y1[j] = 0.f; }
  #pragma unroll
  for (int p = 0; p < NPART; ++p){
    const float* pp = partials + (size_t)p*BD + (size_t)b*2048 + d0;
    f32x4v v0 = *reinterpret_cast<const f32x4v*>(pp);
    f32x4v v1 = *reinterpret_cast<const f32x4v*>(pp + 4);
    #pragma unroll
    for (int j = 0; j < 4; ++j){ y0[j] += v0[j]; y1[j] += v1[j]; }
  }
  f32x4v bb0 = *reinterpret_cast<const f32x4v*>(bias + d0);
  f32x4v bb1 = *reinterpret_cast<const f32x4v*>(bias + d0 + 4);
  f16x8 hh, ll;
  #pragma unroll
  for (int j = 0; j < 4; ++j){
    const float a = tanhf(y0[j] + bb0[j]);
    const float c = tanhf(y1[j] + bb1[j]);
    hh[j] = (f16)a;   ll[j] = (f16)(a - (float)hh[j]);
    hh[4+j] = (f16)c; ll[4+j] = (f16)(c - (float)hh[4+j]);
  }
  *reinterpret_cast<f16x8*>(rHi + ((size_t)t*128 + b)*2048 + d0) = hh;
  *reinterpret_cast<f16x8*>(rLo + ((size_t)t*128 + b)*2048 + d0) = ll;
}

// ---------------------------------------------------------------------------
// Head stage 1: z1 = relu(r1(8192x2048) @ hw1 + hb1), f16 2-pass MFMA
// ---------------------------------------------------------------------------
__global__ __launch_bounds__(256) void k_headgemm(
    const f16* __restrict__ aHi, const f16* __restrict__ aLo,
    const f16* __restrict__ w1H,   // [224][2048]
    const float* __restrict__ hb1,
    float* __restrict__ z1)        // [8192][224]
{
  const int mb = blockIdx.x;   // 0..63 (128 rows each)
  const int nt = blockIdx.y;   // 0..6
  const int lane = threadIdx.x & 63, wv = threadIdx.x >> 6;
  const int rowA = mb*128 + wv*32 + (lane & 31);
  const int kb = lane >> 5;
  const int n = nt*32 + (lane & 31);
  const f16* pAH = aHi + (size_t)rowA*2048 + kb*8;
  const f16* pAL = aLo + (size_t)rowA*2048 + kb*8;
  const f16* pBH = w1H + (size_t)n*2048 + kb*8;
  f32x16 acc;
  #pragma unroll
  for (int r = 0; r < 16; ++r) acc[r] = 0.f;
  #pragma unroll 4
  for (int s = 0; s < 128; ++s){
    f16x8 ah = *reinterpret_cast<const f16x8*>(pAH + s*16);
    f16x8 al = *reinterpret_cast<const f16x8*>(pAL + s*16);
    f16x8 bh = *reinterpret_cast<const f16x8*>(pBH + s*16);
    acc = __builtin_amdgcn_mfma_f32_32x32x16_f16(ah, bh, acc, 0, 0, 0);
    acc = __builtin_amdgcn_mfma_f32_32x32x16_f16(al, bh, acc, 0, 0, 0);
  }
  const float bias = (n < 200) ? hb1[n] : 0.f;
  const int rowBase = mb*128 + wv*32 + 4*kb;
  #pragma unroll
  for (int r = 0; r < 16; ++r){
    const int rr = rowBase + (r & 3) + 8*(r >> 2);
    z1[(size_t)rr*224 + n] = fmaxf(acc[r] + bias, 0.f);
  }
}

// Head stage 2: z2 = relu(z1 @ hw2 + hb2); logits = z2 @ hw3 + hb3
__global__ __launch_bounds__(256) void k_head2(
    const float* __restrict__ z1,   // [8192][224]
    const float* __restrict__ hw2, const float* __restrict__ hb2,
    const float* __restrict__ hw3, const float* __restrict__ hb3,
    float* __restrict__ out)        // [128][64][2]
{
  const int r0 = blockIdx.x * 64;
  const int tid = threadIdx.x;
  __shared__ float zl[64][200];
  __shared__ float z2[64][50];
  for (int i = tid; i < 64*200; i += 256){
    const int r = i / 200, n = i % 200;
    zl[r][n] = z1[(size_t)(r0 + r)*224 + n];
  }
  __syncthreads();
  for (int i = tid; i < 64*50; i += 256){
    const int r = i / 50, n = i % 50;
    float s = hb2[n];
    for (int k = 0; k < 200; ++k) s += zl[r][k] * hw2[k*50 + n];
    z2[r][n] = fmaxf(s, 0.f);
  }
  __syncthreads();
  for (int i = tid; i < 128; i += 256){
    const int r = i >> 1, c = i & 1;
    float s = hb3[c];
    for (int k = 0; k < 50; ++k) s += z2[r][k] * hw3[k*2 + c];
    const int rg = r0 + r;
    const int tt = rg >> 7, b = rg & 127;    // rows are [t][b]
    out[(size_t)b*128 + tt*2 + c] = s;
  }
}

// ---------------------------------------------------------------------------
extern "C" void kernel_launch(void* const* d_in, const int* in_sizes, int n_in,
                              void* d_out, int out_size, void* d_ws, size_t ws_size,
                              hipStream_t stream)
{
  (void)in_sizes; (void)n_in; (void)out_size; (void)ws_size;
  const float* x_flat = (const float*)d_in[0];
  const float* enc    = (const float*)d_in[1];
  const float* h0     = (const float*)d_in[2];
  const float* c0     = (const float*)d_in[3];
  const float* cx_w0  = (const float*)d_in[4];
  const float* cx_b0  = (const float*)d_in[5];
  const float* ch_w0  = (const float*)d_in[6];
  const float* ch_b0  = (const float*)d_in[7];
  const float* cx_w1  = (const float*)d_in[8];
  const float* cx_b1  = (const float*)d_in[9];
  const float* ch_w1  = (const float*)d_in[10];
  const float* ch_b1  = (const float*)d_in[11];
  const float* ia_w0  = (const float*)d_in[12];
  const float* ia_b0  = (const float*)d_in[13];
  const float* sa_w0  = (const float*)d_in[14];
  const float* sa_b0  = (const float*)d_in[15];
  const float* ia_w1  = (const float*)d_in[16];
  const float* ia_b1  = (const float*)d_in[17];
  const float* sa_w1  = (const float*)d_in[18];
  const float* sa_b1  = (const float*)d_in[19];
  const float* hw1    = (const float*)d_in[20];
  const float* hb1    = (const float*)d_in[21];
  const float* hw2    = (const float*)d_in[22];
  const float* hb2    = (const float*)d_in[23];
  const float* hw3    = (const float*)d_in[24];
  const float* hb3    = (const float*)d_in[25];
  float* out = (float*)d_out;

  char* ws = (char*)d_ws;
  size_t off = 0;
  auto alloc = [&](size_t bytes) -> char* {
    char* p = ws + off;
    off += (bytes + 255) & ~(size_t)255;
    return p;
  };
  const size_t WPLANE = (size_t)2048*4096*2;   // one f16 weight plane (16 MB)
  f16* wIa0 = (f16*)alloc(WPLANE);
  f16* wSa0 = (f16*)alloc(WPLANE);
  f16* wIa1 = (f16*)alloc(WPLANE);
  f16* wSa1 = (f16*)alloc(WPLANE);
  f16* w1H  = (f16*)alloc((size_t)224*2048*2);
  unsigned short* encBf = (unsigned short*)alloc((size_t)128*128*2048*2);
  f16* hr0AHi = (f16*)alloc((size_t)64*BD*2);
  f16* hr0ALo = (f16*)alloc((size_t)64*BD*2);
  f16* p0     = (f16*)alloc((size_t)64*BD*2);
  f16* p1     = (f16*)alloc((size_t)64*BD*2);
  f16* r0Hi   = (f16*)alloc((size_t)64*BD*2);
  f16* r0Lo   = (f16*)alloc((size_t)64*BD*2);
  f16* r1Hi   = (f16*)alloc((size_t)64*BD*2);
  f16* r1Lo   = (f16*)alloc((size_t)64*BD*2);
  float* partials = (float*)alloc((size_t)NPART*BD*4);
  f16* ctxHi  = (f16*)alloc((size_t)BD*2);
  f16* ctxLo  = (f16*)alloc((size_t)BD*2);
  f16* hiLo   = (f16*)alloc((size_t)BD*2);
  f16* sctxHi = (f16*)alloc((size_t)BD*2);
  f16* sctxLo = (f16*)alloc((size_t)BD*2);
  f16* hrw1Hi = (f16*)alloc((size_t)BD*2);
  f16* hrw1Lo = (f16*)alloc((size_t)BD*2);
  float* hB   = (float*)alloc((size_t)BD*4);
  float* cB   = (float*)alloc((size_t)BD*4);
  unsigned short* wpack1 = (unsigned short*)alloc((size_t)128*32*6*2);
  float* z1   = (float*)alloc((size_t)8192*224*4);

  // ---- prologue -----------------------------------------------------------
  k_transpose_f16<<<dim3(64,128),256,0,stream>>>(ia_w0, wIa0, 4096, 2048);
  k_transpose_f16<<<dim3(64,128),256,0,stream>>>(sa_w0, wSa0, 4096, 2048);
  k_transpose_f16<<<dim3(64,128),256,0,stream>>>(ia_w1, wIa1, 4096, 2048);
  k_transpose_f16<<<dim3(64,128),256,0,stream>>>(sa_w1, wSa1, 4096, 2048);
  k_transpose_f16<<<dim3(7,64),256,0,stream>>>(hw1, w1H, 2048, 200);
  k_f32_to_bf16<<<(128*128*2048/4 + 255)/256, 256, 0, stream>>>(enc, encBf, 128*128*2048/4);
  k_pack_cellw<<<16,256,0,stream>>>(ch_w1, cx_w1, wpack1);
  k_cell0<<<1024,256,0,stream>>>(x_flat, h0, c0, cx_w0, cx_b0, ch_w0, ch_b0, hr0AHi, hr0ALo);

  // ---- 64 sequential steps ------------------------------------------------
  for (int t = 0; t < 64; ++t){
    const size_t tb = (size_t)t * BD;
    // layer 0
    k_inter<<<128,512,0,stream>>>(encBf, nullptr, hr0AHi + tb, hr0ALo + tb, ctxHi, ctxLo);
    k_gemm<<<dim3(32,NPART),256,0,stream>>>(hr0AHi + tb, hr0ALo + tb, ctxHi, ctxLo,
                                            wIa0, partials);
    k_self<<<128,256,0,stream>>>(partials, ia_b0, p0, r0Hi, r0Lo, hiLo, sctxHi, sctxLo, t);
    k_gemm<<<dim3(32,NPART),256,0,stream>>>(p0 + tb, hiLo, sctxHi, sctxLo,
                                            wSa0, partials);
    // layer 1 cell (also fuse0b epilogue -> hr0)
    k_cell1<<<1024,256,0,stream>>>(partials, sa_b0,
        (t == 0) ? (h0 + (size_t)128*2048) : hB,
        (t == 0) ? (c0 + (size_t)128*2048) : cB,
        hB, cB, wpack1, cx_b1, ch_b1, r0Hi, r0Lo, hrw1Hi, hrw1Lo, t);
    // layer 1
    k_inter<<<128,512,0,stream>>>(encBf, hB, nullptr, nullptr, ctxHi, ctxLo);
    k_gemm<<<dim3(32,NPART),256,0,stream>>>(hrw1Hi, hrw1Lo, ctxHi, ctxLo,
                                            wIa1, partials);
    k_self<<<128,256,0,stream>>>(partials, ia_b1, p1, r1Hi, r1Lo, hiLo, sctxHi, sctxLo, t);
    k_gemm<<<dim3(32,NPART),256,0,stream>>>(p1 + tb, hiLo, sctxHi, sctxLo,
                                            wSa1, partials);
    k_epi<<<128,256,0,stream>>>(partials, sa_b1, r1Hi, r1Lo, t);
  }

  // ---- head (batched over all t,b) ----------------------------------------
  k_headgemm<<<dim3(64,7),256,0,stream>>>(r1Hi, r1Lo, w1H, hb1, z1);
  k_head2<<<128,256,0,stream>>>(z1, hw2, hb2, hw3, hb3, out);
}

// Round 4
// 9486.655 us; speedup vs baseline: 2.4571x; 1.1572x over previous
//
#include <hip/hip_runtime.h>
#include <math.h>

// ---------------------------------------------------------------------------
// CLSADecoder: 2-layer RowSharedConvLSTM + inter-attn + causal self-attn + head
// B=128, T=64, D=2048 (ROWS=8, CH=32, COLS=8), S=128.
// R3: (a) layer-0 inter-attn batched over all t (one launch), (b) layer-0
// ia-GEMM batched full-K with fused tanh epilogue -> p0 for all t, (c) k_gemm
// uses global_load_lds double-buffered staging, NPART=16 (2 blocks/CU).
// t-loop is 8 kernels: self0, gemm(sa0), cell1, inter1, gemm(ia1), self1,
// gemm(sa1), epi.
// ---------------------------------------------------------------------------

typedef _Float16 f16;
typedef _Float16 f16x8 __attribute__((ext_vector_type(8)));
typedef _Float16 f16x4 __attribute__((ext_vector_type(4)));
typedef float  f32x16 __attribute__((ext_vector_type(16)));
typedef float  f32x4v __attribute__((ext_vector_type(4)));
typedef unsigned short u16x8 __attribute__((ext_vector_type(8)));
typedef unsigned short u16x4 __attribute__((ext_vector_type(4)));

#define BD 262144   // 128*2048  (one [B][D] plane)
#define NPART 16    // split-K planes for per-step GEMMs

__device__ __forceinline__ unsigned short f2bf(float x){
  unsigned int u = __builtin_bit_cast(unsigned int, x);
  u += 0x7fffu + ((u >> 16) & 1u);
  return (unsigned short)(u >> 16);
}
__device__ __forceinline__ float bf2f(unsigned short h){
  unsigned int u = ((unsigned int)h) << 16;
  return __builtin_bit_cast(float, u);
}
__device__ __forceinline__ float sigmoidf_(float x){
  return 1.0f / (1.0f + __expf(-x));
}
// async global -> LDS, 16 bytes/lane
__device__ __forceinline__ void g2l16(const void* g, void* l){
  __builtin_amdgcn_global_load_lds(
      (const __attribute__((address_space(1))) unsigned int*)g,
      (__attribute__((address_space(3))) unsigned int*)l,
      16, 0, 0);
}

// ---------------------------------------------------------------------------
// Prologue: transpose f32 weight [K][N] -> f16 plane [Npad][K]
// ---------------------------------------------------------------------------
__global__ __launch_bounds__(256) void k_transpose_f16(
    const float* __restrict__ src, f16* __restrict__ dhi,
    const int K, const int N)
{
  __shared__ float tile[32][33];
  const int n0 = blockIdx.x * 32, k0 = blockIdx.y * 32;
  const int tx = threadIdx.x & 31, ty = threadIdx.x >> 5;
  #pragma unroll
  for (int ii = 0; ii < 4; ++ii){
    const int k = k0 + ty + ii*8, n = n0 + tx;
    float v = (n < N) ? src[(size_t)k * N + n] : 0.0f;
    tile[ty + ii*8][tx] = v;
  }
  __syncthreads();
  #pragma unroll
  for (int ii = 0; ii < 4; ++ii){
    const int n = n0 + ty + ii*8, k = k0 + tx;
    dhi[(size_t)n * K + k] = (f16)tile[tx][ty + ii*8];
  }
}

__global__ void k_f32_to_bf16(const float* __restrict__ src,
                              unsigned short* __restrict__ dst, const int n4)
{
  const int i = blockIdx.x * 256 + threadIdx.x;
  if (i < n4){
    f32x4v v = *reinterpret_cast<const f32x4v*>(src + (size_t)i * 4);
    u16x4 o;
    #pragma unroll
    for (int j = 0; j < 4; ++j) o[j] = f2bf(v[j]);
    *reinterpret_cast<u16x4*>(dst + (size_t)i * 4) = o;
  }
}

__global__ void k_pack_cellw(const float* __restrict__ chw,
                             const float* __restrict__ cxw,
                             unsigned short* __restrict__ wp)
{
  const int i = blockIdx.x * 256 + threadIdx.x;
  if (i < 128 * 32){
    #pragma unroll
    for (int k = 0; k < 3; ++k){
      wp[i*6 + k]     = f2bf(chw[i*3 + k]);
      wp[i*6 + 3 + k] = f2bf(cxw[i*3 + k]);
    }
  }
}

// ---------------------------------------------------------------------------
// Layer-0 ConvLSTM for ALL 64 steps.
// ---------------------------------------------------------------------------
__global__ __launch_bounds__(256) void k_cell0(
    const float* __restrict__ x_flat,
    const float* __restrict__ h0, const float* __restrict__ c0,
    const float* __restrict__ cxw, const float* __restrict__ cxb,
    const float* __restrict__ chw, const float* __restrict__ chb,
    f16* __restrict__ hrawHi, f16* __restrict__ hrawLo)     // [T][B][2048]
{
  const int b = blockIdx.x >> 3, row = blockIdx.x & 7;
  const int tid = threadIdx.x;
  __shared__ float h_lds[256];
  __shared__ float x_lds[8];
  __shared__ float P[128][2][8];
  const int gc = tid >> 1, ih = tid & 1;
  float wh[16][3];
  #pragma unroll
  for (int icl = 0; icl < 16; ++icl)
    #pragma unroll
    for (int k = 0; k < 3; ++k)
      wh[icl][k] = chw[(gc*32 + ih*16 + icl)*3 + k];
  const float wx0 = cxw[gc*3+0], wx1 = cxw[gc*3+1], wx2 = cxw[gc*3+2];
  const float bsum = cxb[gc] + chb[gc];
  const int ic = tid >> 3, col = tid & 7;
  const size_t dg = (size_t)b*2048 + row*256 + tid;
  float c_reg = c0[dg];
  h_lds[tid] = h0[dg];
  __syncthreads();
  for (int t = 0; t < 64; ++t){
    if (tid < 8) x_lds[tid] = x_flat[((size_t)b*64 + t)*64 + row*8 + tid];
    __syncthreads();
    float g8[8];
    #pragma unroll
    for (int c2 = 0; c2 < 8; ++c2) g8[c2] = 0.f;
    #pragma unroll
    for (int icl = 0; icl < 16; ++icl){
      const int icg = ih*16 + icl;
      f32x4v hv0 = *reinterpret_cast<const f32x4v*>(&h_lds[icg*8]);
      f32x4v hv1 = *reinterpret_cast<const f32x4v*>(&h_lds[icg*8 + 4]);
      const float hv[8] = {hv0[0],hv0[1],hv0[2],hv0[3],hv1[0],hv1[1],hv1[2],hv1[3]};
      #pragma unroll
      for (int c2 = 0; c2 < 8; ++c2){
        float s = hv[c2] * wh[icl][1];
        if (c2 > 0) s += hv[c2-1] * wh[icl][0];
        if (c2 < 7) s += hv[c2+1] * wh[icl][2];
        g8[c2] += s;
      }
    }
    if (ih == 0){
      #pragma unroll
      for (int c2 = 0; c2 < 8; ++c2){
        float s = x_lds[c2] * wx1 + bsum;
        if (c2 > 0) s += x_lds[c2-1] * wx0;
        if (c2 < 7) s += x_lds[c2+1] * wx2;
        g8[c2] += s;
      }
    }
    #pragma unroll
    for (int c2 = 0; c2 < 8; ++c2) P[gc][ih][c2] = g8[c2];
    __syncthreads();
    const float ipre = P[ic   ][0][col] + P[ic   ][1][col];
    const float fpre = P[ic+32][0][col] + P[ic+32][1][col];
    const float opre = P[ic+64][0][col] + P[ic+64][1][col];
    const float gpre = P[ic+96][0][col] + P[ic+96][1][col];
    const float cn = sigmoidf_(fpre)*c_reg + sigmoidf_(ipre)*tanhf(gpre);
    c_reg = cn;
    const float hn = sigmoidf_(opre)*tanhf(cn);
    h_lds[tid] = hn;
    const f16 hh = (f16)hn;
    hrawHi[((size_t)t*128 + b)*2048 + row*256 + tid] = hh;
    hrawLo[((size_t)t*128 + b)*2048 + row*256 + tid] = (f16)(hn - (float)hh);
    __syncthreads();
  }
}

// ---------------------------------------------------------------------------
// Layer-1 ConvLSTM for one step (also epilogue of the layer-0 sa fuse-GEMM).
// ---------------------------------------------------------------------------
__global__ __launch_bounds__(256) void k_cell1(
    const float* __restrict__ partials,   // [NPART][128][2048]
    const float* __restrict__ sab0,
    const float* __restrict__ h_src, const float* __restrict__ c_src,
    float* __restrict__ hB, float* __restrict__ cB,
    const unsigned short* __restrict__ wp,
    const float* __restrict__ cxb, const float* __restrict__ chb,
    f16* __restrict__ r0Hi, f16* __restrict__ r0Lo,
    f16* __restrict__ hrw1Hi, f16* __restrict__ hrw1Lo,
    const int t)
{
  const int b = blockIdx.x >> 3, row = blockIdx.x & 7;
  const int tid = threadIdx.x;
  __shared__ float x_lds[256];
  __shared__ float h_lds[256];
  __shared__ float P[128][2][8];
  __shared__ unsigned short wlds[128*32*6];
  const size_t dg = (size_t)b*2048 + row*256 + tid;
  {
    float y = 0.f;
    #pragma unroll
    for (int p = 0; p < NPART; ++p) y += partials[(size_t)p*BD + dg];
    const float hr0 = tanhf(y + sab0[row*256 + tid]);
    x_lds[tid] = hr0;
    const f16 hh = (f16)hr0;
    r0Hi[(size_t)t*BD + dg] = hh;
    r0Lo[(size_t)t*BD + dg] = (f16)(hr0 - (float)hh);
    h_lds[tid] = h_src[dg];
  }
  for (int i = tid; i < 128*32*6; i += 256) wlds[i] = wp[i];
  __syncthreads();
  {
    const int gc = tid >> 1, ih = tid & 1;
    float g8[8];
    #pragma unroll
    for (int c2 = 0; c2 < 8; ++c2) g8[c2] = 0.f;
    #pragma unroll
    for (int icl = 0; icl < 16; ++icl){
      const int icg = ih*16 + icl;
      f32x4v hv0 = *reinterpret_cast<const f32x4v*>(&h_lds[icg*8]);
      f32x4v hv1 = *reinterpret_cast<const f32x4v*>(&h_lds[icg*8 + 4]);
      f32x4v xv0 = *reinterpret_cast<const f32x4v*>(&x_lds[icg*8]);
      f32x4v xv1 = *reinterpret_cast<const f32x4v*>(&x_lds[icg*8 + 4]);
      const float hv[8] = {hv0[0],hv0[1],hv0[2],hv0[3],hv1[0],hv1[1],hv1[2],hv1[3]};
      const float xv[8] = {xv0[0],xv0[1],xv0[2],xv0[3],xv1[0],xv1[1],xv1[2],xv1[3]};
      const unsigned short* wq = &wlds[(gc*32 + icg)*6];
      const float wh0 = bf2f(wq[0]), wh1 = bf2f(wq[1]), wh2 = bf2f(wq[2]);
      const float wx0 = bf2f(wq[3]), wx1 = bf2f(wq[4]), wx2 = bf2f(wq[5]);
      #pragma unroll
      for (int c2 = 0; c2 < 8; ++c2){
        float s = hv[c2]*wh1 + xv[c2]*wx1;
        if (c2 > 0) s += hv[c2-1]*wh0 + xv[c2-1]*wx0;
        if (c2 < 7) s += hv[c2+1]*wh2 + xv[c2+1]*wx2;
        g8[c2] += s;
      }
    }
    #pragma unroll
    for (int c2 = 0; c2 < 8; ++c2) P[gc][ih][c2] = g8[c2];
  }
  __syncthreads();
  {
    const int ic = tid >> 3, col = tid & 7;
    const float ipre = P[ic   ][0][col] + P[ic   ][1][col] + cxb[ic]    + chb[ic];
    const float fpre = P[ic+32][0][col] + P[ic+32][1][col] + cxb[ic+32] + chb[ic+32];
    const float opre = P[ic+64][0][col] + P[ic+64][1][col] + cxb[ic+64] + chb[ic+64];
    const float gpre = P[ic+96][0][col] + P[ic+96][1][col] + cxb[ic+96] + chb[ic+96];
    const float c_old = c_src[dg];
    const float cn = sigmoidf_(fpre)*c_old + sigmoidf_(ipre)*tanhf(gpre);
    cB[dg] = cn;
    const float hraw = sigmoidf_(opre)*tanhf(cn);
    hB[dg] = hraw;
    const f16 hh = (f16)hraw;
    hrw1Hi[dg] = hh;
    hrw1Lo[dg] = (f16)(hraw - (float)hh);
  }
}

// ---------------------------------------------------------------------------
// Inter-attention: block (b, t'); state/ctx offset by blockIdx.y*BD so one
// kernel serves both the batched layer-0 pass (grid 128x64) and the per-step
// layer-1 pass (grid 128, stF path).
// ---------------------------------------------------------------------------
__global__ __launch_bounds__(512) void k_inter(
    const unsigned short* __restrict__ encBf,   // [B][128][2048] bf16
    const float* __restrict__ stF,              // f32 state [B][2048] or null
    const f16* __restrict__ stHi, const f16* __restrict__ stLo,
    f16* __restrict__ ctxHi, f16* __restrict__ ctxLo)
{
  const int b = blockIdx.x;
  const size_t so = (size_t)blockIdx.y * BD + (size_t)b * 2048;
  const int tid = threadIdx.x;
  const int lane = tid & 63, wv = tid >> 6;
  __shared__ float wav[8][2048];
  __shared__ float wm[8], wl[8];
  float sv[32], av[32];
  #pragma unroll
  for (int p = 0; p < 4; ++p){
    const int d = (p*64 + lane)*8;
    if (stF){
      f32x4v v0 = *reinterpret_cast<const f32x4v*>(stF + (size_t)b*2048 + d);
      f32x4v v1 = *reinterpret_cast<const f32x4v*>(stF + (size_t)b*2048 + d + 4);
      #pragma unroll
      for (int j = 0; j < 4; ++j){ sv[p*8+j] = v0[j]; sv[p*8+4+j] = v1[j]; }
    } else {
      f16x8 hh = *reinterpret_cast<const f16x8*>(stHi + so + d);
      f16x8 ll = *reinterpret_cast<const f16x8*>(stLo + so + d);
      #pragma unroll
      for (int j = 0; j < 8; ++j) sv[p*8+j] = (float)hh[j] + (float)ll[j];
    }
    #pragma unroll
    for (int j = 0; j < 8; ++j) av[p*8+j] = 0.f;
  }
  float m = -INFINITY, l = 0.f;
  const int s0 = wv*16;
  for (int r = 0; r < 16; ++r){
    const unsigned short* er = encBf + ((size_t)b*128 + s0 + r)*2048;
    float ef[32];
    float dot = 0.f;
    #pragma unroll
    for (int p = 0; p < 4; ++p){
      u16x8 ev = *reinterpret_cast<const u16x8*>(er + (p*64 + lane)*8);
      #pragma unroll
      for (int j = 0; j < 8; ++j){ const float e = bf2f(ev[j]); ef[p*8+j] = e; dot += e * sv[p*8+j]; }
    }
    #pragma unroll
    for (int off = 1; off < 64; off <<= 1) dot += __shfl_xor(dot, off);
    if (dot > m){
      const float scf = __expf(m - dot);
      l *= scf;
      #pragma unroll
      for (int q = 0; q < 32; ++q) av[q] *= scf;
      m = dot;
    }
    const float pp = __expf(dot - m);
    l += pp;
    #pragma unroll
    for (int q = 0; q < 32; ++q) av[q] += pp * ef[q];
  }
  #pragma unroll
  for (int p = 0; p < 4; ++p){
    const int d = (p*64 + lane)*8;
    f32x4v v0, v1;
    #pragma unroll
    for (int j = 0; j < 4; ++j){ v0[j] = av[p*8+j]; v1[j] = av[p*8+4+j]; }
    *reinterpret_cast<f32x4v*>(&wav[wv][d]) = v0;
    *reinterpret_cast<f32x4v*>(&wav[wv][d+4]) = v1;
  }
  if (lane == 0){ wm[wv] = m; wl[wv] = l; }
  __syncthreads();
  float M = wm[0];
  #pragma unroll
  for (int i = 1; i < 8; ++i) M = fmaxf(M, wm[i]);
  float U[8];
  float L = 0.f;
  #pragma unroll
  for (int i = 0; i < 8; ++i){ U[i] = __expf(wm[i] - M); L += wl[i] * U[i]; }
  const float Linv = 1.f / L;
  const int d0 = tid * 4;
  float acc[4] = {0.f, 0.f, 0.f, 0.f};
  #pragma unroll
  for (int w = 0; w < 8; ++w){
    f32x4v v = *reinterpret_cast<const f32x4v*>(&wav[w][d0]);
    #pragma unroll
    for (int j = 0; j < 4; ++j) acc[j] += U[w] * v[j];
  }
  f16x4 hh, ll;
  #pragma unroll
  for (int j = 0; j < 4; ++j){
    const float v = acc[j] * Linv;
    hh[j] = (f16)v;
    ll[j] = (f16)(v - (float)hh[j]);
  }
  *reinterpret_cast<f16x4*>(ctxHi + so + d0) = hh;
  *reinterpret_cast<f16x4*>(ctxLo + so + d0) = ll;
}

// ---------------------------------------------------------------------------
// Per-step fuse GEMM: y = [A0|A1](128x4096) @ W(4096x2048), f16 2-pass MFMA.
// global_load_lds staging, double-buffered LDS (2x40KB). Grid (32 nt, 16 kc)
// = 512 blocks = 2 blocks/CU. Writes f32 partials [16][128][2048].
// ---------------------------------------------------------------------------
__global__ __launch_bounds__(256, 2) void k_gemm(
    const f16* __restrict__ a0Hi, const f16* __restrict__ a0Lo,
    const f16* __restrict__ a1Hi, const f16* __restrict__ a1Lo,
    const f16* __restrict__ wHp,
    float* __restrict__ partials)
{
  const int nt = blockIdx.x;        // 64-col tile
  const int kc = blockIdx.y;        // 0..15, 256-k chunk
  const int tid = threadIdx.x;
  const int lane = tid & 63, wv = tid >> 6;
  // per buffer: aH 16KB @0, aL 16KB @16K, W 8KB @32K; two buffers (80KB)
  __shared__ __align__(16) char lds[81920];
  const f16* aH = (kc < 8) ? a0Hi : a1Hi;
  const f16* aL = (kc < 8) ? a0Lo : a1Lo;
  const int kA = (kc & 7) * 256;
  const f16* wH = wHp + (size_t)(nt*64)*4096 + kc*256;

  auto stage = [&](int buf, int ki){
    char* lb = lds + buf*40960;
    const int ke = kA + ki*64;
    #pragma unroll
    for (int i = 0; i < 4; ++i){
      const int c = i*256 + tid, row = c >> 3;
      const int srcb = ((c & 7)*16) ^ ((row & 7) << 4);
      g2l16((const char*)(aH + (size_t)row*2048 + ke) + srcb, lb + c*16);
      g2l16((const char*)(aL + (size_t)row*2048 + ke) + srcb, lb + 16384 + c*16);
    }
    #pragma unroll
    for (int i = 0; i < 2; ++i){
      const int c = i*256 + tid, row = c >> 3;
      const int srcb = ((c & 7)*16) ^ ((row & 7) << 4);
      g2l16((const char*)(wH + (size_t)row*4096 + ki*64) + srcb, lb + 32768 + c*16);
    }
  };

  f32x16 acc0, acc1;
  #pragma unroll
  for (int r = 0; r < 16; ++r){ acc0[r] = 0.f; acc1[r] = 0.f; }
  const int rA = wv*32 + (lane & 31);
  const int kb = lane >> 5;
  const int rB0 = lane & 31;
  const int aswz = (rA & 7) << 4;
  const int bswz = (rB0 & 7) << 4;

  stage(0, 0);
  __syncthreads();
  for (int ki = 0; ki < 4; ++ki){
    const int buf = ki & 1;
    if (ki < 3) stage(buf ^ 1, ki + 1);
    const char* lb = lds + buf*40960;
    #pragma unroll
    for (int s = 0; s < 4; ++s){
      const int cb = s*32 + kb*16;
      f16x8 ah  = *reinterpret_cast<const f16x8*>(lb + rA*128 + (cb ^ aswz));
      f16x8 al  = *reinterpret_cast<const f16x8*>(lb + 16384 + rA*128 + (cb ^ aswz));
      f16x8 b0h = *reinterpret_cast<const f16x8*>(lb + 32768 + rB0*128 + (cb ^ bswz));
      f16x8 b1h = *reinterpret_cast<const f16x8*>(lb + 32768 + 4096 + rB0*128 + (cb ^ bswz));
      acc0 = __builtin_amdgcn_mfma_f32_32x32x16_f16(ah, b0h, acc0, 0, 0, 0);
      acc1 = __builtin_amdgcn_mfma_f32_32x32x16_f16(ah, b1h, acc1, 0, 0, 0);
      acc0 = __builtin_amdgcn_mfma_f32_32x32x16_f16(al, b0h, acc0, 0, 0, 0);
      acc1 = __builtin_amdgcn_mfma_f32_32x32x16_f16(al, b1h, acc1, 0, 0, 0);
    }
    __syncthreads();
  }

  float* outp = partials + (size_t)kc*BD + (size_t)(nt*64 + (lane & 31));
  const int rowBase = wv*32 + 4*kb;
  #pragma unroll
  for (int r = 0; r < 16; ++r){
    const int rr = rowBase + (r & 3) + 8*(r >> 2);
    outp[(size_t)rr*2048]      = acc0[r];
    outp[(size_t)rr*2048 + 32] = acc1[r];
  }
}

// ---------------------------------------------------------------------------
// Batched full-K fuse GEMM (layer-0 ia for all t): grid (32 nt, 64 t).
// Fused epilogue: p0[t] = tanh(y + bias), written as f16 hi/lo planes.
// ---------------------------------------------------------------------------
__global__ __launch_bounds__(256, 2) void k_gemm_full(
    const f16* __restrict__ a0Hi, const f16* __restrict__ a0Lo,   // [T][B][2048]
    const f16* __restrict__ a1Hi, const f16* __restrict__ a1Lo,   // [T][B][2048]
    const f16* __restrict__ wHp, const float* __restrict__ bias,
    f16* __restrict__ outHi, f16* __restrict__ outLo)             // [T][B][2048]
{
  const int nt = blockIdx.x, t = blockIdx.y;
  const size_t tb = (size_t)t * BD;
  const int tid = threadIdx.x;
  const int lane = tid & 63, wv = tid >> 6;
  __shared__ __align__(16) char lds[81920];
  const f16* wH = wHp + (size_t)(nt*64)*4096;

  auto stage = [&](int buf, int ki){
    char* lb = lds + buf*40960;
    const f16* aH = ((ki < 32) ? a0Hi : a1Hi) + tb;
    const f16* aL = ((ki < 32) ? a0Lo : a1Lo) + tb;
    const int ke = (ki & 31) * 64;
    #pragma unroll
    for (int i = 0; i < 4; ++i){
      const int c = i*256 + tid, row = c >> 3;
      const int srcb = ((c & 7)*16) ^ ((row & 7) << 4);
      g2l16((const char*)(aH + (size_t)row*2048 + ke) + srcb, lb + c*16);
      g2l16((const char*)(aL + (size_t)row*2048 + ke) + srcb, lb + 16384 + c*16);
    }
    #pragma unroll
    for (int i = 0; i < 2; ++i){
      const int c = i*256 + tid, row = c >> 3;
      const int srcb = ((c & 7)*16) ^ ((row & 7) << 4);
      g2l16((const char*)(wH + (size_t)row*4096 + ki*64) + srcb, lb + 32768 + c*16);
    }
  };

  f32x16 acc0, acc1;
  #pragma unroll
  for (int r = 0; r < 16; ++r){ acc0[r] = 0.f; acc1[r] = 0.f; }
  const int rA = wv*32 + (lane & 31);
  const int kb = lane >> 5;
  const int rB0 = lane & 31;
  const int aswz = (rA & 7) << 4;
  const int bswz = (rB0 & 7) << 4;

  stage(0, 0);
  __syncthreads();
  for (int ki = 0; ki < 64; ++ki){
    const int buf = ki & 1;
    if (ki < 63) stage(buf ^ 1, ki + 1);
    const char* lb = lds + buf*40960;
    #pragma unroll
    for (int s = 0; s < 4; ++s){
      const int cb = s*32 + kb*16;
      f16x8 ah  = *reinterpret_cast<const f16x8*>(lb + rA*128 + (cb ^ aswz));
      f16x8 al  = *reinterpret_cast<const f16x8*>(lb + 16384 + rA*128 + (cb ^ aswz));
      f16x8 b0h = *reinterpret_cast<const f16x8*>(lb + 32768 + rB0*128 + (cb ^ bswz));
      f16x8 b1h = *reinterpret_cast<const f16x8*>(lb + 32768 + 4096 + rB0*128 + (cb ^ bswz));
      acc0 = __builtin_amdgcn_mfma_f32_32x32x16_f16(ah, b0h, acc0, 0, 0, 0);
      acc1 = __builtin_amdgcn_mfma_f32_32x32x16_f16(ah, b1h, acc1, 0, 0, 0);
      acc0 = __builtin_amdgcn_mfma_f32_32x32x16_f16(al, b0h, acc0, 0, 0, 0);
      acc1 = __builtin_amdgcn_mfma_f32_32x32x16_f16(al, b1h, acc1, 0, 0, 0);
    }
    __syncthreads();
  }

  const int col0 = nt*64 + (lane & 31);
  const float b0 = bias[col0], b1 = bias[col0 + 32];
  const int rowBase = wv*32 + 4*kb;
  #pragma unroll
  for (int r = 0; r < 16; ++r){
    const int rr = rowBase + (r & 3) + 8*(r >> 2);
    const size_t o = tb + (size_t)rr*2048 + col0;
    const float p = tanhf(acc0[r] + b0);
    const float q = tanhf(acc1[r] + b1);
    const f16 ph = (f16)p, qh = (f16)q;
    outHi[o]      = ph;  outLo[o]      = (f16)(p - (float)ph);
    outHi[o + 32] = qh;  outLo[o + 32] = (f16)(q - (float)qh);
  }
}

// ---------------------------------------------------------------------------
// Layer-0 self-attention (state precomputed in p0 planes). Block per b.
// ---------------------------------------------------------------------------
__global__ __launch_bounds__(256) void k_self0(
    const f16* __restrict__ pHi, const f16* __restrict__ pLo,   // [T][B][2048]
    const f16* __restrict__ rHi, const f16* __restrict__ rLo,
    f16* __restrict__ sctxHi, f16* __restrict__ sctxLo,
    const int t)
{
  const int b = blockIdx.x;
  const int tid = threadIdx.x;
  __shared__ float sc[64];
  __shared__ float a_lds[64];
  const int lane = tid & 63, wv = tid >> 6;
  float hreg[32];
  #pragma unroll
  for (int jj = 0; jj < 4; ++jj){
    const int d = (jj*64 + lane)*8;
    f16x8 h8 = *reinterpret_cast<const f16x8*>(pHi + ((size_t)t*128 + b)*2048 + d);
    f16x8 l8 = *reinterpret_cast<const f16x8*>(pLo + ((size_t)t*128 + b)*2048 + d);
    #pragma unroll
    for (int j = 0; j < 8; ++j) hreg[jj*8+j] = (float)h8[j] + (float)l8[j];
  }
  for (int i = wv; i < t; i += 4){
    const f16* rh = rHi + ((size_t)i*128 + b)*2048;
    const f16* rl = rLo + ((size_t)i*128 + b)*2048;
    float dot = 0.f;
    #pragma unroll
    for (int jj = 0; jj < 4; ++jj){
      const int d = (jj*64 + lane)*8;
      f16x8 h8 = *reinterpret_cast<const f16x8*>(rh + d);
      f16x8 l8 = *reinterpret_cast<const f16x8*>(rl + d);
      #pragma unroll
      for (int j = 0; j < 8; ++j)
        dot += ((float)h8[j] + (float)l8[j]) * hreg[jj*8+j];
    }
    #pragma unroll
    for (int off = 1; off < 64; off <<= 1) dot += __shfl_xor(dot, off);
    if (lane == 0) sc[i] = dot;
  }
  __syncthreads();
  const int d0 = tid*8;
  if (t > 0){
    if (tid < 64){
      const float s = (tid < t) ? sc[tid] : -INFINITY;
      float mm = s;
      #pragma unroll
      for (int off = 1; off < 64; off <<= 1) mm = fmaxf(mm, __shfl_xor(mm, off));
      const float e = (tid < t) ? __expf(s - mm) : 0.f;
      float sum = e;
      #pragma unroll
      for (int off = 1; off < 64; off <<= 1) sum += __shfl_xor(sum, off);
      a_lds[tid] = e / sum;
    }
    __syncthreads();
    float acc8[8];
    #pragma unroll
    for (int j = 0; j < 8; ++j) acc8[j] = 0.f;
    for (int i = 0; i < t; ++i){
      const float a = a_lds[i];
      f16x8 ph = *reinterpret_cast<const f16x8*>(pHi + ((size_t)i*128 + b)*2048 + d0);
      #pragma unroll
      for (int j = 0; j < 8; ++j) acc8[j] += a * (float)ph[j];
    }
    f16x8 hh, ll;
    #pragma unroll
    for (int j = 0; j < 8; ++j){ hh[j] = (f16)acc8[j]; ll[j] = (f16)(acc8[j] - (float)hh[j]); }
    *reinterpret_cast<f16x8*>(sctxHi + (size_t)b*2048 + d0) = hh;
    *reinterpret_cast<f16x8*>(sctxLo + (size_t)b*2048 + d0) = ll;
  } else {
    f16x8 z;
    #pragma unroll
    for (int j = 0; j < 8; ++j) z[j] = (f16)0.f;
    *reinterpret_cast<f16x8*>(sctxHi + (size_t)b*2048 + d0) = z;
    *reinterpret_cast<f16x8*>(sctxLo + (size_t)b*2048 + d0) = z;
  }
}

// ---------------------------------------------------------------------------
// Layer-1 self-attention + epilogue of the inter fuse-GEMM. Block per b.
// ---------------------------------------------------------------------------
__global__ __launch_bounds__(256) void k_self1(
    const float* __restrict__ partials,
    const float* __restrict__ bias,
    f16* __restrict__ pHist,                      // [T][B][2048] f16 hi
    const f16* __restrict__ rHi, const f16* __restrict__ rLo,
    f16* __restrict__ stLo,                       // current-t lo plane
    f16* __restrict__ sctxHi, f16* __restrict__ sctxLo,
    const int t)
{
  const int b = blockIdx.x;
  const int tid = threadIdx.x;
  __shared__ float hi_lds[2048];
  __shared__ float sc[64];
  __shared__ float a_lds[64];
  const int d0 = tid*8;
  {
    f32x4v y0, y1;
    #pragma unroll
    for (int j = 0; j < 4; ++j){ y0[j] = 0.f; y1[j] = 0.f; }
    #pragma unroll
    for (int p = 0; p < NPART; ++p){
      const float* pp = partials + (size_t)p*BD + (size_t)b*2048 + d0;
      f32x4v v0 = *reinterpret_cast<const f32x4v*>(pp);
      f32x4v v1 = *reinterpret_cast<const f32x4v*>(pp + 4);
      #pragma unroll
      for (int j = 0; j < 4; ++j){ y0[j] += v0[j]; y1[j] += v1[j]; }
    }
    f32x4v bb0 = *reinterpret_cast<const f32x4v*>(bias + d0);
    f32x4v bb1 = *reinterpret_cast<const f32x4v*>(bias + d0 + 4);
    float h[8];
    #pragma unroll
    for (int j = 0; j < 4; ++j){ h[j] = tanhf(y0[j] + bb0[j]); h[4+j] = tanhf(y1[j] + bb1[j]); }
    f32x4v h0, h1;
    #pragma unroll
    for (int j = 0; j < 4; ++j){ h0[j] = h[j]; h1[j] = h[4+j]; }
    *reinterpret_cast<f32x4v*>(&hi_lds[d0]) = h0;
    *reinterpret_cast<f32x4v*>(&hi_lds[d0+4]) = h1;
    f16x8 hh, ll;
    #pragma unroll
    for (int j = 0; j < 8; ++j){ hh[j] = (f16)h[j]; ll[j] = (f16)(h[j] - (float)hh[j]); }
    *reinterpret_cast<f16x8*>(pHist + ((size_t)t*128 + b)*2048 + d0) = hh;
    *reinterpret_cast<f16x8*>(stLo + (size_t)b*2048 + d0) = ll;
  }
  __syncthreads();
  const int lane = tid & 63, wv = tid >> 6;
  float hreg[32];
  #pragma unroll
  for (int jj = 0; jj < 4; ++jj){
    const int d = (jj*64 + lane)*8;
    f32x4v v0 = *reinterpret_cast<const f32x4v*>(&hi_lds[d]);
    f32x4v v1 = *reinterpret_cast<const f32x4v*>(&hi_lds[d+4]);
    #pragma unroll
    for (int j = 0; j < 4; ++j){ hreg[jj*8+j] = v0[j]; hreg[jj*8+4+j] = v1[j]; }
  }
  for (int i = wv; i < t; i += 4){
    const f16* rh = rHi + ((size_t)i*128 + b)*2048;
    const f16* rl = rLo + ((size_t)i*128 + b)*2048;
    float dot = 0.f;
    #pragma unroll
    for (int jj = 0; jj < 4; ++jj){
      const int d = (jj*64 + lane)*8;
      f16x8 h8 = *reinterpret_cast<const f16x8*>(rh + d);
      f16x8 l8 = *reinterpret_cast<const f16x8*>(rl + d);
      #pragma unroll
      for (int j = 0; j < 8; ++j)
        dot += ((float)h8[j] + (float)l8[j]) * hreg[jj*8+j];
    }
    #pragma unroll
    for (int off = 1; off < 64; off <<= 1) dot += __shfl_xor(dot, off);
    if (lane == 0) sc[i] = dot;
  }
  __syncthreads();
  if (t > 0){
    if (tid < 64){
      const float s = (tid < t) ? sc[tid] : -INFINITY;
      float mm = s;
      #pragma unroll
      for (int off = 1; off < 64; off <<= 1) mm = fmaxf(mm, __shfl_xor(mm, off));
      const float e = (tid < t) ? __expf(s - mm) : 0.f;
      float sum = e;
      #pragma unroll
      for (int off = 1; off < 64; off <<= 1) sum += __shfl_xor(sum, off);
      a_lds[tid] = e / sum;
    }
    __syncthreads();
    float acc8[8];
    #pragma unroll
    for (int j = 0; j < 8; ++j) acc8[j] = 0.f;
    for (int i = 0; i < t; ++i){
      const float a = a_lds[i];
      f16x8 ph = *reinterpret_cast<const f16x8*>(pHist + ((size_t)i*128 + b)*2048 + d0);
      #pragma unroll
      for (int j = 0; j < 8; ++j) acc8[j] += a * (float)ph[j];
    }
    f16x8 hh, ll;
    #pragma unroll
    for (int j = 0; j < 8; ++j){ hh[j] = (f16)acc8[j]; ll[j] = (f16)(acc8[j] - (float)hh[j]); }
    *reinterpret_cast<f16x8*>(sctxHi + (size_t)b*2048 + d0) = hh;
    *reinterpret_cast<f16x8*>(sctxLo + (size_t)b*2048 + d0) = ll;
  } else {
    f16x8 z;
    #pragma unroll
    for (int j = 0; j < 8; ++j) z[j] = (f16)0.f;
    *reinterpret_cast<f16x8*>(sctxHi + (size_t)b*2048 + d0) = z;
    *reinterpret_cast<f16x8*>(sctxLo + (size_t)b*2048 + d0) = z;
  }
}

// epilogue of layer-1 self fuse-GEMM: hr1 -> refined history (f16 hi/lo)
__global__ __launch_bounds__(256) void k_epi(
    const float* __restrict__ partials, const float* __restrict__ bias,
    f16* __restrict__ rHi, f16* __restrict__ rLo, const int t)
{
  const int b = blockIdx.x, tid = threadIdx.x;
  const int d0 = tid*8;
  f32x4v y0, y1;
  #pragma unroll
  for (int j = 0; j < 4; ++j){ y0[j] = 0.f; y1[j] = 0.f; }
  #pragma unroll
  for (int p = 0; p < NPART; ++p){
    const float* pp = partials + (size_t)p*BD + (size_t)b*2048 + d0;
    f32x4v v0 = *reinterpret_cast<const f32x4v*>(pp);
    f32x4v v1 = *reinterpret_cast<const f32x4v*>(pp + 4);
    #pragma unroll
    for (int j = 0; j < 4; ++j){ y0[j] += v0[j]; y1[j] += v1[j]; }
  }
  f32x4v bb0 = *reinterpret_cast<const f32x4v*>(bias + d0);
  f32x4v bb1 = *reinterpret_cast<const f32x4v*>(bias + d0 + 4);
  f16x8 hh, ll;
  #pragma unroll
  for (int j = 0; j < 4; ++j){
    const float a = tanhf(y0[j] + bb0[j]);
    const float c = tanhf(y1[j] + bb1[j]);
    hh[j] = (f16)a;   ll[j] = (f16)(a - (float)hh[j]);
    hh[4+j] = (f16)c; ll[4+j] = (f16)(c - (float)hh[4+j]);
  }
  *reinterpret_cast<f16x8*>(rHi + ((size_t)t*128 + b)*2048 + d0) = hh;
  *reinterpret_cast<f16x8*>(rLo + ((size_t)t*128 + b)*2048 + d0) = ll;
}

// ---------------------------------------------------------------------------
// Head stage 1: z1 = relu(r1(8192x2048) @ hw1 + hb1), f16 2-pass MFMA
// ---------------------------------------------------------------------------
__global__ __launch_bounds__(256) void k_headgemm(
    const f16* __restrict__ aHi, const f16* __restrict__ aLo,
    const f16* __restrict__ w1H,   // [224][2048]
    const float* __restrict__ hb1,
    float* __restrict__ z1)        // [8192][224]
{
  const int mb = blockIdx.x;
  const int nt = blockIdx.y;
  const int lane = threadIdx.x & 63, wv = threadIdx.x >> 6;
  const int rowA = mb*128 + wv*32 + (lane & 31);
  const int kb = lane >> 5;
  const int n = nt*32 + (lane & 31);
  const f16* pAH = aHi + (size_t)rowA*2048 + kb*8;
  const f16* pAL = aLo + (size_t)rowA*2048 + kb*8;
  const f16* pBH = w1H + (size_t)n*2048 + kb*8;
  f32x16 acc;
  #pragma unroll
  for (int r = 0; r < 16; ++r) acc[r] = 0.f;
  #pragma unroll 4
  for (int s = 0; s < 128; ++s){
    f16x8 ah = *reinterpret_cast<const f16x8*>(pAH + s*16);
    f16x8 al = *reinterpret_cast<const f16x8*>(pAL + s*16);
    f16x8 bh = *reinterpret_cast<const f16x8*>(pBH + s*16);
    acc = __builtin_amdgcn_mfma_f32_32x32x16_f16(ah, bh, acc, 0, 0, 0);
    acc = __builtin_amdgcn_mfma_f32_32x32x16_f16(al, bh, acc, 0, 0, 0);
  }
  const float bias = (n < 200) ? hb1[n] : 0.f;
  const int rowBase = mb*128 + wv*32 + 4*kb;
  #pragma unroll
  for (int r = 0; r < 16; ++r){
    const int rr = rowBase + (r & 3) + 8*(r >> 2);
    z1[(size_t)rr*224 + n] = fmaxf(acc[r] + bias, 0.f);
  }
}

// Head stage 2
__global__ __launch_bounds__(256) void k_head2(
    const float* __restrict__ z1,
    const float* __restrict__ hw2, const float* __restrict__ hb2,
    const float* __restrict__ hw3, const float* __restrict__ hb3,
    float* __restrict__ out)
{
  const int r0 = blockIdx.x * 64;
  const int tid = threadIdx.x;
  __shared__ float zl[64][200];
  __shared__ float z2[64][50];
  for (int i = tid; i < 64*200; i += 256){
    const int r = i / 200, n = i % 200;
    zl[r][n] = z1[(size_t)(r0 + r)*224 + n];
  }
  __syncthreads();
  for (int i = tid; i < 64*50; i += 256){
    const int r = i / 50, n = i % 50;
    float s = hb2[n];
    for (int k = 0; k < 200; ++k) s += zl[r][k] * hw2[k*50 + n];
    z2[r][n] = fmaxf(s, 0.f);
  }
  __syncthreads();
  for (int i = tid; i < 128; i += 256){
    const int r = i >> 1, c = i & 1;
    float s = hb3[c];
    for (int k = 0; k < 50; ++k) s += z2[r][k] * hw3[k*2 + c];
    const int rg = r0 + r;
    const int tt = rg >> 7, b = rg & 127;
    out[(size_t)b*128 + tt*2 + c] = s;
  }
}

// ---------------------------------------------------------------------------
extern "C" void kernel_launch(void* const* d_in, const int* in_sizes, int n_in,
                              void* d_out, int out_size, void* d_ws, size_t ws_size,
                              hipStream_t stream)
{
  (void)in_sizes; (void)n_in; (void)out_size; (void)ws_size;
  const float* x_flat = (const float*)d_in[0];
  const float* enc    = (const float*)d_in[1];
  const float* h0     = (const float*)d_in[2];
  const float* c0     = (const float*)d_in[3];
  const float* cx_w0  = (const float*)d_in[4];
  const float* cx_b0  = (const float*)d_in[5];
  const float* ch_w0  = (const float*)d_in[6];
  const float* ch_b0  = (const float*)d_in[7];
  const float* cx_w1  = (const float*)d_in[8];
  const float* cx_b1  = (const float*)d_in[9];
  const float* ch_w1  = (const float*)d_in[10];
  const float* ch_b1  = (const float*)d_in[11];
  const float* ia_w0  = (const float*)d_in[12];
  const float* ia_b0  = (const float*)d_in[13];
  const float* sa_w0  = (const float*)d_in[14];
  const float* sa_b0  = (const float*)d_in[15];
  const float* ia_w1  = (const float*)d_in[16];
  const float* ia_b1  = (const float*)d_in[17];
  const float* sa_w1  = (const float*)d_in[18];
  const float* sa_b1  = (const float*)d_in[19];
  const float* hw1    = (const float*)d_in[20];
  const float* hb1    = (const float*)d_in[21];
  const float* hw2    = (const float*)d_in[22];
  const float* hb2    = (const float*)d_in[23];
  const float* hw3    = (const float*)d_in[24];
  const float* hb3    = (const float*)d_in[25];
  float* out = (float*)d_out;

  char* ws = (char*)d_ws;
  size_t off = 0;
  auto alloc = [&](size_t bytes) -> char* {
    char* p = ws + off;
    off += (bytes + 255) & ~(size_t)255;
    return p;
  };
  const size_t WPLANE = (size_t)2048*4096*2;   // one f16 weight plane (16 MB)
  const size_t TPLANE = (size_t)64*BD*2;       // one [T][B][D] f16 plane (32 MB)
  f16* wIa0 = (f16*)alloc(WPLANE);
  f16* wSa0 = (f16*)alloc(WPLANE);
  f16* wIa1 = (f16*)alloc(WPLANE);
  f16* wSa1 = (f16*)alloc(WPLANE);
  f16* w1H  = (f16*)alloc((size_t)224*2048*2);
  unsigned short* encBf = (unsigned short*)alloc((size_t)128*128*2048*2);
  f16* hr0AHi = (f16*)alloc(TPLANE);
  f16* hr0ALo = (f16*)alloc(TPLANE);   // dead after batch phase -> aliased as p1Hi
  f16* ctx0Hi = (f16*)alloc(TPLANE);   // dead after batch phase -> aliased as r1Hi
  f16* ctx0Lo = (f16*)alloc(TPLANE);   // dead after batch phase -> aliased as r1Lo
  f16* p0Hi   = (f16*)alloc(TPLANE);
  f16* p0Lo   = (f16*)alloc(TPLANE);
  f16* r0Hi   = (f16*)alloc(TPLANE);
  f16* r0Lo   = (f16*)alloc(TPLANE);
  float* partials = (float*)alloc((size_t)NPART*BD*4);
  f16* ctxHi  = (f16*)alloc((size_t)BD*2);
  f16* ctxLo  = (f16*)alloc((size_t)BD*2);
  f16* hiLo   = (f16*)alloc((size_t)BD*2);
  f16* sctxHi = (f16*)alloc((size_t)BD*2);
  f16* sctxLo = (f16*)alloc((size_t)BD*2);
  f16* hrw1Hi = (f16*)alloc((size_t)BD*2);
  f16* hrw1Lo = (f16*)alloc((size_t)BD*2);
  float* hB   = (float*)alloc((size_t)BD*4);
  float* cB   = (float*)alloc((size_t)BD*4);
  unsigned short* wpack1 = (unsigned short*)alloc((size_t)128*32*6*2);
  float* z1   = (float*)alloc((size_t)8192*224*4);
  // aliases: live ranges do not overlap within one call (graph-replay safe,
  // every buffer is fully rewritten each call before being read)
  f16* p1Hi = hr0ALo;
  f16* r1Hi = ctx0Hi;
  f16* r1Lo = ctx0Lo;

  // ---- prologue -----------------------------------------------------------
  k_transpose_f16<<<dim3(64,128),256,0,stream>>>(ia_w0, wIa0, 4096, 2048);
  k_transpose_f16<<<dim3(64,128),256,0,stream>>>(sa_w0, wSa0, 4096, 2048);
  k_transpose_f16<<<dim3(64,128),256,0,stream>>>(ia_w1, wIa1, 4096, 2048);
  k_transpose_f16<<<dim3(64,128),256,0,stream>>>(sa_w1, wSa1, 4096, 2048);
  k_transpose_f16<<<dim3(7,64),256,0,stream>>>(hw1, w1H, 2048, 200);
  k_f32_to_bf16<<<(128*128*2048/4 + 255)/256, 256, 0, stream>>>(enc, encBf, 128*128*2048/4);
  k_pack_cellw<<<16,256,0,stream>>>(ch_w1, cx_w1, wpack1);
  k_cell0<<<1024,256,0,stream>>>(x_flat, h0, c0, cx_w0, cx_b0, ch_w0, ch_b0, hr0AHi, hr0ALo);

  // ---- batched recurrence-independent layer-0 phase -----------------------
  k_inter<<<dim3(128,64),512,0,stream>>>(encBf, nullptr, hr0AHi, hr0ALo, ctx0Hi, ctx0Lo);
  k_gemm_full<<<dim3(32,64),256,0,stream>>>(hr0AHi, hr0ALo, ctx0Hi, ctx0Lo,
                                            wIa0, ia_b0, p0Hi, p0Lo);

  // ---- 64 sequential steps (8 kernels each) --------------------------------
  for (int t = 0; t < 64; ++t){
    const size_t tb = (size_t)t * BD;
    // layer 0: self-attn + sa-GEMM -> cell1
    k_self0<<<128,256,0,stream>>>(p0Hi, p0Lo, r0Hi, r0Lo, sctxHi, sctxLo, t);
    k_gemm<<<dim3(32,NPART),256,0,stream>>>(p0Hi + tb, p0Lo + tb, sctxHi, sctxLo,
                                            wSa0, partials);
    k_cell1<<<1024,256,0,stream>>>(partials, sa_b0,
        (t == 0) ? (h0 + (size_t)128*2048) : hB,
        (t == 0) ? (c0 + (size_t)128*2048) : cB,
        hB, cB, wpack1, cx_b1, ch_b1, r0Hi, r0Lo, hrw1Hi, hrw1Lo, t);
    // layer 1
    k_inter<<<dim3(128,1),512,0,stream>>>(encBf, hB, nullptr, nullptr, ctxHi, ctxLo);
    k_gemm<<<dim3(32,NPART),256,0,stream>>>(hrw1Hi, hrw1Lo, ctxHi, ctxLo,
                                            wIa1, partials);
    k_self1<<<128,256,0,stream>>>(partials, ia_b1, p1Hi, r1Hi, r1Lo, hiLo, sctxHi, sctxLo, t);
    k_gemm<<<dim3(32,NPART),256,0,stream>>>(p1Hi + tb, hiLo, sctxHi, sctxLo,
                                            wSa1, partials);
    k_epi<<<128,256,0,stream>>>(partials, sa_b1, r1Hi, r1Lo, t);
  }

  // ---- head (batched over all t,b) ----------------------------------------
  k_headgemm<<<dim3(64,7),256,0,stream>>>(r1Hi, r1Lo, w1H, hb1, z1);
  k_head2<<<128,256,0,stream>>>(z1, hw2, hb2, hw3, hb3, out);
}

// Round 5
// 9457.867 us; speedup vs baseline: 2.4646x; 1.0030x over previous
//
#include <hip/hip_runtime.h>
#include <math.h>

// ---------------------------------------------------------------------------
// CLSADecoder: 2-layer RowSharedConvLSTM + inter-attn + causal self-attn + head
// B=128, T=64, D=2048 (ROWS=8, CH=32, COLS=8), S=128.
// R4: self-attention GEMM hoisting. sctx@W_up = sum_i a_i (p[i]@W_up), so:
//  - layer0: batched Y0[t]=p0@W_low, G0[i]=p0@W_up (one 8192-row GEMM);
//    per-step sa0 GEMM replaced by weighted sum of G0 rows.
//  - layer1: per-step GEMM becomes p1[t]@[W_low|W_up] (K=2048,N=4096) giving
//    y_low and G1[t]; r1[t]=tanh(y_low + sum_i a_i G1[i] + b). p1 history gone.
// Inter-attn per-step split (128,2)+combine for BW. cell1 reads r0 planes.
// ---------------------------------------------------------------------------

typedef _Float16 f16;
typedef _Float16 f16x8 __attribute__((ext_vector_type(8)));
typedef _Float16 f16x4 __attribute__((ext_vector_type(4)));
typedef float  f32x16 __attribute__((ext_vector_type(16)));
typedef float  f32x4v __attribute__((ext_vector_type(4)));
typedef unsigned short u16x8 __attribute__((ext_vector_type(8)));
typedef unsigned short u16x4 __attribute__((ext_vector_type(4)));

#define BD 262144   // 128*2048  (one [B][D] plane)
#define NPART 16    // split-K planes for per-step ia1 GEMM

__device__ __forceinline__ unsigned short f2bf(float x){
  unsigned int u = __builtin_bit_cast(unsigned int, x);
  u += 0x7fffu + ((u >> 16) & 1u);
  return (unsigned short)(u >> 16);
}
__device__ __forceinline__ float bf2f(unsigned short h){
  unsigned int u = ((unsigned int)h) << 16;
  return __builtin_bit_cast(float, u);
}
__device__ __forceinline__ float sigmoidf_(float x){
  return 1.0f / (1.0f + __expf(-x));
}
__device__ __forceinline__ void g2l16(const void* g, void* l){
  __builtin_amdgcn_global_load_lds(
      (const __attribute__((address_space(1))) unsigned int*)g,
      (__attribute__((address_space(3))) unsigned int*)l,
      16, 0, 0);
}

// ---------------------------------------------------------------------------
// transpose f32 weight [K][N] -> f16 plane [N][K]
// ---------------------------------------------------------------------------
__global__ __launch_bounds__(256) void k_transpose_f16(
    const float* __restrict__ src, f16* __restrict__ dhi,
    const int K, const int N)
{
  __shared__ float tile[32][33];
  const int n0 = blockIdx.x * 32, k0 = blockIdx.y * 32;
  const int tx = threadIdx.x & 31, ty = threadIdx.x >> 5;
  #pragma unroll
  for (int ii = 0; ii < 4; ++ii){
    const int k = k0 + ty + ii*8, n = n0 + tx;
    float v = (n < N) ? src[(size_t)k * N + n] : 0.0f;
    tile[ty + ii*8][tx] = v;
  }
  __syncthreads();
  #pragma unroll
  for (int ii = 0; ii < 4; ++ii){
    const int n = n0 + ty + ii*8, k = k0 + tx;
    dhi[(size_t)n * K + k] = (f16)tile[tx][ty + ii*8];
  }
}

__global__ void k_f32_to_bf16(const float* __restrict__ src,
                              unsigned short* __restrict__ dst, const int n4)
{
  const int i = blockIdx.x * 256 + threadIdx.x;
  if (i < n4){
    f32x4v v = *reinterpret_cast<const f32x4v*>(src + (size_t)i * 4);
    u16x4 o;
    #pragma unroll
    for (int j = 0; j < 4; ++j) o[j] = f2bf(v[j]);
    *reinterpret_cast<u16x4*>(dst + (size_t)i * 4) = o;
  }
}

__global__ void k_pack_cellw(const float* __restrict__ chw,
                             const float* __restrict__ cxw,
                             unsigned short* __restrict__ wp)
{
  const int i = blockIdx.x * 256 + threadIdx.x;
  if (i < 128 * 32){
    #pragma unroll
    for (int k = 0; k < 3; ++k){
      wp[i*6 + k]     = f2bf(chw[i*3 + k]);
      wp[i*6 + 3 + k] = f2bf(cxw[i*3 + k]);
    }
  }
}

// ---------------------------------------------------------------------------
// Layer-0 ConvLSTM for ALL 64 steps.
// ---------------------------------------------------------------------------
__global__ __launch_bounds__(256) void k_cell0(
    const float* __restrict__ x_flat,
    const float* __restrict__ h0, const float* __restrict__ c0,
    const float* __restrict__ cxw, const float* __restrict__ cxb,
    const float* __restrict__ chw, const float* __restrict__ chb,
    f16* __restrict__ hrawHi, f16* __restrict__ hrawLo)     // [T][B][2048]
{
  const int b = blockIdx.x >> 3, row = blockIdx.x & 7;
  const int tid = threadIdx.x;
  __shared__ float h_lds[256];
  __shared__ float x_lds[8];
  __shared__ float P[128][2][8];
  const int gc = tid >> 1, ih = tid & 1;
  float wh[16][3];
  #pragma unroll
  for (int icl = 0; icl < 16; ++icl)
    #pragma unroll
    for (int k = 0; k < 3; ++k)
      wh[icl][k] = chw[(gc*32 + ih*16 + icl)*3 + k];
  const float wx0 = cxw[gc*3+0], wx1 = cxw[gc*3+1], wx2 = cxw[gc*3+2];
  const float bsum = cxb[gc] + chb[gc];
  const int ic = tid >> 3, col = tid & 7;
  const size_t dg = (size_t)b*2048 + row*256 + tid;
  float c_reg = c0[dg];
  h_lds[tid] = h0[dg];
  __syncthreads();
  for (int t = 0; t < 64; ++t){
    if (tid < 8) x_lds[tid] = x_flat[((size_t)b*64 + t)*64 + row*8 + tid];
    __syncthreads();
    float g8[8];
    #pragma unroll
    for (int c2 = 0; c2 < 8; ++c2) g8[c2] = 0.f;
    #pragma unroll
    for (int icl = 0; icl < 16; ++icl){
      const int icg = ih*16 + icl;
      f32x4v hv0 = *reinterpret_cast<const f32x4v*>(&h_lds[icg*8]);
      f32x4v hv1 = *reinterpret_cast<const f32x4v*>(&h_lds[icg*8 + 4]);
      const float hv[8] = {hv0[0],hv0[1],hv0[2],hv0[3],hv1[0],hv1[1],hv1[2],hv1[3]};
      #pragma unroll
      for (int c2 = 0; c2 < 8; ++c2){
        float s = hv[c2] * wh[icl][1];
        if (c2 > 0) s += hv[c2-1] * wh[icl][0];
        if (c2 < 7) s += hv[c2+1] * wh[icl][2];
        g8[c2] += s;
      }
    }
    if (ih == 0){
      #pragma unroll
      for (int c2 = 0; c2 < 8; ++c2){
        float s = x_lds[c2] * wx1 + bsum;
        if (c2 > 0) s += x_lds[c2-1] * wx0;
        if (c2 < 7) s += x_lds[c2+1] * wx2;
        g8[c2] += s;
      }
    }
    #pragma unroll
    for (int c2 = 0; c2 < 8; ++c2) P[gc][ih][c2] = g8[c2];
    __syncthreads();
    const float ipre = P[ic   ][0][col] + P[ic   ][1][col];
    const float fpre = P[ic+32][0][col] + P[ic+32][1][col];
    const float opre = P[ic+64][0][col] + P[ic+64][1][col];
    const float gpre = P[ic+96][0][col] + P[ic+96][1][col];
    const float cn = sigmoidf_(fpre)*c_reg + sigmoidf_(ipre)*tanhf(gpre);
    c_reg = cn;
    const float hn = sigmoidf_(opre)*tanhf(cn);
    h_lds[tid] = hn;
    const f16 hh = (f16)hn;
    hrawHi[((size_t)t*128 + b)*2048 + row*256 + tid] = hh;
    hrawLo[((size_t)t*128 + b)*2048 + row*256 + tid] = (f16)(hn - (float)hh);
    __syncthreads();
  }
}

// ---------------------------------------------------------------------------
// Layer-1 ConvLSTM for one step; x = r0[t] read from f16 hi/lo planes.
// ---------------------------------------------------------------------------
__global__ __launch_bounds__(256) void k_cell1(
    const f16* __restrict__ r0Hi, const f16* __restrict__ r0Lo,
    const float* __restrict__ h_src, const float* __restrict__ c_src,
    float* __restrict__ hB, float* __restrict__ cB,
    const unsigned short* __restrict__ wp,
    const float* __restrict__ cxb, const float* __restrict__ chb,
    f16* __restrict__ hrw1Hi, f16* __restrict__ hrw1Lo,
    const int t)
{
  const int b = blockIdx.x >> 3, row = blockIdx.x & 7;
  const int tid = threadIdx.x;
  __shared__ float x_lds[256];
  __shared__ float h_lds[256];
  __shared__ float P[128][2][8];
  __shared__ unsigned short wlds[128*32*6];
  const size_t dg = (size_t)b*2048 + row*256 + tid;
  x_lds[tid] = (float)r0Hi[(size_t)t*BD + dg] + (float)r0Lo[(size_t)t*BD + dg];
  h_lds[tid] = h_src[dg];
  for (int i = tid; i < 128*32*6; i += 256) wlds[i] = wp[i];
  __syncthreads();
  {
    const int gc = tid >> 1, ih = tid & 1;
    float g8[8];
    #pragma unroll
    for (int c2 = 0; c2 < 8; ++c2) g8[c2] = 0.f;
    #pragma unroll
    for (int icl = 0; icl < 16; ++icl){
      const int icg = ih*16 + icl;
      f32x4v hv0 = *reinterpret_cast<const f32x4v*>(&h_lds[icg*8]);
      f32x4v hv1 = *reinterpret_cast<const f32x4v*>(&h_lds[icg*8 + 4]);
      f32x4v xv0 = *reinterpret_cast<const f32x4v*>(&x_lds[icg*8]);
      f32x4v xv1 = *reinterpret_cast<const f32x4v*>(&x_lds[icg*8 + 4]);
      const float hv[8] = {hv0[0],hv0[1],hv0[2],hv0[3],hv1[0],hv1[1],hv1[2],hv1[3]};
      const float xv[8] = {xv0[0],xv0[1],xv0[2],xv0[3],xv1[0],xv1[1],xv1[2],xv1[3]};
      const unsigned short* wq = &wlds[(gc*32 + icg)*6];
      const float wh0 = bf2f(wq[0]), wh1 = bf2f(wq[1]), wh2 = bf2f(wq[2]);
      const float wx0 = bf2f(wq[3]), wx1 = bf2f(wq[4]), wx2 = bf2f(wq[5]);
      #pragma unroll
      for (int c2 = 0; c2 < 8; ++c2){
        float s = hv[c2]*wh1 + xv[c2]*wx1;
        if (c2 > 0) s += hv[c2-1]*wh0 + xv[c2-1]*wx0;
        if (c2 < 7) s += hv[c2+1]*wh2 + xv[c2+1]*wx2;
        g8[c2] += s;
      }
    }
    #pragma unroll
    for (int c2 = 0; c2 < 8; ++c2) P[gc][ih][c2] = g8[c2];
  }
  __syncthreads();
  {
    const int ic = tid >> 3, col = tid & 7;
    const float ipre = P[ic   ][0][col] + P[ic   ][1][col] + cxb[ic]    + chb[ic];
    const float fpre = P[ic+32][0][col] + P[ic+32][1][col] + cxb[ic+32] + chb[ic+32];
    const float opre = P[ic+64][0][col] + P[ic+64][1][col] + cxb[ic+64] + chb[ic+64];
    const float gpre = P[ic+96][0][col] + P[ic+96][1][col] + cxb[ic+96] + chb[ic+96];
    const float c_old = c_src[dg];
    const float cn = sigmoidf_(fpre)*c_old + sigmoidf_(ipre)*tanhf(gpre);
    cB[dg] = cn;
    const float hraw = sigmoidf_(opre)*tanhf(cn);
    hB[dg] = hraw;
    const f16 hh = (f16)hraw;
    hrw1Hi[dg] = hh;
    hrw1Lo[dg] = (f16)(hraw - (float)hh);
  }
}

// ---------------------------------------------------------------------------
// Batched inter-attention (layer 0, all t): block (b, t), 8 waves x 16 rows.
// ---------------------------------------------------------------------------
__global__ __launch_bounds__(512) void k_inter_b(
    const unsigned short* __restrict__ encBf,
    const f16* __restrict__ stHi, const f16* __restrict__ stLo,   // [T][B][2048]
    f16* __restrict__ ctxHi, f16* __restrict__ ctxLo)
{
  const int b = blockIdx.x;
  const size_t so = (size_t)blockIdx.y * BD + (size_t)b * 2048;
  const int tid = threadIdx.x;
  const int lane = tid & 63, wv = tid >> 6;
  __shared__ float wav[8][2048];
  __shared__ float wm[8], wl[8];
  float sv[32], av[32];
  #pragma unroll
  for (int p = 0; p < 4; ++p){
    const int d = (p*64 + lane)*8;
    f16x8 hh = *reinterpret_cast<const f16x8*>(stHi + so + d);
    f16x8 ll = *reinterpret_cast<const f16x8*>(stLo + so + d);
    #pragma unroll
    for (int j = 0; j < 8; ++j){ sv[p*8+j] = (float)hh[j] + (float)ll[j]; av[p*8+j] = 0.f; }
  }
  float m = -INFINITY, l = 0.f;
  const int s0 = wv*16;
  for (int r = 0; r < 16; ++r){
    const unsigned short* er = encBf + ((size_t)b*128 + s0 + r)*2048;
    float ef[32];
    float dot = 0.f;
    #pragma unroll
    for (int p = 0; p < 4; ++p){
      u16x8 ev = *reinterpret_cast<const u16x8*>(er + (p*64 + lane)*8);
      #pragma unroll
      for (int j = 0; j < 8; ++j){ const float e = bf2f(ev[j]); ef[p*8+j] = e; dot += e * sv[p*8+j]; }
    }
    #pragma unroll
    for (int off = 1; off < 64; off <<= 1) dot += __shfl_xor(dot, off);
    if (dot > m){
      const float scf = __expf(m - dot);
      l *= scf;
      #pragma unroll
      for (int q = 0; q < 32; ++q) av[q] *= scf;
      m = dot;
    }
    const float pp = __expf(dot - m);
    l += pp;
    #pragma unroll
    for (int q = 0; q < 32; ++q) av[q] += pp * ef[q];
  }
  #pragma unroll
  for (int p = 0; p < 4; ++p){
    const int d = (p*64 + lane)*8;
    f32x4v v0, v1;
    #pragma unroll
    for (int j = 0; j < 4; ++j){ v0[j] = av[p*8+j]; v1[j] = av[p*8+4+j]; }
    *reinterpret_cast<f32x4v*>(&wav[wv][d]) = v0;
    *reinterpret_cast<f32x4v*>(&wav[wv][d+4]) = v1;
  }
  if (lane == 0){ wm[wv] = m; wl[wv] = l; }
  __syncthreads();
  float M = wm[0];
  #pragma unroll
  for (int i = 1; i < 8; ++i) M = fmaxf(M, wm[i]);
  float U[8];
  float L = 0.f;
  #pragma unroll
  for (int i = 0; i < 8; ++i){ U[i] = __expf(wm[i] - M); L += wl[i] * U[i]; }
  const float Linv = 1.f / L;
  const int d0 = tid * 4;
  float acc[4] = {0.f, 0.f, 0.f, 0.f};
  #pragma unroll
  for (int w = 0; w < 8; ++w){
    f32x4v v = *reinterpret_cast<const f32x4v*>(&wav[w][d0]);
    #pragma unroll
    for (int j = 0; j < 4; ++j) acc[j] += U[w] * v[j];
  }
  f16x4 hh, ll;
  #pragma unroll
  for (int j = 0; j < 4; ++j){
    const float v = acc[j] * Linv;
    hh[j] = (f16)v;
    ll[j] = (f16)(v - (float)hh[j]);
  }
  *reinterpret_cast<f16x4*>(ctxHi + so + d0) = hh;
  *reinterpret_cast<f16x4*>(ctxLo + so + d0) = ll;
}

// ---------------------------------------------------------------------------
// Per-step inter-attention, split over 2 encoder chunks. State = hB (f32).
// ---------------------------------------------------------------------------
__global__ __launch_bounds__(512) void k_inter_part(
    const unsigned short* __restrict__ encBf,
    const float* __restrict__ stF,
    float* __restrict__ pctx, float* __restrict__ pm, float* __restrict__ pl)
{
  const int b = blockIdx.x, sc = blockIdx.y;
  const int tid = threadIdx.x;
  const int lane = tid & 63, wv = tid >> 6;
  __shared__ float wav[8][2048];
  __shared__ float wm[8], wl[8];
  float sv[32], av[32];
  #pragma unroll
  for (int p = 0; p < 4; ++p){
    const int d = (p*64 + lane)*8;
    f32x4v v0 = *reinterpret_cast<const f32x4v*>(stF + (size_t)b*2048 + d);
    f32x4v v1 = *reinterpret_cast<const f32x4v*>(stF + (size_t)b*2048 + d + 4);
    #pragma unroll
    for (int j = 0; j < 4; ++j){ sv[p*8+j] = v0[j]; sv[p*8+4+j] = v1[j]; }
    #pragma unroll
    for (int j = 0; j < 8; ++j) av[p*8+j] = 0.f;
  }
  float m = -INFINITY, l = 0.f;
  const int s0 = sc*64 + wv*8;
  for (int r = 0; r < 8; ++r){
    const unsigned short* er = encBf + ((size_t)b*128 + s0 + r)*2048;
    float ef[32];
    float dot = 0.f;
    #pragma unroll
    for (int p = 0; p < 4; ++p){
      u16x8 ev = *reinterpret_cast<const u16x8*>(er + (p*64 + lane)*8);
      #pragma unroll
      for (int j = 0; j < 8; ++j){ const float e = bf2f(ev[j]); ef[p*8+j] = e; dot += e * sv[p*8+j]; }
    }
    #pragma unroll
    for (int off = 1; off < 64; off <<= 1) dot += __shfl_xor(dot, off);
    if (dot > m){
      const float scf = __expf(m - dot);
      l *= scf;
      #pragma unroll
      for (int q = 0; q < 32; ++q) av[q] *= scf;
      m = dot;
    }
    const float pp = __expf(dot - m);
    l += pp;
    #pragma unroll
    for (int q = 0; q < 32; ++q) av[q] += pp * ef[q];
  }
  #pragma unroll
  for (int p = 0; p < 4; ++p){
    const int d = (p*64 + lane)*8;
    f32x4v v0, v1;
    #pragma unroll
    for (int j = 0; j < 4; ++j){ v0[j] = av[p*8+j]; v1[j] = av[p*8+4+j]; }
    *reinterpret_cast<f32x4v*>(&wav[wv][d]) = v0;
    *reinterpret_cast<f32x4v*>(&wav[wv][d+4]) = v1;
  }
  if (lane == 0){ wm[wv] = m; wl[wv] = l; }
  __syncthreads();
  float M = wm[0];
  #pragma unroll
  for (int i = 1; i < 8; ++i) M = fmaxf(M, wm[i]);
  float U[8];
  float L = 0.f;
  #pragma unroll
  for (int i = 0; i < 8; ++i){ U[i] = __expf(wm[i] - M); L += wl[i] * U[i]; }
  const int d0 = tid * 4;
  float acc[4] = {0.f, 0.f, 0.f, 0.f};
  #pragma unroll
  for (int w = 0; w < 8; ++w){
    f32x4v v = *reinterpret_cast<const f32x4v*>(&wav[w][d0]);
    #pragma unroll
    for (int j = 0; j < 4; ++j) acc[j] += U[w] * v[j];
  }
  f32x4v o;
  #pragma unroll
  for (int j = 0; j < 4; ++j) o[j] = acc[j];
  *reinterpret_cast<f32x4v*>(pctx + ((size_t)b*2 + sc)*2048 + d0) = o;
  if (tid == 0){ pm[b*2 + sc] = M; pl[b*2 + sc] = L; }
}

__global__ __launch_bounds__(256) void k_inter_comb(
    const float* __restrict__ pctx, const float* __restrict__ pm,
    const float* __restrict__ pl,
    f16* __restrict__ ctxHi, f16* __restrict__ ctxLo)
{
  const int b = blockIdx.x, tid = threadIdx.x;
  const float m0 = pm[b*2+0], m1 = pm[b*2+1];
  const float M = fmaxf(m0, m1);
  const float u0 = __expf(m0-M), u1 = __expf(m1-M);
  const float L = pl[b*2+0]*u0 + pl[b*2+1]*u1;
  const float Linv = 1.f / L;
  const int d0 = tid*8;
  const float* q0 = pctx + ((size_t)b*2 + 0)*2048 + d0;
  const float* q1 = pctx + ((size_t)b*2 + 1)*2048 + d0;
  f16x8 hh, ll;
  #pragma unroll
  for (int h = 0; h < 2; ++h){
    f32x4v a = *reinterpret_cast<const f32x4v*>(q0 + h*4);
    f32x4v c = *reinterpret_cast<const f32x4v*>(q1 + h*4);
    #pragma unroll
    for (int j = 0; j < 4; ++j){
      const float v = (u0*a[j] + u1*c[j]) * Linv;
      hh[h*4+j] = (f16)v;
      ll[h*4+j] = (f16)(v - (float)hh[h*4+j]);
    }
  }
  *reinterpret_cast<f16x8*>(ctxHi + (size_t)b*2048 + d0) = hh;
  *reinterpret_cast<f16x8*>(ctxLo + (size_t)b*2048 + d0) = ll;
}

// ---------------------------------------------------------------------------
// Per-step ia1 GEMM: y = [hrw1|ctx1](128x4096) @ W(4096x2048), f16 2-pass.
// Grid (32 nt, 16 kc). Writes f32 partials [16][128][2048].
// ---------------------------------------------------------------------------
__global__ __launch_bounds__(256, 2) void k_gemm(
    const f16* __restrict__ a0Hi, const f16* __restrict__ a0Lo,
    const f16* __restrict__ a1Hi, const f16* __restrict__ a1Lo,
    const f16* __restrict__ wHp,
    float* __restrict__ partials)
{
  const int nt = blockIdx.x;
  const int kc = blockIdx.y;
  const int tid = threadIdx.x;
  const int lane = tid & 63, wv = tid >> 6;
  __shared__ __align__(16) char lds[81920];
  const f16* aH = (kc < 8) ? a0Hi : a1Hi;
  const f16* aL = (kc < 8) ? a0Lo : a1Lo;
  const int kA = (kc & 7) * 256;
  const f16* wH = wHp + (size_t)(nt*64)*4096 + kc*256;

  auto stage = [&](int buf, int ki){
    char* lb = lds + buf*40960;
    const int ke = kA + ki*64;
    #pragma unroll
    for (int i = 0; i < 4; ++i){
      const int c = i*256 + tid, row = c >> 3;
      const int srcb = ((c & 7)*16) ^ ((row & 7) << 4);
      g2l16((const char*)(aH + (size_t)row*2048 + ke) + srcb, lb + c*16);
      g2l16((const char*)(aL + (size_t)row*2048 + ke) + srcb, lb + 16384 + c*16);
    }
    #pragma unroll
    for (int i = 0; i < 2; ++i){
      const int c = i*256 + tid, row = c >> 3;
      const int srcb = ((c & 7)*16) ^ ((row & 7) << 4);
      g2l16((const char*)(wH + (size_t)row*4096 + ki*64) + srcb, lb + 32768 + c*16);
    }
  };

  f32x16 acc0, acc1;
  #pragma unroll
  for (int r = 0; r < 16; ++r){ acc0[r] = 0.f; acc1[r] = 0.f; }
  const int rA = wv*32 + (lane & 31);
  const int kb = lane >> 5;
  const int rB0 = lane & 31;
  const int aswz = (rA & 7) << 4;
  const int bswz = (rB0 & 7) << 4;

  stage(0, 0);
  __syncthreads();
  for (int ki = 0; ki < 4; ++ki){
    const int buf = ki & 1;
    if (ki < 3) stage(buf ^ 1, ki + 1);
    const char* lb = lds + buf*40960;
    #pragma unroll
    for (int s = 0; s < 4; ++s){
      const int cb = s*32 + kb*16;
      f16x8 ah  = *reinterpret_cast<const f16x8*>(lb + rA*128 + (cb ^ aswz));
      f16x8 al  = *reinterpret_cast<const f16x8*>(lb + 16384 + rA*128 + (cb ^ aswz));
      f16x8 b0h = *reinterpret_cast<const f16x8*>(lb + 32768 + rB0*128 + (cb ^ bswz));
      f16x8 b1h = *reinterpret_cast<const f16x8*>(lb + 32768 + 4096 + rB0*128 + (cb ^ bswz));
      acc0 = __builtin_amdgcn_mfma_f32_32x32x16_f16(ah, b0h, acc0, 0, 0, 0);
      acc1 = __builtin_amdgcn_mfma_f32_32x32x16_f16(ah, b1h, acc1, 0, 0, 0);
      acc0 = __builtin_amdgcn_mfma_f32_32x32x16_f16(al, b0h, acc0, 0, 0, 0);
      acc1 = __builtin_amdgcn_mfma_f32_32x32x16_f16(al, b1h, acc1, 0, 0, 0);
    }
    __syncthreads();
  }

  float* outp = partials + (size_t)kc*BD + (size_t)(nt*64 + (lane & 31));
  const int rowBase = wv*32 + 4*kb;
  #pragma unroll
  for (int r = 0; r < 16; ++r){
    const int rr = rowBase + (r & 3) + 8*(r >> 2);
    outp[(size_t)rr*2048]      = acc0[r];
    outp[(size_t)rr*2048 + 32] = acc1[r];
  }
}

// ---------------------------------------------------------------------------
// Batched full-K ia0 GEMM (all t): out p0[t] = tanh(y + bias), f16 hi/lo.
// ---------------------------------------------------------------------------
__global__ __launch_bounds__(256, 2) void k_gemm_full(
    const f16* __restrict__ a0Hi, const f16* __restrict__ a0Lo,
    const f16* __restrict__ a1Hi, const f16* __restrict__ a1Lo,
    const f16* __restrict__ wHp, const float* __restrict__ bias,
    f16* __restrict__ outHi, f16* __restrict__ outLo)
{
  const int nt = blockIdx.x, t = blockIdx.y;
  const size_t tb = (size_t)t * BD;
  const int tid = threadIdx.x;
  const int lane = tid & 63, wv = tid >> 6;
  __shared__ __align__(16) char lds[81920];
  const f16* wH = wHp + (size_t)(nt*64)*4096;

  auto stage = [&](int buf, int ki){
    char* lb = lds + buf*40960;
    const f16* aH = ((ki < 32) ? a0Hi : a1Hi) + tb;
    const f16* aL = ((ki < 32) ? a0Lo : a1Lo) + tb;
    const int ke = (ki & 31) * 64;
    #pragma unroll
    for (int i = 0; i < 4; ++i){
      const int c = i*256 + tid, row = c >> 3;
      const int srcb = ((c & 7)*16) ^ ((row & 7) << 4);
      g2l16((const char*)(aH + (size_t)row*2048 + ke) + srcb, lb + c*16);
      g2l16((const char*)(aL + (size_t)row*2048 + ke) + srcb, lb + 16384 + c*16);
    }
    #pragma unroll
    for (int i = 0; i < 2; ++i){
      const int c = i*256 + tid, row = c >> 3;
      const int srcb = ((c & 7)*16) ^ ((row & 7) << 4);
      g2l16((const char*)(wH + (size_t)row*4096 + ki*64) + srcb, lb + 32768 + c*16);
    }
  };

  f32x16 acc0, acc1;
  #pragma unroll
  for (int r = 0; r < 16; ++r){ acc0[r] = 0.f; acc1[r] = 0.f; }
  const int rA = wv*32 + (lane & 31);
  const int kb = lane >> 5;
  const int rB0 = lane & 31;
  const int aswz = (rA & 7) << 4;
  const int bswz = (rB0 & 7) << 4;

  stage(0, 0);
  __syncthreads();
  for (int ki = 0; ki < 64; ++ki){
    const int buf = ki & 1;
    if (ki < 63) stage(buf ^ 1, ki + 1);
    const char* lb = lds + buf*40960;
    #pragma unroll
    for (int s = 0; s < 4; ++s){
      const int cb = s*32 + kb*16;
      f16x8 ah  = *reinterpret_cast<const f16x8*>(lb + rA*128 + (cb ^ aswz));
      f16x8 al  = *reinterpret_cast<const f16x8*>(lb + 16384 + rA*128 + (cb ^ aswz));
      f16x8 b0h = *reinterpret_cast<const f16x8*>(lb + 32768 + rB0*128 + (cb ^ bswz));
      f16x8 b1h = *reinterpret_cast<const f16x8*>(lb + 32768 + 4096 + rB0*128 + (cb ^ bswz));
      acc0 = __builtin_amdgcn_mfma_f32_32x32x16_f16(ah, b0h, acc0, 0, 0, 0);
      acc1 = __builtin_amdgcn_mfma_f32_32x32x16_f16(ah, b1h, acc1, 0, 0, 0);
      acc0 = __builtin_amdgcn_mfma_f32_32x32x16_f16(al, b0h, acc0, 0, 0, 0);
      acc1 = __builtin_amdgcn_mfma_f32_32x32x16_f16(al, b1h, acc1, 0, 0, 0);
    }
    __syncthreads();
  }

  const int col0 = nt*64 + (lane & 31);
  const float b0 = bias[col0], b1 = bias[col0 + 32];
  const int rowBase = wv*32 + 4*kb;
  #pragma unroll
  for (int r = 0; r < 16; ++r){
    const int rr = rowBase + (r & 3) + 8*(r >> 2);
    const size_t o = tb + (size_t)rr*2048 + col0;
    const float p = tanhf(acc0[r] + b0);
    const float q = tanhf(acc1[r] + b1);
    const f16 ph = (f16)p, qh = (f16)q;
    outHi[o]      = ph;  outLo[o]      = (f16)(p - (float)ph);
    outHi[o + 32] = qh;  outLo[o + 32] = (f16)(q - (float)qh);
  }
}

// ---------------------------------------------------------------------------
// Batched sa0 GEMM (all t): A = p0 hi/lo, W = [Wlow^T|Wup^T] ([4096][2048]).
// nt<32 -> Y0 (f32, raw); nt>=32 -> G0 (f16). Grid (64 nt, 64 t), K=2048.
// ---------------------------------------------------------------------------
__global__ __launch_bounds__(256, 2) void k_gemm_full2(
    const f16* __restrict__ aHi, const f16* __restrict__ aLo,   // [T][B][2048]
    const f16* __restrict__ wSp,                                // [4096][2048]
    float* __restrict__ Y0, f16* __restrict__ G0)               // [T][B][2048]
{
  const int nt = blockIdx.x, t = blockIdx.y;
  const size_t tb = (size_t)t * BD;
  const int tid = threadIdx.x;
  const int lane = tid & 63, wv = tid >> 6;
  __shared__ __align__(16) char lds[81920];
  const f16* wH = wSp + (size_t)(nt*64)*2048;
  const f16* aH = aHi + tb;
  const f16* aL = aLo + tb;

  auto stage = [&](int buf, int ki){
    char* lb = lds + buf*40960;
    const int ke = ki*64;
    #pragma unroll
    for (int i = 0; i < 4; ++i){
      const int c = i*256 + tid, row = c >> 3;
      const int srcb = ((c & 7)*16) ^ ((row & 7) << 4);
      g2l16((const char*)(aH + (size_t)row*2048 + ke) + srcb, lb + c*16);
      g2l16((const char*)(aL + (size_t)row*2048 + ke) + srcb, lb + 16384 + c*16);
    }
    #pragma unroll
    for (int i = 0; i < 2; ++i){
      const int c = i*256 + tid, row = c >> 3;
      const int srcb = ((c & 7)*16) ^ ((row & 7) << 4);
      g2l16((const char*)(wH + (size_t)row*2048 + ke) + srcb, lb + 32768 + c*16);
    }
  };

  f32x16 acc0, acc1;
  #pragma unroll
  for (int r = 0; r < 16; ++r){ acc0[r] = 0.f; acc1[r] = 0.f; }
  const int rA = wv*32 + (lane & 31);
  const int kb = lane >> 5;
  const int rB0 = lane & 31;
  const int aswz = (rA & 7) << 4;
  const int bswz = (rB0 & 7) << 4;

  stage(0, 0);
  __syncthreads();
  for (int ki = 0; ki < 32; ++ki){
    const int buf = ki & 1;
    if (ki < 31) stage(buf ^ 1, ki + 1);
    const char* lb = lds + buf*40960;
    #pragma unroll
    for (int s = 0; s < 4; ++s){
      const int cb = s*32 + kb*16;
      f16x8 ah  = *reinterpret_cast<const f16x8*>(lb + rA*128 + (cb ^ aswz));
      f16x8 al  = *reinterpret_cast<const f16x8*>(lb + 16384 + rA*128 + (cb ^ aswz));
      f16x8 b0h = *reinterpret_cast<const f16x8*>(lb + 32768 + rB0*128 + (cb ^ bswz));
      f16x8 b1h = *reinterpret_cast<const f16x8*>(lb + 32768 + 4096 + rB0*128 + (cb ^ bswz));
      acc0 = __builtin_amdgcn_mfma_f32_32x32x16_f16(ah, b0h, acc0, 0, 0, 0);
      acc1 = __builtin_amdgcn_mfma_f32_32x32x16_f16(ah, b1h, acc1, 0, 0, 0);
      acc0 = __builtin_amdgcn_mfma_f32_32x32x16_f16(al, b0h, acc0, 0, 0, 0);
      acc1 = __builtin_amdgcn_mfma_f32_32x32x16_f16(al, b1h, acc1, 0, 0, 0);
    }
    __syncthreads();
  }

  const int col0 = nt*64 + (lane & 31);
  const int rowBase = wv*32 + 4*kb;
  if (nt < 32){
    float* yp = Y0 + tb + col0;
    #pragma unroll
    for (int r = 0; r < 16; ++r){
      const int rr = rowBase + (r & 3) + 8*(r >> 2);
      yp[(size_t)rr*2048]      = acc0[r];
      yp[(size_t)rr*2048 + 32] = acc1[r];
    }
  } else {
    f16* gp = G0 + tb + (col0 - 2048);
    #pragma unroll
    for (int r = 0; r < 16; ++r){
      const int rr = rowBase + (r & 3) + 8*(r >> 2);
      gp[(size_t)rr*2048]      = (f16)acc0[r];
      gp[(size_t)rr*2048 + 32] = (f16)acc1[r];
    }
  }
}

// ---------------------------------------------------------------------------
// Per-step sa1 GEMM: A = p1[t] hi/lo (128x2048), W = [4096][2048].
// Grid (64 nt, 8 kc). Writes f32 partials [8][128][4096].
// ---------------------------------------------------------------------------
__global__ __launch_bounds__(256, 2) void k_gemm_sa1(
    const f16* __restrict__ aHi, const f16* __restrict__ aLo,   // [B][2048]
    const f16* __restrict__ wSp,
    float* __restrict__ partials)
{
  const int nt = blockIdx.x;
  const int kc = blockIdx.y;     // 0..7, 256-k chunk
  const int tid = threadIdx.x;
  const int lane = tid & 63, wv = tid >> 6;
  __shared__ __align__(16) char lds[81920];
  const f16* wH = wSp + (size_t)(nt*64)*2048 + kc*256;

  auto stage = [&](int buf, int ki){
    char* lb = lds + buf*40960;
    const int ke = kc*256 + ki*64;
    #pragma unroll
    for (int i = 0; i < 4; ++i){
      const int c = i*256 + tid, row = c >> 3;
      const int srcb = ((c & 7)*16) ^ ((row & 7) << 4);
      g2l16((const char*)(aHi + (size_t)row*2048 + ke) + srcb, lb + c*16);
      g2l16((const char*)(aLo + (size_t)row*2048 + ke) + srcb, lb + 16384 + c*16);
    }
    #pragma unroll
    for (int i = 0; i < 2; ++i){
      const int c = i*256 + tid, row = c >> 3;
      const int srcb = ((c & 7)*16) ^ ((row & 7) << 4);
      g2l16((const char*)(wH + (size_t)row*2048 + ki*64) + srcb, lb + 32768 + c*16);
    }
  };

  f32x16 acc0, acc1;
  #pragma unroll
  for (int r = 0; r < 16; ++r){ acc0[r] = 0.f; acc1[r] = 0.f; }
  const int rA = wv*32 + (lane & 31);
  const int kb = lane >> 5;
  const int rB0 = lane & 31;
  const int aswz = (rA & 7) << 4;
  const int bswz = (rB0 & 7) << 4;

  stage(0, 0);
  __syncthreads();
  for (int ki = 0; ki < 4; ++ki){
    const int buf = ki & 1;
    if (ki < 3) stage(buf ^ 1, ki + 1);
    const char* lb = lds + buf*40960;
    #pragma unroll
    for (int s = 0; s < 4; ++s){
      const int cb = s*32 + kb*16;
      f16x8 ah  = *reinterpret_cast<const f16x8*>(lb + rA*128 + (cb ^ aswz));
      f16x8 al  = *reinterpret_cast<const f16x8*>(lb + 16384 + rA*128 + (cb ^ aswz));
      f16x8 b0h = *reinterpret_cast<const f16x8*>(lb + 32768 + rB0*128 + (cb ^ bswz));
      f16x8 b1h = *reinterpret_cast<const f16x8*>(lb + 32768 + 4096 + rB0*128 + (cb ^ bswz));
      acc0 = __builtin_amdgcn_mfma_f32_32x32x16_f16(ah, b0h, acc0, 0, 0, 0);
      acc1 = __builtin_amdgcn_mfma_f32_32x32x16_f16(ah, b1h, acc1, 0, 0, 0);
      acc0 = __builtin_amdgcn_mfma_f32_32x32x16_f16(al, b0h, acc0, 0, 0, 0);
      acc1 = __builtin_amdgcn_mfma_f32_32x32x16_f16(al, b1h, acc1, 0, 0, 0);
    }
    __syncthreads();
  }

  float* outp = partials + (size_t)kc*(128*4096) + (size_t)(nt*64 + (lane & 31));
  const int rowBase = wv*32 + 4*kb;
  #pragma unroll
  for (int r = 0; r < 16; ++r){
    const int rr = rowBase + (r & 3) + 8*(r >> 2);
    outp[(size_t)rr*4096]      = acc0[r];
    outp[(size_t)rr*4096 + 32] = acc1[r];
  }
}

// ---------------------------------------------------------------------------
// Layer-0 step: scores vs r0 hist, softmax, y = Y0[t] + sum a*G0 + bias,
// r0[t] = tanh(y). Block per b.
// ---------------------------------------------------------------------------
__global__ __launch_bounds__(256) void k_step0(
    const f16* __restrict__ p0Hi, const f16* __restrict__ p0Lo,
    f16* __restrict__ r0Hi, f16* __restrict__ r0Lo,
    const float* __restrict__ Y0, const f16* __restrict__ G0,
    const float* __restrict__ sab0, const int t)
{
  const int b = blockIdx.x, tid = threadIdx.x;
  __shared__ float sc[64];
  __shared__ float a_lds[64];
  const int lane = tid & 63, wv = tid >> 6;
  float hreg[32];
  #pragma unroll
  for (int jj = 0; jj < 4; ++jj){
    const int d = (jj*64 + lane)*8;
    f16x8 h8 = *reinterpret_cast<const f16x8*>(p0Hi + ((size_t)t*128 + b)*2048 + d);
    f16x8 l8 = *reinterpret_cast<const f16x8*>(p0Lo + ((size_t)t*128 + b)*2048 + d);
    #pragma unroll
    for (int j = 0; j < 8; ++j) hreg[jj*8+j] = (float)h8[j] + (float)l8[j];
  }
  for (int i = wv; i < t; i += 4){
    const f16* rh = r0Hi + ((size_t)i*128 + b)*2048;
    const f16* rl = r0Lo + ((size_t)i*128 + b)*2048;
    float dot = 0.f;
    #pragma unroll
    for (int jj = 0; jj < 4; ++jj){
      const int d = (jj*64 + lane)*8;
      f16x8 h8 = *reinterpret_cast<const f16x8*>(rh + d);
      f16x8 l8 = *reinterpret_cast<const f16x8*>(rl + d);
      #pragma unroll
      for (int j = 0; j < 8; ++j)
        dot += ((float)h8[j] + (float)l8[j]) * hreg[jj*8+j];
    }
    #pragma unroll
    for (int off = 1; off < 64; off <<= 1) dot += __shfl_xor(dot, off);
    if (lane == 0) sc[i] = dot;
  }
  __syncthreads();
  if (t > 0 && tid < 64){
    const float s = (tid < t) ? sc[tid] : -INFINITY;
    float mm = s;
    #pragma unroll
    for (int off = 1; off < 64; off <<= 1) mm = fmaxf(mm, __shfl_xor(mm, off));
    const float e = (tid < t) ? __expf(s - mm) : 0.f;
    float sum = e;
    #pragma unroll
    for (int off = 1; off < 64; off <<= 1) sum += __shfl_xor(sum, off);
    a_lds[tid] = e / sum;
  }
  __syncthreads();
  const int d0 = tid*8;
  float y[8];
  {
    f32x4v y0 = *reinterpret_cast<const f32x4v*>(Y0 + (size_t)t*BD + (size_t)b*2048 + d0);
    f32x4v y1 = *reinterpret_cast<const f32x4v*>(Y0 + (size_t)t*BD + (size_t)b*2048 + d0 + 4);
    #pragma unroll
    for (int j = 0; j < 4; ++j){ y[j] = y0[j]; y[4+j] = y1[j]; }
  }
  if (t > 0){
    for (int i = 0; i < t; ++i){
      const float a = a_lds[i];
      f16x8 g8 = *reinterpret_cast<const f16x8*>(G0 + ((size_t)i*128 + b)*2048 + d0);
      #pragma unroll
      for (int j = 0; j < 8; ++j) y[j] += a * (float)g8[j];
    }
  }
  f32x4v bb0 = *reinterpret_cast<const f32x4v*>(sab0 + d0);
  f32x4v bb1 = *reinterpret_cast<const f32x4v*>(sab0 + d0 + 4);
  f16x8 hh, ll;
  #pragma unroll
  for (int j = 0; j < 4; ++j){
    const float a = tanhf(y[j] + bb0[j]);
    const float c = tanhf(y[4+j] + bb1[j]);
    hh[j] = (f16)a;   ll[j] = (f16)(a - (float)hh[j]);
    hh[4+j] = (f16)c; ll[4+j] = (f16)(c - (float)hh[4+j]);
  }
  *reinterpret_cast<f16x8*>(r0Hi + ((size_t)t*128 + b)*2048 + d0) = hh;
  *reinterpret_cast<f16x8*>(r0Lo + ((size_t)t*128 + b)*2048 + d0) = ll;
}

// ---------------------------------------------------------------------------
// Layer-1 self phase 1: p1 = tanh(sum ia1-partials + bias); scores vs r1;
// softmax weights -> aG. Block per b.
// ---------------------------------------------------------------------------
__global__ __launch_bounds__(256) void k_self1(
    const float* __restrict__ partials,       // [16][128][2048]
    const float* __restrict__ bias,
    f16* __restrict__ p1Hi, f16* __restrict__ p1Lo,
    const f16* __restrict__ r1Hi, const f16* __restrict__ r1Lo,
    float* __restrict__ aG, const int t)
{
  const int b = blockIdx.x, tid = threadIdx.x;
  __shared__ float hi_lds[2048];
  __shared__ float sc[64];
  const int d0 = tid*8;
  {
    f32x4v y0, y1;
    #pragma unroll
    for (int j = 0; j < 4; ++j){ y0[j] = 0.f; y1[j] = 0.f; }
    #pragma unroll
    for (int p = 0; p < NPART; ++p){
      const float* pp = partials + (size_t)p*BD + (size_t)b*2048 + d0;
      f32x4v v0 = *reinterpret_cast<const f32x4v*>(pp);
      f32x4v v1 = *reinterpret_cast<const f32x4v*>(pp + 4);
      #pragma unroll
      for (int j = 0; j < 4; ++j){ y0[j] += v0[j]; y1[j] += v1[j]; }
    }
    f32x4v bb0 = *reinterpret_cast<const f32x4v*>(bias + d0);
    f32x4v bb1 = *reinterpret_cast<const f32x4v*>(bias + d0 + 4);
    f16x8 hh, ll;
    #pragma unroll
    for (int j = 0; j < 4; ++j){
      const float a = tanhf(y0[j] + bb0[j]);
      const float c = tanhf(y1[j] + bb1[j]);
      hi_lds[d0 + j] = a; hi_lds[d0 + 4 + j] = c;
      hh[j] = (f16)a;   ll[j] = (f16)(a - (float)hh[j]);
      hh[4+j] = (f16)c; ll[4+j] = (f16)(c - (float)hh[4+j]);
    }
    *reinterpret_cast<f16x8*>(p1Hi + (size_t)b*2048 + d0) = hh;
    *reinterpret_cast<f16x8*>(p1Lo + (size_t)b*2048 + d0) = ll;
  }
  __syncthreads();
  const int lane = tid & 63, wv = tid >> 6;
  float hreg[32];
  #pragma unroll
  for (int jj = 0; jj < 4; ++jj){
    const int d = (jj*64 + lane)*8;
    f32x4v v0 = *reinterpret_cast<const f32x4v*>(&hi_lds[d]);
    f32x4v v1 = *reinterpret_cast<const f32x4v*>(&hi_lds[d+4]);
    #pragma unroll
    for (int j = 0; j < 4; ++j){ hreg[jj*8+j] = v0[j]; hreg[jj*8+4+j] = v1[j]; }
  }
  for (int i = wv; i < t; i += 4){
    const f16* rh = r1Hi + ((size_t)i*128 + b)*2048;
    const f16* rl = r1Lo + ((size_t)i*128 + b)*2048;
    float dot = 0.f;
    #pragma unroll
    for (int jj = 0; jj < 4; ++jj){
      const int d = (jj*64 + lane)*8;
      f16x8 h8 = *reinterpret_cast<const f16x8*>(rh + d);
      f16x8 l8 = *reinterpret_cast<const f16x8*>(rl + d);
      #pragma unroll
      for (int j = 0; j < 8; ++j)
        dot += ((float)h8[j] + (float)l8[j]) * hreg[jj*8+j];
    }
    #pragma unroll
    for (int off = 1; off < 64; off <<= 1) dot += __shfl_xor(dot, off);
    if (lane == 0) sc[i] = dot;
  }
  __syncthreads();
  if (t > 0 && tid < 64){
    const float s = (tid < t) ? sc[tid] : -INFINITY;
    float mm = s;
    #pragma unroll
    for (int off = 1; off < 64; off <<= 1) mm = fmaxf(mm, __shfl_xor(mm, off));
    const float e = (tid < t) ? __expf(s - mm) : 0.f;
    float sum = e;
    #pragma unroll
    for (int off = 1; off < 64; off <<= 1) sum += __shfl_xor(sum, off);
    aG[b*64 + tid] = e / sum;
  }
}

// ---------------------------------------------------------------------------
// Layer-1 finish: r1[t] = tanh(sum low-partials + bias + sum_i a_i G1[i]);
// G1[t] = sum high-partials. Block per b.
// ---------------------------------------------------------------------------
__global__ __launch_bounds__(256) void k_fin1(
    const float* __restrict__ partials,       // [8][128][4096]
    const float* __restrict__ sab1,
    const float* __restrict__ aG,
    f16* __restrict__ G1,                     // [T][B][2048]
    f16* __restrict__ r1Hi, f16* __restrict__ r1Lo,
    const int t)
{
  const int b = blockIdx.x, tid = threadIdx.x;
  const int d0 = tid*8;
  float y[8], g[8];
  #pragma unroll
  for (int j = 0; j < 8; ++j){ y[j] = 0.f; g[j] = 0.f; }
  #pragma unroll
  for (int p = 0; p < 8; ++p){
    const float* base = partials + (size_t)p*(128*4096) + (size_t)b*4096;
    f32x4v v0 = *reinterpret_cast<const f32x4v*>(base + d0);
    f32x4v v1 = *reinterpret_cast<const f32x4v*>(base + d0 + 4);
    f32x4v w0 = *reinterpret_cast<const f32x4v*>(base + 2048 + d0);
    f32x4v w1 = *reinterpret_cast<const f32x4v*>(base + 2048 + d0 + 4);
    #pragma unroll
    for (int j = 0; j < 4; ++j){
      y[j] += v0[j]; y[4+j] += v1[j];
      g[j] += w0[j]; g[4+j] += w1[j];
    }
  }
  if (t > 0){
    for (int i = 0; i < t; ++i){
      const float a = aG[b*64 + i];
      f16x8 g8 = *reinterpret_cast<const f16x8*>(G1 + ((size_t)i*128 + b)*2048 + d0);
      #pragma unroll
      for (int j = 0; j < 8; ++j) y[j] += a * (float)g8[j];
    }
  }
  f32x4v bb0 = *reinterpret_cast<const f32x4v*>(sab1 + d0);
  f32x4v bb1 = *reinterpret_cast<const f32x4v*>(sab1 + d0 + 4);
  f16x8 hh, ll, gg;
  #pragma unroll
  for (int j = 0; j < 4; ++j){
    const float a = tanhf(y[j] + bb0[j]);
    const float c = tanhf(y[4+j] + bb1[j]);
    hh[j] = (f16)a;   ll[j] = (f16)(a - (float)hh[j]);
    hh[4+j] = (f16)c; ll[4+j] = (f16)(c - (float)hh[4+j]);
    gg[j] = (f16)g[j]; gg[4+j] = (f16)g[4+j];
  }
  *reinterpret_cast<f16x8*>(r1Hi + ((size_t)t*128 + b)*2048 + d0) = hh;
  *reinterpret_cast<f16x8*>(r1Lo + ((size_t)t*128 + b)*2048 + d0) = ll;
  *reinterpret_cast<f16x8*>(G1 + ((size_t)t*128 + b)*2048 + d0) = gg;
}

// ---------------------------------------------------------------------------
// Head stage 1: z1 = relu(r1(8192x2048) @ hw1 + hb1), f16 2-pass MFMA
// ---------------------------------------------------------------------------
__global__ __launch_bounds__(256) void k_headgemm(
    const f16* __restrict__ aHi, const f16* __restrict__ aLo,
    const f16* __restrict__ w1H,   // [224][2048]
    const float* __restrict__ hb1,
    float* __restrict__ z1)        // [8192][224]
{
  const int mb = blockIdx.x;
  const int nt = blockIdx.y;
  const int lane = threadIdx.x & 63, wv = threadIdx.x >> 6;
  const int rowA = mb*128 + wv*32 + (lane & 31);
  const int kb = lane >> 5;
  const int n = nt*32 + (lane & 31);
  const f16* pAH = aHi + (size_t)rowA*2048 + kb*8;
  const f16* pAL = aLo + (size_t)rowA*2048 + kb*8;
  const f16* pBH = w1H + (size_t)n*2048 + kb*8;
  f32x16 acc;
  #pragma unroll
  for (int r = 0; r < 16; ++r) acc[r] = 0.f;
  #pragma unroll 4
  for (int s = 0; s < 128; ++s){
    f16x8 ah = *reinterpret_cast<const f16x8*>(pAH + s*16);
    f16x8 al = *reinterpret_cast<const f16x8*>(pAL + s*16);
    f16x8 bh = *reinterpret_cast<const f16x8*>(pBH + s*16);
    acc = __builtin_amdgcn_mfma_f32_32x32x16_f16(ah, bh, acc, 0, 0, 0);
    acc = __builtin_amdgcn_mfma_f32_32x32x16_f16(al, bh, acc, 0, 0, 0);
  }
  const float bias = (n < 200) ? hb1[n] : 0.f;
  const int rowBase = mb*128 + wv*32 + 4*kb;
  #pragma unroll
  for (int r = 0; r < 16; ++r){
    const int rr = rowBase + (r & 3) + 8*(r >> 2);
    z1[(size_t)rr*224 + n] = fmaxf(acc[r] + bias, 0.f);
  }
}

// Head stage 2
__global__ __launch_bounds__(256) void k_head2(
    const float* __restrict__ z1,
    const float* __restrict__ hw2, const float* __restrict__ hb2,
    const float* __restrict__ hw3, const float* __restrict__ hb3,
    float* __restrict__ out)
{
  const int r0 = blockIdx.x * 64;
  const int tid = threadIdx.x;
  __shared__ float zl[64][200];
  __shared__ float z2[64][50];
  for (int i = tid; i < 64*200; i += 256){
    const int r = i / 200, n = i % 200;
    zl[r][n] = z1[(size_t)(r0 + r)*224 + n];
  }
  __syncthreads();
  for (int i = tid; i < 64*50; i += 256){
    const int r = i / 50, n = i % 50;
    float s = hb2[n];
    for (int k = 0; k < 200; ++k) s += zl[r][k] * hw2[k*50 + n];
    z2[r][n] = fmaxf(s, 0.f);
  }
  __syncthreads();
  for (int i = tid; i < 128; i += 256){
    const int r = i >> 1, c = i & 1;
    float s = hb3[c];
    for (int k = 0; k < 50; ++k) s += z2[r][k] * hw3[k*2 + c];
    const int rg = r0 + r;
    const int tt = rg >> 7, b = rg & 127;
    out[(size_t)b*128 + tt*2 + c] = s;
  }
}

// ---------------------------------------------------------------------------
extern "C" void kernel_launch(void* const* d_in, const int* in_sizes, int n_in,
                              void* d_out, int out_size, void* d_ws, size_t ws_size,
                              hipStream_t stream)
{
  (void)in_sizes; (void)n_in; (void)out_size; (void)ws_size;
  const float* x_flat = (const float*)d_in[0];
  const float* enc    = (const float*)d_in[1];
  const float* h0     = (const float*)d_in[2];
  const float* c0     = (const float*)d_in[3];
  const float* cx_w0  = (const float*)d_in[4];
  const float* cx_b0  = (const float*)d_in[5];
  const float* ch_w0  = (const float*)d_in[6];
  const float* ch_b0  = (const float*)d_in[7];
  const float* cx_w1  = (const float*)d_in[8];
  const float* cx_b1  = (const float*)d_in[9];
  const float* ch_w1  = (const float*)d_in[10];
  const float* ch_b1  = (const float*)d_in[11];
  const float* ia_w0  = (const float*)d_in[12];
  const float* ia_b0  = (const float*)d_in[13];
  const float* sa_w0  = (const float*)d_in[14];
  const float* sa_b0  = (const float*)d_in[15];
  const float* ia_w1  = (const float*)d_in[16];
  const float* ia_b1  = (const float*)d_in[17];
  const float* sa_w1  = (const float*)d_in[18];
  const float* sa_b1  = (const float*)d_in[19];
  const float* hw1    = (const float*)d_in[20];
  const float* hb1    = (const float*)d_in[21];
  const float* hw2    = (const float*)d_in[22];
  const float* hb2    = (const float*)d_in[23];
  const float* hw3    = (const float*)d_in[24];
  const float* hb3    = (const float*)d_in[25];
  float* out = (float*)d_out;

  char* ws = (char*)d_ws;
  size_t off = 0;
  auto alloc = [&](size_t bytes) -> char* {
    char* p = ws + off;
    off += (bytes + 255) & ~(size_t)255;
    return p;
  };
  const size_t WPLANE = (size_t)2048*4096*2;   // 16 MiB
  const size_t TPLANE = (size_t)64*BD*2;       // 32 MiB, [T][B][D] f16
  f16* wIa0 = (f16*)alloc(WPLANE);
  f16* wSa0 = (f16*)alloc(WPLANE);   // [4096][2048]: rows 0..2047 Wl^T, 2048.. Wu^T
  f16* wIa1 = (f16*)alloc(WPLANE);
  f16* wSa1 = (f16*)alloc(WPLANE);   // [4096][2048]
  f16* w1H  = (f16*)alloc((size_t)224*2048*2);
  unsigned short* encBf = (unsigned short*)alloc((size_t)128*128*2048*2);
  f16* hr0AHi = (f16*)alloc(TPLANE);
  f16* hr0ALo = (f16*)alloc(TPLANE);
  f16* ctx0Hi = (f16*)alloc(TPLANE);
  f16* ctx0Lo = (f16*)alloc(TPLANE);
  f16* p0Hi   = (f16*)alloc(TPLANE);
  f16* p0Lo   = (f16*)alloc(TPLANE);
  f16* r0Hi   = (f16*)alloc(TPLANE);
  f16* r0Lo   = (f16*)alloc(TPLANE);
  f16* r1Hi   = (f16*)alloc(TPLANE);
  f16* r1Lo   = (f16*)alloc(TPLANE);
  f16* p1Hi   = (f16*)alloc((size_t)BD*2);
  f16* p1Lo   = (f16*)alloc((size_t)BD*2);
  f16* ctx1Hi = (f16*)alloc((size_t)BD*2);
  f16* ctx1Lo = (f16*)alloc((size_t)BD*2);
  f16* hrw1Hi = (f16*)alloc((size_t)BD*2);
  f16* hrw1Lo = (f16*)alloc((size_t)BD*2);
  float* hB   = (float*)alloc((size_t)BD*4);
  float* cB   = (float*)alloc((size_t)BD*4);
  float* pctx = (float*)alloc((size_t)128*2*2048*4);
  float* pm   = (float*)alloc((size_t)256*4);
  float* pl   = (float*)alloc((size_t)256*4);
  float* aG   = (float*)alloc((size_t)128*64*4);
  unsigned short* wpack1 = (unsigned short*)alloc((size_t)128*32*6*2);
  // aliases (live ranges disjoint; every alias target fully rewritten each
  // call before being read):
  float* partials = (float*)wIa0;    // 16 MiB, used only inside the t-loop
  float* z1 = (float*)wSa0;          // 7.3 MiB, used only in the head
  float* Y0 = (float*)hr0AHi;        // 64 MiB f32 over hr0AHi+hr0ALo (contig)
  f16* G0 = ctx0Hi;                  // 32 MiB
  f16* G1 = ctx0Lo;                  // 32 MiB

  // ---- prologue -----------------------------------------------------------
  k_transpose_f16<<<dim3(64,128),256,0,stream>>>(ia_w0, wIa0, 4096, 2048);
  k_transpose_f16<<<dim3(64,128),256,0,stream>>>(ia_w1, wIa1, 4096, 2048);
  k_transpose_f16<<<dim3(64,64),256,0,stream>>>(sa_w0, wSa0, 2048, 2048);
  k_transpose_f16<<<dim3(64,64),256,0,stream>>>(sa_w0 + (size_t)2048*2048,
                                                wSa0 + (size_t)2048*2048, 2048, 2048);
  k_transpose_f16<<<dim3(64,64),256,0,stream>>>(sa_w1, wSa1, 2048, 2048);
  k_transpose_f16<<<dim3(64,64),256,0,stream>>>(sa_w1 + (size_t)2048*2048,
                                                wSa1 + (size_t)2048*2048, 2048, 2048);
  k_transpose_f16<<<dim3(7,64),256,0,stream>>>(hw1, w1H, 2048, 200);
  k_f32_to_bf16<<<(128*128*2048/4 + 255)/256, 256, 0, stream>>>(enc, encBf, 128*128*2048/4);
  k_pack_cellw<<<16,256,0,stream>>>(ch_w1, cx_w1, wpack1);
  k_cell0<<<1024,256,0,stream>>>(x_flat, h0, c0, cx_w0, cx_b0, ch_w0, ch_b0, hr0AHi, hr0ALo);

  // ---- batched recurrence-independent layer-0 phase -----------------------
  k_inter_b<<<dim3(128,64),512,0,stream>>>(encBf, hr0AHi, hr0ALo, ctx0Hi, ctx0Lo);
  k_gemm_full<<<dim3(32,64),256,0,stream>>>(hr0AHi, hr0ALo, ctx0Hi, ctx0Lo,
                                            wIa0, ia_b0, p0Hi, p0Lo);
  // (hr0A and ctx0 are dead after this point; Y0/G0/G1 alias them)
  k_gemm_full2<<<dim3(64,64),256,0,stream>>>(p0Hi, p0Lo, wSa0, Y0, G0);

  // ---- 64 sequential steps (8 kernels each) -------------------------------
  for (int t = 0; t < 64; ++t){
    // layer 0: scores + weighted G0 sum -> r0[t]
    k_step0<<<128,256,0,stream>>>(p0Hi, p0Lo, r0Hi, r0Lo, Y0, G0, sa_b0, t);
    k_cell1<<<1024,256,0,stream>>>(r0Hi, r0Lo,
        (t == 0) ? (h0 + (size_t)128*2048) : hB,
        (t == 0) ? (c0 + (size_t)128*2048) : cB,
        hB, cB, wpack1, cx_b1, ch_b1, hrw1Hi, hrw1Lo, t);
    // layer 1
    k_inter_part<<<dim3(128,2),512,0,stream>>>(encBf, hB, pctx, pm, pl);
    k_inter_comb<<<128,256,0,stream>>>(pctx, pm, pl, ctx1Hi, ctx1Lo);
    k_gemm<<<dim3(32,NPART),256,0,stream>>>(hrw1Hi, hrw1Lo, ctx1Hi, ctx1Lo,
                                            wIa1, partials);
    k_self1<<<128,256,0,stream>>>(partials, ia_b1, p1Hi, p1Lo, r1Hi, r1Lo, aG, t);
    k_gemm_sa1<<<dim3(64,8),256,0,stream>>>(p1Hi, p1Lo, wSa1, partials);
    k_fin1<<<128,256,0,stream>>>(partials, sa_b1, aG, G1, r1Hi, r1Lo, t);
  }

  // ---- head (batched over all t,b) ----------------------------------------
  k_headgemm<<<dim3(64,7),256,0,stream>>>(r1Hi, r1Lo, w1H, hb1, z1);
  k_head2<<<128,256,0,stream>>>(z1, hw2, hb2, hw3, hb3, out);
}

// Round 6
// 6001.350 us; speedup vs baseline: 3.8840x; 1.5760x over previous
//
#include <hip/hip_runtime.h>
#include <math.h>

// ---------------------------------------------------------------------------
// CLSADecoder: 2-layer RowSharedConvLSTM + inter-attn + causal self-attn + head
// B=128, T=64, D=2048 (ROWS=8, CH=32, COLS=8), S=128.
// R5: eliminate the 512-launch t-loop. All GEMMs batched over t; the two
// remaining serial recurrences (self-attn refine chains, ConvLSTM-1 carry)
// are per-b / per-(b,row) independent -> persistent kernels looping t
// internally. 21 launches total.
//   1. cell0 (all t) -> hraw0
//   2. inter_b(l0) -> ctx0 ; gemm_full(ia0) -> p0 ; gemm_full2(sa0) -> Y0,G0
//   3. selfchain(l0): r0[t] = tanh(Y0[t] + sum_i a_i G0[i] + b)   [persistent]
//   4. cell1_all: hraw1[t] for all t                               [persistent]
//   5. inter_b(l1) -> ctx1 ; gemm_full(ia1) -> p1 ; gemm_full2(sa1) -> Y1,G1
//   6. selfchain(l1) -> r1 ; head.
// ---------------------------------------------------------------------------

typedef _Float16 f16;
typedef _Float16 f16x8 __attribute__((ext_vector_type(8)));
typedef _Float16 f16x4 __attribute__((ext_vector_type(4)));
typedef float  f32x16 __attribute__((ext_vector_type(16)));
typedef float  f32x4v __attribute__((ext_vector_type(4)));
typedef unsigned short u16x8 __attribute__((ext_vector_type(8)));
typedef unsigned short u16x4 __attribute__((ext_vector_type(4)));

#define BD 262144   // 128*2048  (one [B][D] plane)

__device__ __forceinline__ unsigned short f2bf(float x){
  unsigned int u = __builtin_bit_cast(unsigned int, x);
  u += 0x7fffu + ((u >> 16) & 1u);
  return (unsigned short)(u >> 16);
}
__device__ __forceinline__ float bf2f(unsigned short h){
  unsigned int u = ((unsigned int)h) << 16;
  return __builtin_bit_cast(float, u);
}
__device__ __forceinline__ float sigmoidf_(float x){
  return 1.0f / (1.0f + __expf(-x));
}
__device__ __forceinline__ void g2l16(const void* g, void* l){
  __builtin_amdgcn_global_load_lds(
      (const __attribute__((address_space(1))) unsigned int*)g,
      (__attribute__((address_space(3))) unsigned int*)l,
      16, 0, 0);
}

// ---------------------------------------------------------------------------
// transpose f32 weight [K][N] -> f16 plane [N][K]
// ---------------------------------------------------------------------------
__global__ __launch_bounds__(256) void k_transpose_f16(
    const float* __restrict__ src, f16* __restrict__ dhi,
    const int K, const int N)
{
  __shared__ float tile[32][33];
  const int n0 = blockIdx.x * 32, k0 = blockIdx.y * 32;
  const int tx = threadIdx.x & 31, ty = threadIdx.x >> 5;
  #pragma unroll
  for (int ii = 0; ii < 4; ++ii){
    const int k = k0 + ty + ii*8, n = n0 + tx;
    float v = (n < N) ? src[(size_t)k * N + n] : 0.0f;
    tile[ty + ii*8][tx] = v;
  }
  __syncthreads();
  #pragma unroll
  for (int ii = 0; ii < 4; ++ii){
    const int n = n0 + ty + ii*8, k = k0 + tx;
    dhi[(size_t)n * K + k] = (f16)tile[tx][ty + ii*8];
  }
}

__global__ void k_f32_to_bf16(const float* __restrict__ src,
                              unsigned short* __restrict__ dst, const int n4)
{
  const int i = blockIdx.x * 256 + threadIdx.x;
  if (i < n4){
    f32x4v v = *reinterpret_cast<const f32x4v*>(src + (size_t)i * 4);
    u16x4 o;
    #pragma unroll
    for (int j = 0; j < 4; ++j) o[j] = f2bf(v[j]);
    *reinterpret_cast<u16x4*>(dst + (size_t)i * 4) = o;
  }
}

__global__ void k_pack_cellw(const float* __restrict__ chw,
                             const float* __restrict__ cxw,
                             unsigned short* __restrict__ wp)
{
  const int i = blockIdx.x * 256 + threadIdx.x;
  if (i < 128 * 32){
    #pragma unroll
    for (int k = 0; k < 3; ++k){
      wp[i*6 + k]     = f2bf(chw[i*3 + k]);
      wp[i*6 + 3 + k] = f2bf(cxw[i*3 + k]);
    }
  }
}

// ---------------------------------------------------------------------------
// Layer-0 ConvLSTM for ALL 64 steps (persistent over t). Block = (b,row).
// ---------------------------------------------------------------------------
__global__ __launch_bounds__(256) void k_cell0(
    const float* __restrict__ x_flat,
    const float* __restrict__ h0, const float* __restrict__ c0,
    const float* __restrict__ cxw, const float* __restrict__ cxb,
    const float* __restrict__ chw, const float* __restrict__ chb,
    f16* __restrict__ hrawHi, f16* __restrict__ hrawLo)     // [T][B][2048]
{
  const int b = blockIdx.x >> 3, row = blockIdx.x & 7;
  const int tid = threadIdx.x;
  __shared__ float h_lds[256];
  __shared__ float x_lds[8];
  __shared__ float P[128][2][8];
  const int gc = tid >> 1, ih = tid & 1;
  float wh[16][3];
  #pragma unroll
  for (int icl = 0; icl < 16; ++icl)
    #pragma unroll
    for (int k = 0; k < 3; ++k)
      wh[icl][k] = chw[(gc*32 + ih*16 + icl)*3 + k];
  const float wx0 = cxw[gc*3+0], wx1 = cxw[gc*3+1], wx2 = cxw[gc*3+2];
  const float bsum = cxb[gc] + chb[gc];
  const int ic = tid >> 3, col = tid & 7;
  const size_t dg = (size_t)b*2048 + row*256 + tid;
  float c_reg = c0[dg];
  h_lds[tid] = h0[dg];
  __syncthreads();
  for (int t = 0; t < 64; ++t){
    if (tid < 8) x_lds[tid] = x_flat[((size_t)b*64 + t)*64 + row*8 + tid];
    __syncthreads();
    float g8[8];
    #pragma unroll
    for (int c2 = 0; c2 < 8; ++c2) g8[c2] = 0.f;
    #pragma unroll
    for (int icl = 0; icl < 16; ++icl){
      const int icg = ih*16 + icl;
      f32x4v hv0 = *reinterpret_cast<const f32x4v*>(&h_lds[icg*8]);
      f32x4v hv1 = *reinterpret_cast<const f32x4v*>(&h_lds[icg*8 + 4]);
      const float hv[8] = {hv0[0],hv0[1],hv0[2],hv0[3],hv1[0],hv1[1],hv1[2],hv1[3]};
      #pragma unroll
      for (int c2 = 0; c2 < 8; ++c2){
        float s = hv[c2] * wh[icl][1];
        if (c2 > 0) s += hv[c2-1] * wh[icl][0];
        if (c2 < 7) s += hv[c2+1] * wh[icl][2];
        g8[c2] += s;
      }
    }
    if (ih == 0){
      #pragma unroll
      for (int c2 = 0; c2 < 8; ++c2){
        float s = x_lds[c2] * wx1 + bsum;
        if (c2 > 0) s += x_lds[c2-1] * wx0;
        if (c2 < 7) s += x_lds[c2+1] * wx2;
        g8[c2] += s;
      }
    }
    #pragma unroll
    for (int c2 = 0; c2 < 8; ++c2) P[gc][ih][c2] = g8[c2];
    __syncthreads();
    const float ipre = P[ic   ][0][col] + P[ic   ][1][col];
    const float fpre = P[ic+32][0][col] + P[ic+32][1][col];
    const float opre = P[ic+64][0][col] + P[ic+64][1][col];
    const float gpre = P[ic+96][0][col] + P[ic+96][1][col];
    const float cn = sigmoidf_(fpre)*c_reg + sigmoidf_(ipre)*tanhf(gpre);
    c_reg = cn;
    const float hn = sigmoidf_(opre)*tanhf(cn);
    h_lds[tid] = hn;
    const f16 hh = (f16)hn;
    hrawHi[((size_t)t*128 + b)*2048 + row*256 + tid] = hh;
    hrawLo[((size_t)t*128 + b)*2048 + row*256 + tid] = (f16)(hn - (float)hh);
    __syncthreads();
  }
}

// ---------------------------------------------------------------------------
// Layer-1 ConvLSTM for ALL 64 steps (persistent over t). x = r0[t] planes.
// ---------------------------------------------------------------------------
__global__ __launch_bounds__(256) void k_cell1_all(
    const f16* __restrict__ r0Hi, const f16* __restrict__ r0Lo,
    const float* __restrict__ h0s, const float* __restrict__ c0s,  // layer-1 slices
    const unsigned short* __restrict__ wp,
    const float* __restrict__ cxb, const float* __restrict__ chb,
    f16* __restrict__ hrw1Hi, f16* __restrict__ hrw1Lo)            // [T][B][2048]
{
  const int b = blockIdx.x >> 3, row = blockIdx.x & 7;
  const int tid = threadIdx.x;
  __shared__ float x_lds[256];
  __shared__ float h_lds[256];
  __shared__ float P[128][2][8];
  __shared__ unsigned short wlds[128*32*6];
  const size_t dg = (size_t)b*2048 + row*256 + tid;
  float c_reg = c0s[dg];
  h_lds[tid] = h0s[dg];
  for (int i = tid; i < 128*32*6; i += 256) wlds[i] = wp[i];
  const int ic = tid >> 3, col = tid & 7;
  const float bi = cxb[ic]    + chb[ic];
  const float bf = cxb[ic+32] + chb[ic+32];
  const float bo = cxb[ic+64] + chb[ic+64];
  const float bg = cxb[ic+96] + chb[ic+96];
  const int gc = tid >> 1, ih = tid & 1;
  __syncthreads();
  for (int t = 0; t < 64; ++t){
    x_lds[tid] = (float)r0Hi[(size_t)t*BD + dg] + (float)r0Lo[(size_t)t*BD + dg];
    __syncthreads();
    {
      float g8[8];
      #pragma unroll
      for (int c2 = 0; c2 < 8; ++c2) g8[c2] = 0.f;
      #pragma unroll
      for (int icl = 0; icl < 16; ++icl){
        const int icg = ih*16 + icl;
        f32x4v hv0 = *reinterpret_cast<const f32x4v*>(&h_lds[icg*8]);
        f32x4v hv1 = *reinterpret_cast<const f32x4v*>(&h_lds[icg*8 + 4]);
        f32x4v xv0 = *reinterpret_cast<const f32x4v*>(&x_lds[icg*8]);
        f32x4v xv1 = *reinterpret_cast<const f32x4v*>(&x_lds[icg*8 + 4]);
        const float hv[8] = {hv0[0],hv0[1],hv0[2],hv0[3],hv1[0],hv1[1],hv1[2],hv1[3]};
        const float xv[8] = {xv0[0],xv0[1],xv0[2],xv0[3],xv1[0],xv1[1],xv1[2],xv1[3]};
        const unsigned short* wq = &wlds[(gc*32 + icg)*6];
        const float wh0 = bf2f(wq[0]), wh1 = bf2f(wq[1]), wh2 = bf2f(wq[2]);
        const float wx0 = bf2f(wq[3]), wx1 = bf2f(wq[4]), wx2 = bf2f(wq[5]);
        #pragma unroll
        for (int c2 = 0; c2 < 8; ++c2){
          float s = hv[c2]*wh1 + xv[c2]*wx1;
          if (c2 > 0) s += hv[c2-1]*wh0 + xv[c2-1]*wx0;
          if (c2 < 7) s += hv[c2+1]*wh2 + xv[c2+1]*wx2;
          g8[c2] += s;
        }
      }
      #pragma unroll
      for (int c2 = 0; c2 < 8; ++c2) P[gc][ih][c2] = g8[c2];
    }
    __syncthreads();
    {
      const float ipre = P[ic   ][0][col] + P[ic   ][1][col] + bi;
      const float fpre = P[ic+32][0][col] + P[ic+32][1][col] + bf;
      const float opre = P[ic+64][0][col] + P[ic+64][1][col] + bo;
      const float gpre = P[ic+96][0][col] + P[ic+96][1][col] + bg;
      const float cn = sigmoidf_(fpre)*c_reg + sigmoidf_(ipre)*tanhf(gpre);
      c_reg = cn;
      const float hraw = sigmoidf_(opre)*tanhf(cn);
      const f16 hh = (f16)hraw;
      hrw1Hi[(size_t)t*BD + dg] = hh;
      hrw1Lo[(size_t)t*BD + dg] = (f16)(hraw - (float)hh);
      __syncthreads();           // all P reads done before next iter overwrites
      h_lds[tid] = hraw;
    }
  }
}

// ---------------------------------------------------------------------------
// Batched inter-attention (both layers, all t): block (b, t), 8 waves x 16
// encoder rows, online softmax, deterministic 8-way LDS combine.
// ---------------------------------------------------------------------------
__global__ __launch_bounds__(512) void k_inter_b(
    const unsigned short* __restrict__ encBf,
    const f16* __restrict__ stHi, const f16* __restrict__ stLo,   // [T][B][2048]
    f16* __restrict__ ctxHi, f16* __restrict__ ctxLo)
{
  const int b = blockIdx.x;
  const size_t so = (size_t)blockIdx.y * BD + (size_t)b * 2048;
  const int tid = threadIdx.x;
  const int lane = tid & 63, wv = tid >> 6;
  __shared__ float wav[8][2048];
  __shared__ float wm[8], wl[8];
  float sv[32], av[32];
  #pragma unroll
  for (int p = 0; p < 4; ++p){
    const int d = (p*64 + lane)*8;
    f16x8 hh = *reinterpret_cast<const f16x8*>(stHi + so + d);
    f16x8 ll = *reinterpret_cast<const f16x8*>(stLo + so + d);
    #pragma unroll
    for (int j = 0; j < 8; ++j){ sv[p*8+j] = (float)hh[j] + (float)ll[j]; av[p*8+j] = 0.f; }
  }
  float m = -INFINITY, l = 0.f;
  const int s0 = wv*16;
  for (int r = 0; r < 16; ++r){
    const unsigned short* er = encBf + ((size_t)b*128 + s0 + r)*2048;
    float ef[32];
    float dot = 0.f;
    #pragma unroll
    for (int p = 0; p < 4; ++p){
      u16x8 ev = *reinterpret_cast<const u16x8*>(er + (p*64 + lane)*8);
      #pragma unroll
      for (int j = 0; j < 8; ++j){ const float e = bf2f(ev[j]); ef[p*8+j] = e; dot += e * sv[p*8+j]; }
    }
    #pragma unroll
    for (int off = 1; off < 64; off <<= 1) dot += __shfl_xor(dot, off);
    if (dot > m){
      const float scf = __expf(m - dot);
      l *= scf;
      #pragma unroll
      for (int q = 0; q < 32; ++q) av[q] *= scf;
      m = dot;
    }
    const float pp = __expf(dot - m);
    l += pp;
    #pragma unroll
    for (int q = 0; q < 32; ++q) av[q] += pp * ef[q];
  }
  #pragma unroll
  for (int p = 0; p < 4; ++p){
    const int d = (p*64 + lane)*8;
    f32x4v v0, v1;
    #pragma unroll
    for (int j = 0; j < 4; ++j){ v0[j] = av[p*8+j]; v1[j] = av[p*8+4+j]; }
    *reinterpret_cast<f32x4v*>(&wav[wv][d]) = v0;
    *reinterpret_cast<f32x4v*>(&wav[wv][d+4]) = v1;
  }
  if (lane == 0){ wm[wv] = m; wl[wv] = l; }
  __syncthreads();
  float M = wm[0];
  #pragma unroll
  for (int i = 1; i < 8; ++i) M = fmaxf(M, wm[i]);
  float U[8];
  float L = 0.f;
  #pragma unroll
  for (int i = 0; i < 8; ++i){ U[i] = __expf(wm[i] - M); L += wl[i] * U[i]; }
  const float Linv = 1.f / L;
  const int d0 = tid * 4;
  float acc[4] = {0.f, 0.f, 0.f, 0.f};
  #pragma unroll
  for (int w = 0; w < 8; ++w){
    f32x4v v = *reinterpret_cast<const f32x4v*>(&wav[w][d0]);
    #pragma unroll
    for (int j = 0; j < 4; ++j) acc[j] += U[w] * v[j];
  }
  f16x4 hh, ll;
  #pragma unroll
  for (int j = 0; j < 4; ++j){
    const float v = acc[j] * Linv;
    hh[j] = (f16)v;
    ll[j] = (f16)(v - (float)hh[j]);
  }
  *reinterpret_cast<f16x4*>(ctxHi + so + d0) = hh;
  *reinterpret_cast<f16x4*>(ctxLo + so + d0) = ll;
}

// ---------------------------------------------------------------------------
// Batched full-K ia GEMM (all t): p[t] = tanh([A0|A1]@W + bias), f16 hi/lo.
// Grid (32 nt, 64 t). K=4096, f16 2-pass MFMA, global_load_lds double-buffer.
// ---------------------------------------------------------------------------
__global__ __launch_bounds__(256, 2) void k_gemm_full(
    const f16* __restrict__ a0Hi, const f16* __restrict__ a0Lo,
    const f16* __restrict__ a1Hi, const f16* __restrict__ a1Lo,
    const f16* __restrict__ wHp, const float* __restrict__ bias,
    f16* __restrict__ outHi, f16* __restrict__ outLo)
{
  const int nt = blockIdx.x, t = blockIdx.y;
  const size_t tb = (size_t)t * BD;
  const int tid = threadIdx.x;
  const int lane = tid & 63, wv = tid >> 6;
  __shared__ __align__(16) char lds[81920];
  const f16* wH = wHp + (size_t)(nt*64)*4096;

  auto stage = [&](int buf, int ki){
    char* lb = lds + buf*40960;
    const f16* aH = ((ki < 32) ? a0Hi : a1Hi) + tb;
    const f16* aL = ((ki < 32) ? a0Lo : a1Lo) + tb;
    const int ke = (ki & 31) * 64;
    #pragma unroll
    for (int i = 0; i < 4; ++i){
      const int c = i*256 + tid, row = c >> 3;
      const int srcb = ((c & 7)*16) ^ ((row & 7) << 4);
      g2l16((const char*)(aH + (size_t)row*2048 + ke) + srcb, lb + c*16);
      g2l16((const char*)(aL + (size_t)row*2048 + ke) + srcb, lb + 16384 + c*16);
    }
    #pragma unroll
    for (int i = 0; i < 2; ++i){
      const int c = i*256 + tid, row = c >> 3;
      const int srcb = ((c & 7)*16) ^ ((row & 7) << 4);
      g2l16((const char*)(wH + (size_t)row*4096 + ki*64) + srcb, lb + 32768 + c*16);
    }
  };

  f32x16 acc0, acc1;
  #pragma unroll
  for (int r = 0; r < 16; ++r){ acc0[r] = 0.f; acc1[r] = 0.f; }
  const int rA = wv*32 + (lane & 31);
  const int kb = lane >> 5;
  const int rB0 = lane & 31;
  const int aswz = (rA & 7) << 4;
  const int bswz = (rB0 & 7) << 4;

  stage(0, 0);
  __syncthreads();
  for (int ki = 0; ki < 64; ++ki){
    const int buf = ki & 1;
    if (ki < 63) stage(buf ^ 1, ki + 1);
    const char* lb = lds + buf*40960;
    #pragma unroll
    for (int s = 0; s < 4; ++s){
      const int cb = s*32 + kb*16;
      f16x8 ah  = *reinterpret_cast<const f16x8*>(lb + rA*128 + (cb ^ aswz));
      f16x8 al  = *reinterpret_cast<const f16x8*>(lb + 16384 + rA*128 + (cb ^ aswz));
      f16x8 b0h = *reinterpret_cast<const f16x8*>(lb + 32768 + rB0*128 + (cb ^ bswz));
      f16x8 b1h = *reinterpret_cast<const f16x8*>(lb + 32768 + 4096 + rB0*128 + (cb ^ bswz));
      acc0 = __builtin_amdgcn_mfma_f32_32x32x16_f16(ah, b0h, acc0, 0, 0, 0);
      acc1 = __builtin_amdgcn_mfma_f32_32x32x16_f16(ah, b1h, acc1, 0, 0, 0);
      acc0 = __builtin_amdgcn_mfma_f32_32x32x16_f16(al, b0h, acc0, 0, 0, 0);
      acc1 = __builtin_amdgcn_mfma_f32_32x32x16_f16(al, b1h, acc1, 0, 0, 0);
    }
    __syncthreads();
  }

  const int col0 = nt*64 + (lane & 31);
  const float b0 = bias[col0], b1 = bias[col0 + 32];
  const int rowBase = wv*32 + 4*kb;
  #pragma unroll
  for (int r = 0; r < 16; ++r){
    const int rr = rowBase + (r & 3) + 8*(r >> 2);
    const size_t o = tb + (size_t)rr*2048 + col0;
    const float p = tanhf(acc0[r] + b0);
    const float q = tanhf(acc1[r] + b1);
    const f16 ph = (f16)p, qh = (f16)q;
    outHi[o]      = ph;  outLo[o]      = (f16)(p - (float)ph);
    outHi[o + 32] = qh;  outLo[o + 32] = (f16)(q - (float)qh);
  }
}

// ---------------------------------------------------------------------------
// Batched sa GEMM (all t): A = p hi/lo, W = [Wlow^T|Wup^T] ([4096][2048]).
// nt<32 -> Y (f32, raw); nt>=32 -> G (f16). Grid (64 nt, 64 t), K=2048.
// ---------------------------------------------------------------------------
__global__ __launch_bounds__(256, 2) void k_gemm_full2(
    const f16* __restrict__ aHi, const f16* __restrict__ aLo,   // [T][B][2048]
    const f16* __restrict__ wSp,                                // [4096][2048]
    float* __restrict__ Y, f16* __restrict__ G)                 // [T][B][2048]
{
  const int nt = blockIdx.x, t = blockIdx.y;
  const size_t tb = (size_t)t * BD;
  const int tid = threadIdx.x;
  const int lane = tid & 63, wv = tid >> 6;
  __shared__ __align__(16) char lds[81920];
  const f16* wH = wSp + (size_t)(nt*64)*2048;
  const f16* aH = aHi + tb;
  const f16* aL = aLo + tb;

  auto stage = [&](int buf, int ki){
    char* lb = lds + buf*40960;
    const int ke = ki*64;
    #pragma unroll
    for (int i = 0; i < 4; ++i){
      const int c = i*256 + tid, row = c >> 3;
      const int srcb = ((c & 7)*16) ^ ((row & 7) << 4);
      g2l16((const char*)(aH + (size_t)row*2048 + ke) + srcb, lb + c*16);
      g2l16((const char*)(aL + (size_t)row*2048 + ke) + srcb, lb + 16384 + c*16);
    }
    #pragma unroll
    for (int i = 0; i < 2; ++i){
      const int c = i*256 + tid, row = c >> 3;
      const int srcb = ((c & 7)*16) ^ ((row & 7) << 4);
      g2l16((const char*)(wH + (size_t)row*2048 + ke) + srcb, lb + 32768 + c*16);
    }
  };

  f32x16 acc0, acc1;
  #pragma unroll
  for (int r = 0; r < 16; ++r){ acc0[r] = 0.f; acc1[r] = 0.f; }
  const int rA = wv*32 + (lane & 31);
  const int kb = lane >> 5;
  const int rB0 = lane & 31;
  const int aswz = (rA & 7) << 4;
  const int bswz = (rB0 & 7) << 4;

  stage(0, 0);
  __syncthreads();
  for (int ki = 0; ki < 32; ++ki){
    const int buf = ki & 1;
    if (ki < 31) stage(buf ^ 1, ki + 1);
    const char* lb = lds + buf*40960;
    #pragma unroll
    for (int s = 0; s < 4; ++s){
      const int cb = s*32 + kb*16;
      f16x8 ah  = *reinterpret_cast<const f16x8*>(lb + rA*128 + (cb ^ aswz));
      f16x8 al  = *reinterpret_cast<const f16x8*>(lb + 16384 + rA*128 + (cb ^ aswz));
      f16x8 b0h = *reinterpret_cast<const f16x8*>(lb + 32768 + rB0*128 + (cb ^ bswz));
      f16x8 b1h = *reinterpret_cast<const f16x8*>(lb + 32768 + 4096 + rB0*128 + (cb ^ bswz));
      acc0 = __builtin_amdgcn_mfma_f32_32x32x16_f16(ah, b0h, acc0, 0, 0, 0);
      acc1 = __builtin_amdgcn_mfma_f32_32x32x16_f16(ah, b1h, acc1, 0, 0, 0);
      acc0 = __builtin_amdgcn_mfma_f32_32x32x16_f16(al, b0h, acc0, 0, 0, 0);
      acc1 = __builtin_amdgcn_mfma_f32_32x32x16_f16(al, b1h, acc1, 0, 0, 0);
    }
    __syncthreads();
  }

  const int col0 = nt*64 + (lane & 31);
  const int rowBase = wv*32 + 4*kb;
  if (nt < 32){
    float* yp = Y + tb + col0;
    #pragma unroll
    for (int r = 0; r < 16; ++r){
      const int rr = rowBase + (r & 3) + 8*(r >> 2);
      yp[(size_t)rr*2048]      = acc0[r];
      yp[(size_t)rr*2048 + 32] = acc1[r];
    }
  } else {
    f16* gp = G + tb + (col0 - 2048);
    #pragma unroll
    for (int r = 0; r < 16; ++r){
      const int rr = rowBase + (r & 3) + 8*(r >> 2);
      gp[(size_t)rr*2048]      = (f16)acc0[r];
      gp[(size_t)rr*2048 + 32] = (f16)acc1[r];
    }
  }
}

// ---------------------------------------------------------------------------
// Self-attention refine chain (persistent over t). Block per b, 512 threads.
// r[t] = tanh(Y[t] + sum_{i<t} a_i G[i] + bias),  a = softmax(r[i<t] . p[t]).
// Block-local RAW through global is ordered by __syncthreads (vmcnt drain).
// ---------------------------------------------------------------------------
__global__ __launch_bounds__(512) void k_selfchain(
    const f16* __restrict__ pHi, const f16* __restrict__ pLo,   // [T][B][2048]
    const float* __restrict__ Y, const f16* __restrict__ G,     // [T][B][2048]
    const float* __restrict__ bias,
    f16* __restrict__ rHi, f16* __restrict__ rLo)               // [T][B][2048]
{
  const int b = blockIdx.x;
  const int tid = threadIdx.x, lane = tid & 63, wv = tid >> 6;   // 8 waves
  __shared__ float sc[64];
  __shared__ float a_lds[64];
  const int d0 = tid * 4;
  f32x4v bb = *reinterpret_cast<const f32x4v*>(bias + d0);
  for (int t = 0; t < 64; ++t){
    const size_t pb = ((size_t)t*128 + b)*2048;
    if (t > 0){
      // state p[t][b] distributed across each wave's lanes (32 elems/lane)
      float hreg[32];
      #pragma unroll
      for (int jj = 0; jj < 4; ++jj){
        const int d = (jj*64 + lane)*8;
        f16x8 h8 = *reinterpret_cast<const f16x8*>(pHi + pb + d);
        f16x8 l8 = *reinterpret_cast<const f16x8*>(pLo + pb + d);
        #pragma unroll
        for (int j = 0; j < 8; ++j) hreg[jj*8+j] = (float)h8[j] + (float)l8[j];
      }
      for (int i = wv; i < t; i += 8){
        const f16* rh = rHi + ((size_t)i*128 + b)*2048;
        const f16* rl = rLo + ((size_t)i*128 + b)*2048;
        float dot = 0.f;
        #pragma unroll
        for (int jj = 0; jj < 4; ++jj){
          const int d = (jj*64 + lane)*8;
          f16x8 h8 = *reinterpret_cast<const f16x8*>(rh + d);
          f16x8 l8 = *reinterpret_cast<const f16x8*>(rl + d);
          #pragma unroll
          for (int j = 0; j < 8; ++j)
            dot += ((float)h8[j] + (float)l8[j]) * hreg[jj*8+j];
        }
        #pragma unroll
        for (int off = 1; off < 64; off <<= 1) dot += __shfl_xor(dot, off);
        if (lane == 0) sc[i] = dot;
      }
      __syncthreads();
      if (tid < 64){
        const float s = (tid < t) ? sc[tid] : -INFINITY;
        float mm = s;
        #pragma unroll
        for (int off = 1; off < 64; off <<= 1) mm = fmaxf(mm, __shfl_xor(mm, off));
        const float e = (tid < t) ? __expf(s - mm) : 0.f;
        float sum = e;
        #pragma unroll
        for (int off = 1; off < 64; off <<= 1) sum += __shfl_xor(sum, off);
        a_lds[tid] = e / sum;
      }
      __syncthreads();
    }
    float y[4];
    {
      f32x4v yv = *reinterpret_cast<const f32x4v*>(Y + (size_t)t*BD + (size_t)b*2048 + d0);
      #pragma unroll
      for (int j = 0; j < 4; ++j) y[j] = yv[j] + bb[j];
    }
    if (t > 0){
      for (int i = 0; i < t; ++i){
        const float a = a_lds[i];
        f16x4 g4 = *reinterpret_cast<const f16x4*>(G + ((size_t)i*128 + b)*2048 + d0);
        #pragma unroll
        for (int j = 0; j < 4; ++j) y[j] += a * (float)g4[j];
      }
    }
    f16x4 hh, ll;
    #pragma unroll
    for (int j = 0; j < 4; ++j){
      const float v = tanhf(y[j]);
      hh[j] = (f16)v;
      ll[j] = (f16)(v - (float)hh[j]);
    }
    *reinterpret_cast<f16x4*>(rHi + pb + d0) = hh;
    *reinterpret_cast<f16x4*>(rLo + pb + d0) = ll;
    __syncthreads();   // r[t] stores drained before t+1 scores read them
  }
}

// ---------------------------------------------------------------------------
// Head stage 1: z1 = relu(r1(8192x2048) @ hw1 + hb1), f16 2-pass MFMA
// ---------------------------------------------------------------------------
__global__ __launch_bounds__(256) void k_headgemm(
    const f16* __restrict__ aHi, const f16* __restrict__ aLo,
    const f16* __restrict__ w1H,   // [224][2048]
    const float* __restrict__ hb1,
    float* __restrict__ z1)        // [8192][224]
{
  const int mb = blockIdx.x;
  const int nt = blockIdx.y;
  const int lane = threadIdx.x & 63, wv = threadIdx.x >> 6;
  const int rowA = mb*128 + wv*32 + (lane & 31);
  const int kb = lane >> 5;
  const int n = nt*32 + (lane & 31);
  const f16* pAH = aHi + (size_t)rowA*2048 + kb*8;
  const f16* pAL = aLo + (size_t)rowA*2048 + kb*8;
  const f16* pBH = w1H + (size_t)n*2048 + kb*8;
  f32x16 acc;
  #pragma unroll
  for (int r = 0; r < 16; ++r) acc[r] = 0.f;
  #pragma unroll 4
  for (int s = 0; s < 128; ++s){
    f16x8 ah = *reinterpret_cast<const f16x8*>(pAH + s*16);
    f16x8 al = *reinterpret_cast<const f16x8*>(pAL + s*16);
    f16x8 bh = *reinterpret_cast<const f16x8*>(pBH + s*16);
    acc = __builtin_amdgcn_mfma_f32_32x32x16_f16(ah, bh, acc, 0, 0, 0);
    acc = __builtin_amdgcn_mfma_f32_32x32x16_f16(al, bh, acc, 0, 0, 0);
  }
  const float bias = (n < 200) ? hb1[n] : 0.f;
  const int rowBase = mb*128 + wv*32 + 4*kb;
  #pragma unroll
  for (int r = 0; r < 16; ++r){
    const int rr = rowBase + (r & 3) + 8*(r >> 2);
    z1[(size_t)rr*224 + n] = fmaxf(acc[r] + bias, 0.f);
  }
}

// Head stage 2
__global__ __launch_bounds__(256) void k_head2(
    const float* __restrict__ z1,
    const float* __restrict__ hw2, const float* __restrict__ hb2,
    const float* __restrict__ hw3, const float* __restrict__ hb3,
    float* __restrict__ out)
{
  const int r0 = blockIdx.x * 64;
  const int tid = threadIdx.x;
  __shared__ float zl[64][200];
  __shared__ float z2[64][50];
  for (int i = tid; i < 64*200; i += 256){
    const int r = i / 200, n = i % 200;
    zl[r][n] = z1[(size_t)(r0 + r)*224 + n];
  }
  __syncthreads();
  for (int i = tid; i < 64*50; i += 256){
    const int r = i / 50, n = i % 50;
    float s = hb2[n];
    for (int k = 0; k < 200; ++k) s += zl[r][k] * hw2[k*50 + n];
    z2[r][n] = fmaxf(s, 0.f);
  }
  __syncthreads();
  for (int i = tid; i < 128; i += 256){
    const int r = i >> 1, c = i & 1;
    float s = hb3[c];
    for (int k = 0; k < 50; ++k) s += z2[r][k] * hw3[k*2 + c];
    const int rg = r0 + r;
    const int tt = rg >> 7, b = rg & 127;
    out[(size_t)b*128 + tt*2 + c] = s;
  }
}

// ---------------------------------------------------------------------------
extern "C" void kernel_launch(void* const* d_in, const int* in_sizes, int n_in,
                              void* d_out, int out_size, void* d_ws, size_t ws_size,
                              hipStream_t stream)
{
  (void)in_sizes; (void)n_in; (void)out_size; (void)ws_size;
  const float* x_flat = (const float*)d_in[0];
  const float* enc    = (const float*)d_in[1];
  const float* h0     = (const float*)d_in[2];
  const float* c0     = (const float*)d_in[3];
  const float* cx_w0  = (const float*)d_in[4];
  const float* cx_b0  = (const float*)d_in[5];
  const float* ch_w0  = (const float*)d_in[6];
  const float* ch_b0  = (const float*)d_in[7];
  const float* cx_w1  = (const float*)d_in[8];
  const float* cx_b1  = (const float*)d_in[9];
  const float* ch_w1  = (const float*)d_in[10];
  const float* ch_b1  = (const float*)d_in[11];
  const float* ia_w0  = (const float*)d_in[12];
  const float* ia_b0  = (const float*)d_in[13];
  const float* sa_w0  = (const float*)d_in[14];
  const float* sa_b0  = (const float*)d_in[15];
  const float* ia_w1  = (const float*)d_in[16];
  const float* ia_b1  = (const float*)d_in[17];
  const float* sa_w1  = (const float*)d_in[18];
  const float* sa_b1  = (const float*)d_in[19];
  const float* hw1    = (const float*)d_in[20];
  const float* hb1    = (const float*)d_in[21];
  const float* hw2    = (const float*)d_in[22];
  const float* hb2    = (const float*)d_in[23];
  const float* hw3    = (const float*)d_in[24];
  const float* hb3    = (const float*)d_in[25];
  float* out = (float*)d_out;

  char* ws = (char*)d_ws;
  size_t off = 0;
  auto alloc = [&](size_t bytes) -> char* {
    char* p = ws + off;
    off += (bytes + 255) & ~(size_t)255;
    return p;
  };
  const size_t WPLANE = (size_t)2048*4096*2;   // 16 MiB
  const size_t TPLANE = (size_t)64*BD*2;       // 32 MiB, [T][B][D] f16
  f16* wIa0 = (f16*)alloc(WPLANE);
  f16* wSa0 = (f16*)alloc(WPLANE);   // [4096][2048]: Wlow^T rows 0..2047, Wup^T rows 2048..
  f16* wIa1 = (f16*)alloc(WPLANE);
  f16* wSa1 = (f16*)alloc(WPLANE);
  f16* w1H  = (f16*)alloc((size_t)224*2048*2);
  unsigned short* encBf = (unsigned short*)alloc((size_t)128*128*2048*2);
  f16* S1 = (f16*)alloc(TPLANE);   // hr0AHi -> Y0(lo half) -> ctx1Hi -> Y1(lo half)
  f16* S2 = (f16*)alloc(TPLANE);   // hr0ALo -> Y0(hi half) -> ctx1Lo -> Y1(hi half)
  f16* S3 = (f16*)alloc(TPLANE);   // ctx0Hi -> G0 -> r1Lo
  f16* S4 = (f16*)alloc(TPLANE);   // ctx0Lo -> G1
  f16* S5 = (f16*)alloc(TPLANE);   // p0Hi -> hrw1Hi -> r1Hi
  f16* S6 = (f16*)alloc(TPLANE);   // p0Lo -> hrw1Lo
  f16* S7 = (f16*)alloc(TPLANE);   // r0Hi -> p1Hi
  f16* S8 = (f16*)alloc(TPLANE);   // r0Lo -> p1Lo
  unsigned short* wpack1 = (unsigned short*)alloc((size_t)128*32*6*2);
  // total ws ~= 385 MiB. Alias names (lifetimes verified disjoint):
  f16*  hr0AHi = S1;  f16* hr0ALo = S2;
  f16*  ctx0Hi = S3;  f16* ctx0Lo = S4;
  f16*  p0Hi   = S5;  f16* p0Lo   = S6;
  float* Y0 = (float*)S1;                    // 64 MiB over S1+S2 (contiguous)
  f16*  G0  = S3;
  f16*  r0Hi = S7;    f16* r0Lo   = S8;
  f16*  hrw1Hi = S5;  f16* hrw1Lo = S6;
  f16*  ctx1Hi = S1;  f16* ctx1Lo = S2;
  f16*  p1Hi = S7;    f16* p1Lo   = S8;
  float* Y1 = (float*)S1;                    // 64 MiB over S1+S2
  f16*  G1  = S4;
  f16*  r1Hi = S5;    f16* r1Lo   = S3;
  float* z1 = (float*)wSa0;                  // head scratch (wSa0 dead by then)

  // ---- prologue -----------------------------------------------------------
  k_transpose_f16<<<dim3(64,128),256,0,stream>>>(ia_w0, wIa0, 4096, 2048);
  k_transpose_f16<<<dim3(64,128),256,0,stream>>>(ia_w1, wIa1, 4096, 2048);
  k_transpose_f16<<<dim3(64,64),256,0,stream>>>(sa_w0, wSa0, 2048, 2048);
  k_transpose_f16<<<dim3(64,64),256,0,stream>>>(sa_w0 + (size_t)2048*2048,
                                                wSa0 + (size_t)2048*2048, 2048, 2048);
  k_transpose_f16<<<dim3(64,64),256,0,stream>>>(sa_w1, wSa1, 2048, 2048);
  k_transpose_f16<<<dim3(64,64),256,0,stream>>>(sa_w1 + (size_t)2048*2048,
                                                wSa1 + (size_t)2048*2048, 2048, 2048);
  k_transpose_f16<<<dim3(7,64),256,0,stream>>>(hw1, w1H, 2048, 200);
  k_f32_to_bf16<<<(128*128*2048/4 + 255)/256, 256, 0, stream>>>(enc, encBf, 128*128*2048/4);
  k_pack_cellw<<<16,256,0,stream>>>(ch_w1, cx_w1, wpack1);

  // ---- layer 0 (fully batched + one persistent chain) ---------------------
  k_cell0<<<1024,256,0,stream>>>(x_flat, h0, c0, cx_w0, cx_b0, ch_w0, ch_b0,
                                 hr0AHi, hr0ALo);
  k_inter_b<<<dim3(128,64),512,0,stream>>>(encBf, hr0AHi, hr0ALo, ctx0Hi, ctx0Lo);
  k_gemm_full<<<dim3(32,64),256,0,stream>>>(hr0AHi, hr0ALo, ctx0Hi, ctx0Lo,
                                            wIa0, ia_b0, p0Hi, p0Lo);
  k_gemm_full2<<<dim3(64,64),256,0,stream>>>(p0Hi, p0Lo, wSa0, Y0, G0);
  k_selfchain<<<128,512,0,stream>>>(p0Hi, p0Lo, Y0, G0, sa_b0, r0Hi, r0Lo);

  // ---- layer 1 (persistent cell + fully batched + one persistent chain) ---
  k_cell1_all<<<1024,256,0,stream>>>(r0Hi, r0Lo,
                                     h0 + (size_t)128*2048, c0 + (size_t)128*2048,
                                     wpack1, cx_b1, ch_b1, hrw1Hi, hrw1Lo);
  k_inter_b<<<dim3(128,64),512,0,stream>>>(encBf, hrw1Hi, hrw1Lo, ctx1Hi, ctx1Lo);
  k_gemm_full<<<dim3(32,64),256,0,stream>>>(hrw1Hi, hrw1Lo, ctx1Hi, ctx1Lo,
                                            wIa1, ia_b1, p1Hi, p1Lo);
  k_gemm_full2<<<dim3(64,64),256,0,stream>>>(p1Hi, p1Lo, wSa1, Y1, G1);
  k_selfchain<<<128,512,0,stream>>>(p1Hi, p1Lo, Y1, G1, sa_b1, r1Hi, r1Lo);

  // ---- head (batched over all t,b) ----------------------------------------
  k_headgemm<<<dim3(64,7),256,0,stream>>>(r1Hi, r1Lo, w1H, hb1, z1);
  k_head2<<<128,256,0,stream>>>(z1, hw2, hb2, hw3, hb3, out);
}

// Round 7
// 5655.452 us; speedup vs baseline: 4.1216x; 1.0612x over previous
//
#include <hip/hip_runtime.h>
#include <math.h>

// ---------------------------------------------------------------------------
// CLSADecoder: 2-layer RowSharedConvLSTM + inter-attn + causal self-attn + head
// B=128, T=64, D=2048 (ROWS=8, CH=32, COLS=8), S=128.
// R6: LDS bank-conflict fixes in the two ConvLSTM cell kernels (the #1 cost
// per rocprof: SQ_LDS_BANK_CONFLICT=3.4e8 on k_cell1_all):
//  - weight LDS layout [icg][j][gc] (was (gc*32+icg)*6+j => 32-way conflict)
//  - gate-staging P padded [128][2][9] (was [..][8] => 16-way write conflict)
//  - next-t input prefetched into registers (hides global latency between
//    barriers).
// Launch structure unchanged from R5 (21 launches, no per-t loop on host).
// ---------------------------------------------------------------------------

typedef _Float16 f16;
typedef _Float16 f16x8 __attribute__((ext_vector_type(8)));
typedef _Float16 f16x4 __attribute__((ext_vector_type(4)));
typedef float  f32x16 __attribute__((ext_vector_type(16)));
typedef float  f32x4v __attribute__((ext_vector_type(4)));
typedef unsigned short u16x8 __attribute__((ext_vector_type(8)));
typedef unsigned short u16x4 __attribute__((ext_vector_type(4)));

#define BD 262144   // 128*2048  (one [B][D] plane)

__device__ __forceinline__ unsigned short f2bf(float x){
  unsigned int u = __builtin_bit_cast(unsigned int, x);
  u += 0x7fffu + ((u >> 16) & 1u);
  return (unsigned short)(u >> 16);
}
__device__ __forceinline__ float bf2f(unsigned short h){
  unsigned int u = ((unsigned int)h) << 16;
  return __builtin_bit_cast(float, u);
}
__device__ __forceinline__ float sigmoidf_(float x){
  return 1.0f / (1.0f + __expf(-x));
}
__device__ __forceinline__ void g2l16(const void* g, void* l){
  __builtin_amdgcn_global_load_lds(
      (const __attribute__((address_space(1))) unsigned int*)g,
      (__attribute__((address_space(3))) unsigned int*)l,
      16, 0, 0);
}

// ---------------------------------------------------------------------------
// transpose f32 weight [K][N] -> f16 plane [N][K]
// ---------------------------------------------------------------------------
__global__ __launch_bounds__(256) void k_transpose_f16(
    const float* __restrict__ src, f16* __restrict__ dhi,
    const int K, const int N)
{
  __shared__ float tile[32][33];
  const int n0 = blockIdx.x * 32, k0 = blockIdx.y * 32;
  const int tx = threadIdx.x & 31, ty = threadIdx.x >> 5;
  #pragma unroll
  for (int ii = 0; ii < 4; ++ii){
    const int k = k0 + ty + ii*8, n = n0 + tx;
    float v = (n < N) ? src[(size_t)k * N + n] : 0.0f;
    tile[ty + ii*8][tx] = v;
  }
  __syncthreads();
  #pragma unroll
  for (int ii = 0; ii < 4; ++ii){
    const int n = n0 + ty + ii*8, k = k0 + tx;
    dhi[(size_t)n * K + k] = (f16)tile[tx][ty + ii*8];
  }
}

__global__ void k_f32_to_bf16(const float* __restrict__ src,
                              unsigned short* __restrict__ dst, const int n4)
{
  const int i = blockIdx.x * 256 + threadIdx.x;
  if (i < n4){
    f32x4v v = *reinterpret_cast<const f32x4v*>(src + (size_t)i * 4);
    u16x4 o;
    #pragma unroll
    for (int j = 0; j < 4; ++j) o[j] = f2bf(v[j]);
    *reinterpret_cast<u16x4*>(dst + (size_t)i * 4) = o;
  }
}

// pack cell1 conv weights, conflict-free layout: wp[(icg*6 + j)*128 + gc]
// j in 0..2 = ch taps, 3..5 = cx taps; icg in [0,32), gc in [0,128).
__global__ void k_pack_cellw(const float* __restrict__ chw,
                             const float* __restrict__ cxw,
                             unsigned short* __restrict__ wp)
{
  const int i = blockIdx.x * 256 + threadIdx.x;   // i = gc*32 + icg
  if (i < 128 * 32){
    const int gc = i >> 5, icg = i & 31;
    #pragma unroll
    for (int k = 0; k < 3; ++k){
      wp[(icg*6 + k)*128 + gc]     = f2bf(chw[i*3 + k]);
      wp[(icg*6 + 3 + k)*128 + gc] = f2bf(cxw[i*3 + k]);
    }
  }
}

// ---------------------------------------------------------------------------
// Layer-0 ConvLSTM for ALL 64 steps (persistent over t). Block = (b,row).
// P padded to [2][9] (bank-conflict fix); x prefetched one step ahead.
// ---------------------------------------------------------------------------
__global__ __launch_bounds__(256) void k_cell0(
    const float* __restrict__ x_flat,
    const float* __restrict__ h0, const float* __restrict__ c0,
    const float* __restrict__ cxw, const float* __restrict__ cxb,
    const float* __restrict__ chw, const float* __restrict__ chb,
    f16* __restrict__ hrawHi, f16* __restrict__ hrawLo)     // [T][B][2048]
{
  const int b = blockIdx.x >> 3, row = blockIdx.x & 7;
  const int tid = threadIdx.x;
  __shared__ float h_lds[256];
  __shared__ float x_lds[8];
  __shared__ float P[128][2][9];
  const int gc = tid >> 1, ih = tid & 1;
  float wh[16][3];
  #pragma unroll
  for (int icl = 0; icl < 16; ++icl)
    #pragma unroll
    for (int k = 0; k < 3; ++k)
      wh[icl][k] = chw[(gc*32 + ih*16 + icl)*3 + k];
  const float wx0 = cxw[gc*3+0], wx1 = cxw[gc*3+1], wx2 = cxw[gc*3+2];
  const float bsum = cxb[gc] + chb[gc];
  const int ic = tid >> 3, col = tid & 7;
  const size_t dg = (size_t)b*2048 + row*256 + tid;
  float c_reg = c0[dg];
  h_lds[tid] = h0[dg];
  float xnext = (tid < 8) ? x_flat[((size_t)b*64 + 0)*64 + row*8 + tid] : 0.f;
  __syncthreads();
  for (int t = 0; t < 64; ++t){
    if (tid < 8) x_lds[tid] = xnext;
    __syncthreads();
    if (t < 63 && tid < 8)
      xnext = x_flat[((size_t)b*64 + t + 1)*64 + row*8 + tid];
    float g8[8];
    #pragma unroll
    for (int c2 = 0; c2 < 8; ++c2) g8[c2] = 0.f;
    #pragma unroll
    for (int icl = 0; icl < 16; ++icl){
      const int icg = ih*16 + icl;
      f32x4v hv0 = *reinterpret_cast<const f32x4v*>(&h_lds[icg*8]);
      f32x4v hv1 = *reinterpret_cast<const f32x4v*>(&h_lds[icg*8 + 4]);
      const float hv[8] = {hv0[0],hv0[1],hv0[2],hv0[3],hv1[0],hv1[1],hv1[2],hv1[3]};
      #pragma unroll
      for (int c2 = 0; c2 < 8; ++c2){
        float s = hv[c2] * wh[icl][1];
        if (c2 > 0) s += hv[c2-1] * wh[icl][0];
        if (c2 < 7) s += hv[c2+1] * wh[icl][2];
        g8[c2] += s;
      }
    }
    if (ih == 0){
      #pragma unroll
      for (int c2 = 0; c2 < 8; ++c2){
        float s = x_lds[c2] * wx1 + bsum;
        if (c2 > 0) s += x_lds[c2-1] * wx0;
        if (c2 < 7) s += x_lds[c2+1] * wx2;
        g8[c2] += s;
      }
    }
    #pragma unroll
    for (int c2 = 0; c2 < 8; ++c2) P[gc][ih][c2] = g8[c2];
    __syncthreads();
    const float ipre = P[ic   ][0][col] + P[ic   ][1][col];
    const float fpre = P[ic+32][0][col] + P[ic+32][1][col];
    const float opre = P[ic+64][0][col] + P[ic+64][1][col];
    const float gpre = P[ic+96][0][col] + P[ic+96][1][col];
    const float cn = sigmoidf_(fpre)*c_reg + sigmoidf_(ipre)*tanhf(gpre);
    c_reg = cn;
    const float hn = sigmoidf_(opre)*tanhf(cn);
    const f16 hh = (f16)hn;
    hrawHi[((size_t)t*128 + b)*2048 + row*256 + tid] = hh;
    hrawLo[((size_t)t*128 + b)*2048 + row*256 + tid] = (f16)(hn - (float)hh);
    __syncthreads();
    h_lds[tid] = hn;
  }
}

// ---------------------------------------------------------------------------
// Layer-1 ConvLSTM for ALL 64 steps (persistent over t). x = r0[t] planes.
// Conflict-free wlds layout + padded P + x prefetch.
// ---------------------------------------------------------------------------
__global__ __launch_bounds__(256) void k_cell1_all(
    const f16* __restrict__ r0Hi, const f16* __restrict__ r0Lo,
    const float* __restrict__ h0s, const float* __restrict__ c0s,
    const unsigned short* __restrict__ wp,     // [(icg*6+j)*128+gc]
    const float* __restrict__ cxb, const float* __restrict__ chb,
    f16* __restrict__ hrw1Hi, f16* __restrict__ hrw1Lo)            // [T][B][2048]
{
  const int b = blockIdx.x >> 3, row = blockIdx.x & 7;
  const int tid = threadIdx.x;
  __shared__ float x_lds[256];
  __shared__ float h_lds[256];
  __shared__ float P[128][2][9];
  __shared__ unsigned short wlds[128*32*6];
  const size_t dg = (size_t)b*2048 + row*256 + tid;
  float c_reg = c0s[dg];
  h_lds[tid] = h0s[dg];
  for (int i = tid; i < 128*32*6; i += 256) wlds[i] = wp[i];
  const int ic = tid >> 3, col = tid & 7;
  const float bi = cxb[ic]    + chb[ic];
  const float bf = cxb[ic+32] + chb[ic+32];
  const float bo = cxb[ic+64] + chb[ic+64];
  const float bg = cxb[ic+96] + chb[ic+96];
  const int gc = tid >> 1, ih = tid & 1;
  float xnext = (float)r0Hi[dg] + (float)r0Lo[dg];
  __syncthreads();
  for (int t = 0; t < 64; ++t){
    x_lds[tid] = xnext;
    __syncthreads();
    if (t < 63)
      xnext = (float)r0Hi[(size_t)(t+1)*BD + dg] + (float)r0Lo[(size_t)(t+1)*BD + dg];
    {
      float g8[8];
      #pragma unroll
      for (int c2 = 0; c2 < 8; ++c2) g8[c2] = 0.f;
      #pragma unroll
      for (int icl = 0; icl < 16; ++icl){
        const int icg = ih*16 + icl;
        f32x4v hv0 = *reinterpret_cast<const f32x4v*>(&h_lds[icg*8]);
        f32x4v hv1 = *reinterpret_cast<const f32x4v*>(&h_lds[icg*8 + 4]);
        f32x4v xv0 = *reinterpret_cast<const f32x4v*>(&x_lds[icg*8]);
        f32x4v xv1 = *reinterpret_cast<const f32x4v*>(&x_lds[icg*8 + 4]);
        const float hv[8] = {hv0[0],hv0[1],hv0[2],hv0[3],hv1[0],hv1[1],hv1[2],hv1[3]};
        const float xv[8] = {xv0[0],xv0[1],xv0[2],xv0[3],xv1[0],xv1[1],xv1[2],xv1[3]};
        // conflict-free weight reads: bank = gc/2 (broadcast pairs), 2-way max
        const unsigned short* wq = &wlds[icg*6*128 + gc];
        const float wh0 = bf2f(wq[0]),     wh1 = bf2f(wq[128]),   wh2 = bf2f(wq[256]);
        const float wx0 = bf2f(wq[384]),   wx1 = bf2f(wq[512]),   wx2 = bf2f(wq[640]);
        #pragma unroll
        for (int c2 = 0; c2 < 8; ++c2){
          float s = hv[c2]*wh1 + xv[c2]*wx1;
          if (c2 > 0) s += hv[c2-1]*wh0 + xv[c2-1]*wx0;
          if (c2 < 7) s += hv[c2+1]*wh2 + xv[c2+1]*wx2;
          g8[c2] += s;
        }
      }
      #pragma unroll
      for (int c2 = 0; c2 < 8; ++c2) P[gc][ih][c2] = g8[c2];
    }
    __syncthreads();
    {
      const float ipre = P[ic   ][0][col] + P[ic   ][1][col] + bi;
      const float fpre = P[ic+32][0][col] + P[ic+32][1][col] + bf;
      const float opre = P[ic+64][0][col] + P[ic+64][1][col] + bo;
      const float gpre = P[ic+96][0][col] + P[ic+96][1][col] + bg;
      const float cn = sigmoidf_(fpre)*c_reg + sigmoidf_(ipre)*tanhf(gpre);
      c_reg = cn;
      const float hraw = sigmoidf_(opre)*tanhf(cn);
      const f16 hh = (f16)hraw;
      hrw1Hi[(size_t)t*BD + dg] = hh;
      hrw1Lo[(size_t)t*BD + dg] = (f16)(hraw - (float)hh);
      __syncthreads();           // all P reads done before next iter overwrites
      h_lds[tid] = hraw;
    }
  }
}

// ---------------------------------------------------------------------------
// Batched inter-attention (both layers, all t): block (b, t), 8 waves x 16
// encoder rows, online softmax, deterministic 8-way LDS combine.
// ---------------------------------------------------------------------------
__global__ __launch_bounds__(512) void k_inter_b(
    const unsigned short* __restrict__ encBf,
    const f16* __restrict__ stHi, const f16* __restrict__ stLo,   // [T][B][2048]
    f16* __restrict__ ctxHi, f16* __restrict__ ctxLo)
{
  const int b = blockIdx.x;
  const size_t so = (size_t)blockIdx.y * BD + (size_t)b * 2048;
  const int tid = threadIdx.x;
  const int lane = tid & 63, wv = tid >> 6;
  __shared__ float wav[8][2048];
  __shared__ float wm[8], wl[8];
  float sv[32], av[32];
  #pragma unroll
  for (int p = 0; p < 4; ++p){
    const int d = (p*64 + lane)*8;
    f16x8 hh = *reinterpret_cast<const f16x8*>(stHi + so + d);
    f16x8 ll = *reinterpret_cast<const f16x8*>(stLo + so + d);
    #pragma unroll
    for (int j = 0; j < 8; ++j){ sv[p*8+j] = (float)hh[j] + (float)ll[j]; av[p*8+j] = 0.f; }
  }
  float m = -INFINITY, l = 0.f;
  const int s0 = wv*16;
  for (int r = 0; r < 16; ++r){
    const unsigned short* er = encBf + ((size_t)b*128 + s0 + r)*2048;
    float ef[32];
    float dot = 0.f;
    #pragma unroll
    for (int p = 0; p < 4; ++p){
      u16x8 ev = *reinterpret_cast<const u16x8*>(er + (p*64 + lane)*8);
      #pragma unroll
      for (int j = 0; j < 8; ++j){ const float e = bf2f(ev[j]); ef[p*8+j] = e; dot += e * sv[p*8+j]; }
    }
    #pragma unroll
    for (int off = 1; off < 64; off <<= 1) dot += __shfl_xor(dot, off);
    if (dot > m){
      const float scf = __expf(m - dot);
      l *= scf;
      #pragma unroll
      for (int q = 0; q < 32; ++q) av[q] *= scf;
      m = dot;
    }
    const float pp = __expf(dot - m);
    l += pp;
    #pragma unroll
    for (int q = 0; q < 32; ++q) av[q] += pp * ef[q];
  }
  #pragma unroll
  for (int p = 0; p < 4; ++p){
    const int d = (p*64 + lane)*8;
    f32x4v v0, v1;
    #pragma unroll
    for (int j = 0; j < 4; ++j){ v0[j] = av[p*8+j]; v1[j] = av[p*8+4+j]; }
    *reinterpret_cast<f32x4v*>(&wav[wv][d]) = v0;
    *reinterpret_cast<f32x4v*>(&wav[wv][d+4]) = v1;
  }
  if (lane == 0){ wm[wv] = m; wl[wv] = l; }
  __syncthreads();
  float M = wm[0];
  #pragma unroll
  for (int i = 1; i < 8; ++i) M = fmaxf(M, wm[i]);
  float U[8];
  float L = 0.f;
  #pragma unroll
  for (int i = 0; i < 8; ++i){ U[i] = __expf(wm[i] - M); L += wl[i] * U[i]; }
  const float Linv = 1.f / L;
  const int d0 = tid * 4;
  float acc[4] = {0.f, 0.f, 0.f, 0.f};
  #pragma unroll
  for (int w = 0; w < 8; ++w){
    f32x4v v = *reinterpret_cast<const f32x4v*>(&wav[w][d0]);
    #pragma unroll
    for (int j = 0; j < 4; ++j) acc[j] += U[w] * v[j];
  }
  f16x4 hh, ll;
  #pragma unroll
  for (int j = 0; j < 4; ++j){
    const float v = acc[j] * Linv;
    hh[j] = (f16)v;
    ll[j] = (f16)(v - (float)hh[j]);
  }
  *reinterpret_cast<f16x4*>(ctxHi + so + d0) = hh;
  *reinterpret_cast<f16x4*>(ctxLo + so + d0) = ll;
}

// ---------------------------------------------------------------------------
// Batched full-K ia GEMM (all t): p[t] = tanh([A0|A1]@W + bias), f16 hi/lo.
// Grid (32 nt, 64 t). K=4096, f16 2-pass MFMA, global_load_lds double-buffer.
// ---------------------------------------------------------------------------
__global__ __launch_bounds__(256, 2) void k_gemm_full(
    const f16* __restrict__ a0Hi, const f16* __restrict__ a0Lo,
    const f16* __restrict__ a1Hi, const f16* __restrict__ a1Lo,
    const f16* __restrict__ wHp, const float* __restrict__ bias,
    f16* __restrict__ outHi, f16* __restrict__ outLo)
{
  const int nt = blockIdx.x, t = blockIdx.y;
  const size_t tb = (size_t)t * BD;
  const int tid = threadIdx.x;
  const int lane = tid & 63, wv = tid >> 6;
  __shared__ __align__(16) char lds[81920];
  const f16* wH = wHp + (size_t)(nt*64)*4096;

  auto stage = [&](int buf, int ki){
    char* lb = lds + buf*40960;
    const f16* aH = ((ki < 32) ? a0Hi : a1Hi) + tb;
    const f16* aL = ((ki < 32) ? a0Lo : a1Lo) + tb;
    const int ke = (ki & 31) * 64;
    #pragma unroll
    for (int i = 0; i < 4; ++i){
      const int c = i*256 + tid, row = c >> 3;
      const int srcb = ((c & 7)*16) ^ ((row & 7) << 4);
      g2l16((const char*)(aH + (size_t)row*2048 + ke) + srcb, lb + c*16);
      g2l16((const char*)(aL + (size_t)row*2048 + ke) + srcb, lb + 16384 + c*16);
    }
    #pragma unroll
    for (int i = 0; i < 2; ++i){
      const int c = i*256 + tid, row = c >> 3;
      const int srcb = ((c & 7)*16) ^ ((row & 7) << 4);
      g2l16((const char*)(wH + (size_t)row*4096 + ki*64) + srcb, lb + 32768 + c*16);
    }
  };

  f32x16 acc0, acc1;
  #pragma unroll
  for (int r = 0; r < 16; ++r){ acc0[r] = 0.f; acc1[r] = 0.f; }
  const int rA = wv*32 + (lane & 31);
  const int kb = lane >> 5;
  const int rB0 = lane & 31;
  const int aswz = (rA & 7) << 4;
  const int bswz = (rB0 & 7) << 4;

  stage(0, 0);
  __syncthreads();
  for (int ki = 0; ki < 64; ++ki){
    const int buf = ki & 1;
    if (ki < 63) stage(buf ^ 1, ki + 1);
    const char* lb = lds + buf*40960;
    #pragma unroll
    for (int s = 0; s < 4; ++s){
      const int cb = s*32 + kb*16;
      f16x8 ah  = *reinterpret_cast<const f16x8*>(lb + rA*128 + (cb ^ aswz));
      f16x8 al  = *reinterpret_cast<const f16x8*>(lb + 16384 + rA*128 + (cb ^ aswz));
      f16x8 b0h = *reinterpret_cast<const f16x8*>(lb + 32768 + rB0*128 + (cb ^ bswz));
      f16x8 b1h = *reinterpret_cast<const f16x8*>(lb + 32768 + 4096 + rB0*128 + (cb ^ bswz));
      acc0 = __builtin_amdgcn_mfma_f32_32x32x16_f16(ah, b0h, acc0, 0, 0, 0);
      acc1 = __builtin_amdgcn_mfma_f32_32x32x16_f16(ah, b1h, acc1, 0, 0, 0);
      acc0 = __builtin_amdgcn_mfma_f32_32x32x16_f16(al, b0h, acc0, 0, 0, 0);
      acc1 = __builtin_amdgcn_mfma_f32_32x32x16_f16(al, b1h, acc1, 0, 0, 0);
    }
    __syncthreads();
  }

  const int col0 = nt*64 + (lane & 31);
  const float b0 = bias[col0], b1 = bias[col0 + 32];
  const int rowBase = wv*32 + 4*kb;
  #pragma unroll
  for (int r = 0; r < 16; ++r){
    const int rr = rowBase + (r & 3) + 8*(r >> 2);
    const size_t o = tb + (size_t)rr*2048 + col0;
    const float p = tanhf(acc0[r] + b0);
    const float q = tanhf(acc1[r] + b1);
    const f16 ph = (f16)p, qh = (f16)q;
    outHi[o]      = ph;  outLo[o]      = (f16)(p - (float)ph);
    outHi[o + 32] = qh;  outLo[o + 32] = (f16)(q - (float)qh);
  }
}

// ---------------------------------------------------------------------------
// Batched sa GEMM (all t): A = p hi/lo, W = [Wlow^T|Wup^T] ([4096][2048]).
// nt<32 -> Y (f32, raw); nt>=32 -> G (f16). Grid (64 nt, 64 t), K=2048.
// ---------------------------------------------------------------------------
__global__ __launch_bounds__(256, 2) void k_gemm_full2(
    const f16* __restrict__ aHi, const f16* __restrict__ aLo,   // [T][B][2048]
    const f16* __restrict__ wSp,                                // [4096][2048]
    float* __restrict__ Y, f16* __restrict__ G)                 // [T][B][2048]
{
  const int nt = blockIdx.x, t = blockIdx.y;
  const size_t tb = (size_t)t * BD;
  const int tid = threadIdx.x;
  const int lane = tid & 63, wv = tid >> 6;
  __shared__ __align__(16) char lds[81920];
  const f16* wH = wSp + (size_t)(nt*64)*2048;
  const f16* aH = aHi + tb;
  const f16* aL = aLo + tb;

  auto stage = [&](int buf, int ki){
    char* lb = lds + buf*40960;
    const int ke = ki*64;
    #pragma unroll
    for (int i = 0; i < 4; ++i){
      const int c = i*256 + tid, row = c >> 3;
      const int srcb = ((c & 7)*16) ^ ((row & 7) << 4);
      g2l16((const char*)(aH + (size_t)row*2048 + ke) + srcb, lb + c*16);
      g2l16((const char*)(aL + (size_t)row*2048 + ke) + srcb, lb + 16384 + c*16);
    }
    #pragma unroll
    for (int i = 0; i < 2; ++i){
      const int c = i*256 + tid, row = c >> 3;
      const int srcb = ((c & 7)*16) ^ ((row & 7) << 4);
      g2l16((const char*)(wH + (size_t)row*2048 + ke) + srcb, lb + 32768 + c*16);
    }
  };

  f32x16 acc0, acc1;
  #pragma unroll
  for (int r = 0; r < 16; ++r){ acc0[r] = 0.f; acc1[r] = 0.f; }
  const int rA = wv*32 + (lane & 31);
  const int kb = lane >> 5;
  const int rB0 = lane & 31;
  const int aswz = (rA & 7) << 4;
  const int bswz = (rB0 & 7) << 4;

  stage(0, 0);
  __syncthreads();
  for (int ki = 0; ki < 32; ++ki){
    const int buf = ki & 1;
    if (ki < 31) stage(buf ^ 1, ki + 1);
    const char* lb = lds + buf*40960;
    #pragma unroll
    for (int s = 0; s < 4; ++s){
      const int cb = s*32 + kb*16;
      f16x8 ah  = *reinterpret_cast<const f16x8*>(lb + rA*128 + (cb ^ aswz));
      f16x8 al  = *reinterpret_cast<const f16x8*>(lb + 16384 + rA*128 + (cb ^ aswz));
      f16x8 b0h = *reinterpret_cast<const f16x8*>(lb + 32768 + rB0*128 + (cb ^ bswz));
      f16x8 b1h = *reinterpret_cast<const f16x8*>(lb + 32768 + 4096 + rB0*128 + (cb ^ bswz));
      acc0 = __builtin_amdgcn_mfma_f32_32x32x16_f16(ah, b0h, acc0, 0, 0, 0);
      acc1 = __builtin_amdgcn_mfma_f32_32x32x16_f16(ah, b1h, acc1, 0, 0, 0);
      acc0 = __builtin_amdgcn_mfma_f32_32x32x16_f16(al, b0h, acc0, 0, 0, 0);
      acc1 = __builtin_amdgcn_mfma_f32_32x32x16_f16(al, b1h, acc1, 0, 0, 0);
    }
    __syncthreads();
  }

  const int col0 = nt*64 + (lane & 31);
  const int rowBase = wv*32 + 4*kb;
  if (nt < 32){
    float* yp = Y + tb + col0;
    #pragma unroll
    for (int r = 0; r < 16; ++r){
      const int rr = rowBase + (r & 3) + 8*(r >> 2);
      yp[(size_t)rr*2048]      = acc0[r];
      yp[(size_t)rr*2048 + 32] = acc1[r];
    }
  } else {
    f16* gp = G + tb + (col0 - 2048);
    #pragma unroll
    for (int r = 0; r < 16; ++r){
      const int rr = rowBase + (r & 3) + 8*(r >> 2);
      gp[(size_t)rr*2048]      = (f16)acc0[r];
      gp[(size_t)rr*2048 + 32] = (f16)acc1[r];
    }
  }
}

// ---------------------------------------------------------------------------
// Self-attention refine chain (persistent over t). Block per b, 512 threads.
// r[t] = tanh(Y[t] + sum_{i<t} a_i G[i] + bias),  a = softmax(r[i<t] . p[t]).
// ---------------------------------------------------------------------------
__global__ __launch_bounds__(512) void k_selfchain(
    const f16* __restrict__ pHi, const f16* __restrict__ pLo,   // [T][B][2048]
    const float* __restrict__ Y, const f16* __restrict__ G,     // [T][B][2048]
    const float* __restrict__ bias,
    f16* __restrict__ rHi, f16* __restrict__ rLo)               // [T][B][2048]
{
  const int b = blockIdx.x;
  const int tid = threadIdx.x, lane = tid & 63, wv = tid >> 6;   // 8 waves
  __shared__ float sc[64];
  __shared__ float a_lds[64];
  const int d0 = tid * 4;
  f32x4v bb = *reinterpret_cast<const f32x4v*>(bias + d0);
  for (int t = 0; t < 64; ++t){
    const size_t pb = ((size_t)t*128 + b)*2048;
    if (t > 0){
      float hreg[32];
      #pragma unroll
      for (int jj = 0; jj < 4; ++jj){
        const int d = (jj*64 + lane)*8;
        f16x8 h8 = *reinterpret_cast<const f16x8*>(pHi + pb + d);
        f16x8 l8 = *reinterpret_cast<const f16x8*>(pLo + pb + d);
        #pragma unroll
        for (int j = 0; j < 8; ++j) hreg[jj*8+j] = (float)h8[j] + (float)l8[j];
      }
      for (int i = wv; i < t; i += 8){
        const f16* rh = rHi + ((size_t)i*128 + b)*2048;
        const f16* rl = rLo + ((size_t)i*128 + b)*2048;
        float dot = 0.f;
        #pragma unroll
        for (int jj = 0; jj < 4; ++jj){
          const int d = (jj*64 + lane)*8;
          f16x8 h8 = *reinterpret_cast<const f16x8*>(rh + d);
          f16x8 l8 = *reinterpret_cast<const f16x8*>(rl + d);
          #pragma unroll
          for (int j = 0; j < 8; ++j)
            dot += ((float)h8[j] + (float)l8[j]) * hreg[jj*8+j];
        }
        #pragma unroll
        for (int off = 1; off < 64; off <<= 1) dot += __shfl_xor(dot, off);
        if (lane == 0) sc[i] = dot;
      }
      __syncthreads();
      if (tid < 64){
        const float s = (tid < t) ? sc[tid] : -INFINITY;
        float mm = s;
        #pragma unroll
        for (int off = 1; off < 64; off <<= 1) mm = fmaxf(mm, __shfl_xor(mm, off));
        const float e = (tid < t) ? __expf(s - mm) : 0.f;
        float sum = e;
        #pragma unroll
        for (int off = 1; off < 64; off <<= 1) sum += __shfl_xor(sum, off);
        a_lds[tid] = e / sum;
      }
      __syncthreads();
    }
    float y[4];
    {
      f32x4v yv = *reinterpret_cast<const f32x4v*>(Y + (size_t)t*BD + (size_t)b*2048 + d0);
      #pragma unroll
      for (int j = 0; j < 4; ++j) y[j] = yv[j] + bb[j];
    }
    if (t > 0){
      for (int i = 0; i < t; ++i){
        const float a = a_lds[i];
        f16x4 g4 = *reinterpret_cast<const f16x4*>(G + ((size_t)i*128 + b)*2048 + d0);
        #pragma unroll
        for (int j = 0; j < 4; ++j) y[j] += a * (float)g4[j];
      }
    }
    f16x4 hh, ll;
    #pragma unroll
    for (int j = 0; j < 4; ++j){
      const float v = tanhf(y[j]);
      hh[j] = (f16)v;
      ll[j] = (f16)(v - (float)hh[j]);
    }
    *reinterpret_cast<f16x4*>(rHi + pb + d0) = hh;
    *reinterpret_cast<f16x4*>(rLo + pb + d0) = ll;
    __syncthreads();   // r[t] stores drained before t+1 scores read them
  }
}

// ---------------------------------------------------------------------------
// Head stage 1: z1 = relu(r1(8192x2048) @ hw1 + hb1), f16 2-pass MFMA
// ---------------------------------------------------------------------------
__global__ __launch_bounds__(256) void k_headgemm(
    const f16* __restrict__ aHi, const f16* __restrict__ aLo,
    const f16* __restrict__ w1H,   // [224][2048]
    const float* __restrict__ hb1,
    float* __restrict__ z1)        // [8192][224]
{
  const int mb = blockIdx.x;
  const int nt = blockIdx.y;
  const int lane = threadIdx.x & 63, wv = threadIdx.x >> 6;
  const int rowA = mb*128 + wv*32 + (lane & 31);
  const int kb = lane >> 5;
  const int n = nt*32 + (lane & 31);
  const f16* pAH = aHi + (size_t)rowA*2048 + kb*8;
  const f16* pAL = aLo + (size_t)rowA*2048 + kb*8;
  const f16* pBH = w1H + (size_t)n*2048 + kb*8;
  f32x16 acc;
  #pragma unroll
  for (int r = 0; r < 16; ++r) acc[r] = 0.f;
  #pragma unroll 4
  for (int s = 0; s < 128; ++s){
    f16x8 ah = *reinterpret_cast<const f16x8*>(pAH + s*16);
    f16x8 al = *reinterpret_cast<const f16x8*>(pAL + s*16);
    f16x8 bh = *reinterpret_cast<const f16x8*>(pBH + s*16);
    acc = __builtin_amdgcn_mfma_f32_32x32x16_f16(ah, bh, acc, 0, 0, 0);
    acc = __builtin_amdgcn_mfma_f32_32x32x16_f16(al, bh, acc, 0, 0, 0);
  }
  const float bias = (n < 200) ? hb1[n] : 0.f;
  const int rowBase = mb*128 + wv*32 + 4*kb;
  #pragma unroll
  for (int r = 0; r < 16; ++r){
    const int rr = rowBase + (r & 3) + 8*(r >> 2);
    z1[(size_t)rr*224 + n] = fmaxf(acc[r] + bias, 0.f);
  }
}

// Head stage 2
__global__ __launch_bounds__(256) void k_head2(
    const float* __restrict__ z1,
    const float* __restrict__ hw2, const float* __restrict__ hb2,
    const float* __restrict__ hw3, const float* __restrict__ hb3,
    float* __restrict__ out)
{
  const int r0 = blockIdx.x * 64;
  const int tid = threadIdx.x;
  __shared__ float zl[64][200];
  __shared__ float z2[64][50];
  for (int i = tid; i < 64*200; i += 256){
    const int r = i / 200, n = i % 200;
    zl[r][n] = z1[(size_t)(r0 + r)*224 + n];
  }
  __syncthreads();
  for (int i = tid; i < 64*50; i += 256){
    const int r = i / 50, n = i % 50;
    float s = hb2[n];
    for (int k = 0; k < 200; ++k) s += zl[r][k] * hw2[k*50 + n];
    z2[r][n] = fmaxf(s, 0.f);
  }
  __syncthreads();
  for (int i = tid; i < 128; i += 256){
    const int r = i >> 1, c = i & 1;
    float s = hb3[c];
    for (int k = 0; k < 50; ++k) s += z2[r][k] * hw3[k*2 + c];
    const int rg = r0 + r;
    const int tt = rg >> 7, b = rg & 127;
    out[(size_t)b*128 + tt*2 + c] = s;
  }
}

// ---------------------------------------------------------------------------
extern "C" void kernel_launch(void* const* d_in, const int* in_sizes, int n_in,
                              void* d_out, int out_size, void* d_ws, size_t ws_size,
                              hipStream_t stream)
{
  (void)in_sizes; (void)n_in; (void)out_size; (void)ws_size;
  const float* x_flat = (const float*)d_in[0];
  const float* enc    = (const float*)d_in[1];
  const float* h0     = (const float*)d_in[2];
  const float* c0     = (const float*)d_in[3];
  const float* cx_w0  = (const float*)d_in[4];
  const float* cx_b0  = (const float*)d_in[5];
  const float* ch_w0  = (const float*)d_in[6];
  const float* ch_b0  = (const float*)d_in[7];
  const float* cx_w1  = (const float*)d_in[8];
  const float* cx_b1  = (const float*)d_in[9];
  const float* ch_w1  = (const float*)d_in[10];
  const float* ch_b1  = (const float*)d_in[11];
  const float* ia_w0  = (const float*)d_in[12];
  const float* ia_b0  = (const float*)d_in[13];
  const float* sa_w0  = (const float*)d_in[14];
  const float* sa_b0  = (const float*)d_in[15];
  const float* ia_w1  = (const float*)d_in[16];
  const float* ia_b1  = (const float*)d_in[17];
  const float* sa_w1  = (const float*)d_in[18];
  const float* sa_b1  = (const float*)d_in[19];
  const float* hw1    = (const float*)d_in[20];
  const float* hb1    = (const float*)d_in[21];
  const float* hw2    = (const float*)d_in[22];
  const float* hb2    = (const float*)d_in[23];
  const float* hw3    = (const float*)d_in[24];
  const float* hb3    = (const float*)d_in[25];
  float* out = (float*)d_out;

  char* ws = (char*)d_ws;
  size_t off = 0;
  auto alloc = [&](size_t bytes) -> char* {
    char* p = ws + off;
    off += (bytes + 255) & ~(size_t)255;
    return p;
  };
  const size_t WPLANE = (size_t)2048*4096*2;   // 16 MiB
  const size_t TPLANE = (size_t)64*BD*2;       // 32 MiB, [T][B][D] f16
  f16* wIa0 = (f16*)alloc(WPLANE);
  f16* wSa0 = (f16*)alloc(WPLANE);   // [4096][2048]: Wlow^T rows 0..2047, Wup^T rows 2048..
  f16* wIa1 = (f16*)alloc(WPLANE);
  f16* wSa1 = (f16*)alloc(WPLANE);
  f16* w1H  = (f16*)alloc((size_t)224*2048*2);
  unsigned short* encBf = (unsigned short*)alloc((size_t)128*128*2048*2);
  f16* S1 = (f16*)alloc(TPLANE);
  f16* S2 = (f16*)alloc(TPLANE);
  f16* S3 = (f16*)alloc(TPLANE);
  f16* S4 = (f16*)alloc(TPLANE);
  f16* S5 = (f16*)alloc(TPLANE);
  f16* S6 = (f16*)alloc(TPLANE);
  f16* S7 = (f16*)alloc(TPLANE);
  f16* S8 = (f16*)alloc(TPLANE);
  unsigned short* wpack1 = (unsigned short*)alloc((size_t)128*32*6*2);
  // total ws ~= 385 MiB. Alias names (lifetimes verified disjoint):
  f16*  hr0AHi = S1;  f16* hr0ALo = S2;
  f16*  ctx0Hi = S3;  f16* ctx0Lo = S4;
  f16*  p0Hi   = S5;  f16* p0Lo   = S6;
  float* Y0 = (float*)S1;                    // 64 MiB over S1+S2 (contiguous)
  f16*  G0  = S3;
  f16*  r0Hi = S7;    f16* r0Lo   = S8;
  f16*  hrw1Hi = S5;  f16* hrw1Lo = S6;
  f16*  ctx1Hi = S1;  f16* ctx1Lo = S2;
  f16*  p1Hi = S7;    f16* p1Lo   = S8;
  float* Y1 = (float*)S1;                    // 64 MiB over S1+S2
  f16*  G1  = S4;
  f16*  r1Hi = S5;    f16* r1Lo   = S3;
  float* z1 = (float*)wSa0;                  // head scratch (wSa0 dead by then)

  // ---- prologue -----------------------------------------------------------
  k_transpose_f16<<<dim3(64,128),256,0,stream>>>(ia_w0, wIa0, 4096, 2048);
  k_transpose_f16<<<dim3(64,128),256,0,stream>>>(ia_w1, wIa1, 4096, 2048);
  k_transpose_f16<<<dim3(64,64),256,0,stream>>>(sa_w0, wSa0, 2048, 2048);
  k_transpose_f16<<<dim3(64,64),256,0,stream>>>(sa_w0 + (size_t)2048*2048,
                                                wSa0 + (size_t)2048*2048, 2048, 2048);
  k_transpose_f16<<<dim3(64,64),256,0,stream>>>(sa_w1, wSa1, 2048, 2048);
  k_transpose_f16<<<dim3(64,64),256,0,stream>>>(sa_w1 + (size_t)2048*2048,
                                                wSa1 + (size_t)2048*2048, 2048, 2048);
  k_transpose_f16<<<dim3(7,64),256,0,stream>>>(hw1, w1H, 2048, 200);
  k_f32_to_bf16<<<(128*128*2048/4 + 255)/256, 256, 0, stream>>>(enc, encBf, 128*128*2048/4);
  k_pack_cellw<<<16,256,0,stream>>>(ch_w1, cx_w1, wpack1);

  // ---- layer 0 (fully batched + one persistent chain) ---------------------
  k_cell0<<<1024,256,0,stream>>>(x_flat, h0, c0, cx_w0, cx_b0, ch_w0, ch_b0,
                                 hr0AHi, hr0ALo);
  k_inter_b<<<dim3(128,64),512,0,stream>>>(encBf, hr0AHi, hr0ALo, ctx0Hi, ctx0Lo);
  k_gemm_full<<<dim3(32,64),256,0,stream>>>(hr0AHi, hr0ALo, ctx0Hi, ctx0Lo,
                                            wIa0, ia_b0, p0Hi, p0Lo);
  k_gemm_full2<<<dim3(64,64),256,0,stream>>>(p0Hi, p0Lo, wSa0, Y0, G0);
  k_selfchain<<<128,512,0,stream>>>(p0Hi, p0Lo, Y0, G0, sa_b0, r0Hi, r0Lo);

  // ---- layer 1 (persistent cell + fully batched + one persistent chain) ---
  k_cell1_all<<<1024,256,0,stream>>>(r0Hi, r0Lo,
                                     h0 + (size_t)128*2048, c0 + (size_t)128*2048,
                                     wpack1, cx_b1, ch_b1, hrw1Hi, hrw1Lo);
  k_inter_b<<<dim3(128,64),512,0,stream>>>(encBf, hrw1Hi, hrw1Lo, ctx1Hi, ctx1Lo);
  k_gemm_full<<<dim3(32,64),256,0,stream>>>(hrw1Hi, hrw1Lo, ctx1Hi, ctx1Lo,
                                            wIa1, ia_b1, p1Hi, p1Lo);
  k_gemm_full2<<<dim3(64,64),256,0,stream>>>(p1Hi, p1Lo, wSa1, Y1, G1);
  k_selfchain<<<128,512,0,stream>>>(p1Hi, p1Lo, Y1, G1, sa_b1, r1Hi, r1Lo);

  // ---- head (batched over all t,b) ----------------------------------------
  k_headgemm<<<dim3(64,7),256,0,stream>>>(r1Hi, r1Lo, w1H, hb1, z1);
  k_head2<<<128,256,0,stream>>>(z1, hw2, hb2, hw3, hb3, out);
}